// Round 1
// baseline (402.478 us; speedup 1.0000x reference)
//
#include <hip/hip_runtime.h>

typedef unsigned short u16;
typedef unsigned int u32;
typedef __bf16 bf16x8 __attribute__((ext_vector_type(8)));
typedef float f32x4 __attribute__((ext_vector_type(4)));

__device__ __forceinline__ u16 f2bf(float f) {
    union { float f; u32 u; } v;
    v.f = f;
    u32 r = v.u + 0x7fffu + ((v.u >> 16) & 1u);
    return (u16)(r >> 16);
}

__device__ __forceinline__ void glds16(const void* g, void* l) {
    __builtin_amdgcn_global_load_lds(
        (__attribute__((address_space(1))) unsigned int*)(g),
        (__attribute__((address_space(3))) unsigned int*)(l), 16, 0, 0);
}

// ---------------- cast fp32 -> bf16, 4 elems/thread ----------------
__global__ void castbf(const float* __restrict__ in, u16* __restrict__ out, int n4) {
    int i = blockIdx.x * 256 + threadIdx.x;
    if (i >= n4) return;
    float4 v = ((const float4*)in)[i];
    ushort4 o;
    o.x = f2bf(v.x); o.y = f2bf(v.y); o.z = f2bf(v.z); o.w = f2bf(v.w);
    ((ushort4*)out)[i] = o;
}

// ---------------- 128x128 bf16 GEMM, C = A * B^T, fp32 out ----------------
// A: MxK bf16 row-major, B: NxK bf16 row-major ("B^T input" layout)
__global__ __launch_bounds__(256) void gemm128(
    const u16* __restrict__ A, const u16* __restrict__ B,
    float* __restrict__ C, int M, int N, int K)
{
    __shared__ alignas(16) u16 As[128 * 32];
    __shared__ alignas(16) u16 Bs[128 * 32];
    const int tid = threadIdx.x;
    const int lane = tid & 63;
    const int wave = tid >> 6;
    const int bm = blockIdx.y * 128, bn = blockIdx.x * 128;
    const int wm = (wave >> 1) * 64, wn = (wave & 1) * 64;
    const int ln = lane & 15, quad = lane >> 4;

    f32x4 acc[4][4] = {};

    // staging map: chunk c*256+tid (16B each); row = chunk>>2, colElem = (chunk&3)*8
    const int srow = tid >> 2;
    const int scol = (tid & 3) * 8;
    const u16* gA = A + (size_t)(bm + srow) * K + scol;
    const u16* gB = B + (size_t)(bn + srow) * K + scol;
    u16* lA = &As[wave * 512];   // wave-uniform LDS base (bytes: wave*1024)
    u16* lB = &Bs[wave * 512];

    for (int k0 = 0; k0 < K; k0 += 32) {
        glds16(gA + k0, lA);
        glds16(gA + (size_t)64 * K + k0, lA + 2048);
        glds16(gB + k0, lB);
        glds16(gB + (size_t)64 * K + k0, lB + 2048);
        __builtin_amdgcn_s_waitcnt(0);
        __syncthreads();

        bf16x8 af[4], bfr[4];
#pragma unroll
        for (int i = 0; i < 4; ++i)
            af[i] = *(const bf16x8*)&As[(wm + i * 16 + ln) * 32 + quad * 8];
#pragma unroll
        for (int j = 0; j < 4; ++j)
            bfr[j] = *(const bf16x8*)&Bs[(wn + j * 16 + ln) * 32 + quad * 8];
#pragma unroll
        for (int i = 0; i < 4; ++i)
#pragma unroll
            for (int j = 0; j < 4; ++j)
                acc[i][j] = __builtin_amdgcn_mfma_f32_16x16x32_bf16(af[i], bfr[j], acc[i][j], 0, 0, 0);
        __syncthreads();
    }

    // epilogue: C/D layout col=lane&15, row=quad*4+reg
#pragma unroll
    for (int i = 0; i < 4; ++i) {
#pragma unroll
        for (int r = 0; r < 4; ++r) {
            int gm = bm + wm + i * 16 + quad * 4 + r;
            float* Crow = C + (size_t)gm * N + bn + wn + ln;
#pragma unroll
            for (int j = 0; j < 4; ++j)
                Crow[j * 16] = acc[i][j][r];
        }
    }
}

// ---------------- fused RMSNorm + RoPE, qkv fp32 -> q/k/v bf16 (B,H,T,64) ----------------
__global__ void normrope_kernel(
    const float* __restrict__ qkv, const float* __restrict__ fcos,
    const float* __restrict__ fsin, const float* __restrict__ qw,
    const float* __restrict__ kw,
    u16* __restrict__ q, u16* __restrict__ k, u16* __restrict__ v)
{
    int gw = blockIdx.x * 4 + (threadIdx.x >> 6);   // row over (b,t,which,h)
    int lane = threadIdx.x & 63;
    int h = gw & 15;
    int rest = gw >> 4;
    int which = rest % 3;
    int bt = rest / 3;           // b*2048 + t
    int t = bt & 2047;
    int b = bt >> 11;

    float xv = qkv[(size_t)gw * 64 + lane];
    size_t outIdx = ((size_t)((b * 16 + h) * 2048 + t)) * 64 + lane;

    if (which == 2) { v[outIdx] = f2bf(xv); return; }

    float ss = xv * xv;
#pragma unroll
    for (int m = 32; m; m >>= 1) ss += __shfl_xor(ss, m);
    float xn = xv * rsqrtf(ss * (1.0f / 64.0f) + 1e-6f) * ((which == 0) ? qw[lane] : kw[lane]);
    float other = __shfl_xor(xn, 1);
    float c = fcos[t * 32 + (lane >> 1)];
    float s = fsin[t * 32 + (lane >> 1)];
    float res = (lane & 1) ? fmaf(other, s, xn * c) : fmaf(xn, c, -(other * s));
    u16* dst = (which == 0) ? q : k;
    dst[outIdx] = f2bf(res);
}

// ---------------- flash attention (causal), bf16 in/out ----------------
// Q,K,V: (B*H, 2048, 64) bf16. Y: (B, 2048, 1024) bf16.
__global__ __launch_bounds__(256) void attn_kernel(
    const u16* __restrict__ Q, const u16* __restrict__ K,
    const u16* __restrict__ V, u16* __restrict__ Y)
{
    __shared__ alignas(16) u16 Ks[32 * 64];   // [kv][d]
    __shared__ alignas(16) u16 Vt[64 * 32];   // [d][kv]
    __shared__ alignas(16) u16 Ps[4 * 16 * 32]; // per-wave P scratch [m][kv]

    const int tid = threadIdx.x;
    const int lane = tid & 63;
    const int wave = tid >> 6;
    const int ln = lane & 15, quad = lane >> 4;
    const int qt = blockIdx.x;      // 0..31
    const int bh = blockIdx.y;      // 0..31
    const int qb = qt * 64;
    const size_t base = (size_t)bh * 2048 * 64;

    const int qrow = qb + wave * 16 + ln;
    bf16x8 qf0 = *(const bf16x8*)&Q[base + (size_t)qrow * 64 + quad * 8];
    bf16x8 qf1 = *(const bf16x8*)&Q[base + (size_t)qrow * 64 + 32 + quad * 8];

    f32x4 o0 = {}, o1 = {}, o2 = {}, o3 = {};
    float m_r[4], l_r[4];
#pragma unroll
    for (int r = 0; r < 4; ++r) { m_r[r] = -1e30f; l_r[r] = 0.0f; }

    const int ntiles = qb / 32 + 2;
    for (int jt = 0; jt < ntiles; ++jt) {
        const int jb = jt * 32;
        // stage K tile: wave loads rows jb + wave*8 .. +7
        glds16(&K[base + (size_t)(jb + wave * 8 + (lane >> 3)) * 64 + (lane & 7) * 8],
               &Ks[wave * 512]);
        // stage V tile transposed
        {
            int vr = tid >> 3, vc = (tid & 7) * 8;
            uint4 vv = *(const uint4*)&V[base + (size_t)(jb + vr) * 64 + vc];
            Vt[(vc + 0) * 32 + vr] = (u16)(vv.x & 0xffff);
            Vt[(vc + 1) * 32 + vr] = (u16)(vv.x >> 16);
            Vt[(vc + 2) * 32 + vr] = (u16)(vv.y & 0xffff);
            Vt[(vc + 3) * 32 + vr] = (u16)(vv.y >> 16);
            Vt[(vc + 4) * 32 + vr] = (u16)(vv.z & 0xffff);
            Vt[(vc + 5) * 32 + vr] = (u16)(vv.z >> 16);
            Vt[(vc + 6) * 32 + vr] = (u16)(vv.w & 0xffff);
            Vt[(vc + 7) * 32 + vr] = (u16)(vv.w >> 16);
        }
        __builtin_amdgcn_s_waitcnt(0);
        __syncthreads();

        // S = Q K^T  (two 16-col tiles)
        f32x4 s0 = {}, s1 = {};
        {
            bf16x8 kf;
            kf = *(const bf16x8*)&Ks[ln * 64 + quad * 8];            s0 = __builtin_amdgcn_mfma_f32_16x16x32_bf16(qf0, kf, s0, 0, 0, 0);
            kf = *(const bf16x8*)&Ks[ln * 64 + 32 + quad * 8];       s0 = __builtin_amdgcn_mfma_f32_16x16x32_bf16(qf1, kf, s0, 0, 0, 0);
            kf = *(const bf16x8*)&Ks[(16 + ln) * 64 + quad * 8];     s1 = __builtin_amdgcn_mfma_f32_16x16x32_bf16(qf0, kf, s1, 0, 0, 0);
            kf = *(const bf16x8*)&Ks[(16 + ln) * 64 + 32 + quad * 8];s1 = __builtin_amdgcn_mfma_f32_16x16x32_bf16(qf1, kf, s1, 0, 0, 0);
        }

        const bool domask = (jb + 31) > (qb + wave * 16);
#pragma unroll
        for (int r = 0; r < 4; ++r) {
            float sv0 = s0[r] * 0.125f;
            float sv1 = s1[r] * 0.125f;
            if (domask) {
                int gq = qb + wave * 16 + quad * 4 + r;
                if (jb + ln > gq)      sv0 = -1e30f;
                if (jb + 16 + ln > gq) sv1 = -1e30f;
            }
            float mx = fmaxf(sv0, sv1);
            mx = fmaxf(mx, __shfl_xor(mx, 1));
            mx = fmaxf(mx, __shfl_xor(mx, 2));
            mx = fmaxf(mx, __shfl_xor(mx, 4));
            mx = fmaxf(mx, __shfl_xor(mx, 8));
            float mnew = fmaxf(m_r[r], mx);
            float alpha = __expf(m_r[r] - mnew);
            float e0 = __expf(sv0 - mnew);
            float e1 = __expf(sv1 - mnew);
            float sum = e0 + e1;
            sum += __shfl_xor(sum, 1);
            sum += __shfl_xor(sum, 2);
            sum += __shfl_xor(sum, 4);
            sum += __shfl_xor(sum, 8);
            l_r[r] = l_r[r] * alpha + sum;
            m_r[r] = mnew;
            o0[r] *= alpha; o1[r] *= alpha; o2[r] *= alpha; o3[r] *= alpha;
            Ps[wave * 512 + (quad * 4 + r) * 32 + ln] = f2bf(e0);
            Ps[wave * 512 + (quad * 4 + r) * 32 + 16 + ln] = f2bf(e1);
        }

        __builtin_amdgcn_s_waitcnt(0xC07F);  // lgkmcnt(0): Ps writes -> reads
        bf16x8 pf = *(const bf16x8*)&Ps[wave * 512 + ln * 32 + quad * 8];
        {
            bf16x8 vf;
            vf = *(const bf16x8*)&Vt[(0 * 16 + ln) * 32 + quad * 8]; o0 = __builtin_amdgcn_mfma_f32_16x16x32_bf16(pf, vf, o0, 0, 0, 0);
            vf = *(const bf16x8*)&Vt[(1 * 16 + ln) * 32 + quad * 8]; o1 = __builtin_amdgcn_mfma_f32_16x16x32_bf16(pf, vf, o1, 0, 0, 0);
            vf = *(const bf16x8*)&Vt[(2 * 16 + ln) * 32 + quad * 8]; o2 = __builtin_amdgcn_mfma_f32_16x16x32_bf16(pf, vf, o2, 0, 0, 0);
            vf = *(const bf16x8*)&Vt[(3 * 16 + ln) * 32 + quad * 8]; o3 = __builtin_amdgcn_mfma_f32_16x16x32_bf16(pf, vf, o3, 0, 0, 0);
        }
        __syncthreads();
    }

    // epilogue: y (B,T,C) bf16, C index = h*64 + d
    const int b = bh >> 4, h = bh & 15;
#pragma unroll
    for (int r = 0; r < 4; ++r) {
        int gq = qb + wave * 16 + quad * 4 + r;
        float inv = 1.0f / l_r[r];
        size_t ybase = ((size_t)(b * 2048 + gq)) * 1024 + h * 64;
        Y[ybase + 0  + ln] = f2bf(o0[r] * inv);
        Y[ybase + 16 + ln] = f2bf(o1[r] * inv);
        Y[ybase + 32 + ln] = f2bf(o2[r] * inv);
        Y[ybase + 48 + ln] = f2bf(o3[r] * inv);
    }
}

extern "C" void kernel_launch(void* const* d_in, const int* in_sizes, int n_in,
                              void* d_out, int out_size, void* d_ws, size_t ws_size,
                              hipStream_t stream) {
    const float* x      = (const float*)d_in[0];
    const float* fcos   = (const float*)d_in[1];
    const float* fsin   = (const float*)d_in[2];
    const float* w_attn = (const float*)d_in[3];
    const float* w_proj = (const float*)d_in[4];
    const float* qw     = (const float*)d_in[5];
    const float* kw     = (const float*)d_in[6];
    float* out = (float*)d_out;

    char* ws = (char*)d_ws;
    u16*   xb  = (u16*)(ws + 0);            //  8388608 B : x bf16 (4096x1024)
    u16*   wab = (u16*)(ws + 8388608);      //  6291456 B : w_attn bf16 (3072x1024)
    u16*   wpb = (u16*)(ws + 14680064);     //  2097152 B : w_proj bf16 (1024x1024)
    float* qkv = (float*)(ws + 16777216);   // 50331648 B : qkv fp32 (dead after normrope)
    u16*   yb  = (u16*)(ws + 16777216);     // aliases qkv region: y bf16 (4096x1024)
    u16*   qb  = (u16*)(ws + 67108864);     //  8388608 B : q bf16 (B,H,T,64)
    u16*   kb  = (u16*)(ws + 75497472);     //  8388608 B
    u16*   vb  = (u16*)(ws + 83886080);     //  8388608 B   (total 92274688 B)

    castbf<<<4096, 256, 0, stream>>>(x, xb, 1048576);
    castbf<<<3072, 256, 0, stream>>>(w_attn, wab, 786432);
    castbf<<<1024, 256, 0, stream>>>(w_proj, wpb, 262144);

    gemm128<<<dim3(24, 32), 256, 0, stream>>>(xb, wab, qkv, 4096, 3072, 1024);

    normrope_kernel<<<49152, 256, 0, stream>>>(qkv, fcos, fsin, qw, kw, qb, kb, vb);

    attn_kernel<<<dim3(32, 32), 256, 0, stream>>>(qb, kb, vb, yb);

    gemm128<<<dim3(8, 32), 256, 0, stream>>>(yb, wpb, out, 4096, 1024, 1024);
}

// Round 2
// 284.918 us; speedup vs baseline: 1.4126x; 1.4126x over previous
//
#include <hip/hip_runtime.h>

typedef unsigned short u16;
typedef unsigned int u32;
typedef __bf16 bf16x8 __attribute__((ext_vector_type(8)));
typedef float f32x4 __attribute__((ext_vector_type(4)));

__device__ __forceinline__ u16 f2bf(float f) {
    union { float f; u32 u; } v;
    v.f = f;
    u32 r = v.u + 0x7fffu + ((v.u >> 16) & 1u);
    return (u16)(r >> 16);
}

__device__ __forceinline__ void glds16(const void* g, void* l) {
    __builtin_amdgcn_global_load_lds(
        (__attribute__((address_space(1))) unsigned int*)(g),
        (__attribute__((address_space(3))) unsigned int*)(l), 16, 0, 0);
}

// ---------------- cast fp32 -> bf16, 4 elems/thread ----------------
__global__ void castbf(const float* __restrict__ in, u16* __restrict__ out, int n4) {
    int i = blockIdx.x * 256 + threadIdx.x;
    if (i >= n4) return;
    float4 v = ((const float4*)in)[i];
    ushort4 o;
    o.x = f2bf(v.x); o.y = f2bf(v.y); o.z = f2bf(v.z); o.w = f2bf(v.w);
    ((ushort4*)out)[i] = o;
}

// ---------------- 128x128 bf16 GEMM, C = A * B^T, fp32 out ----------------
__global__ __launch_bounds__(256) void gemm128(
    const u16* __restrict__ A, const u16* __restrict__ B,
    float* __restrict__ C, int M, int N, int K)
{
    __shared__ alignas(16) u16 As[128 * 32];
    __shared__ alignas(16) u16 Bs[128 * 32];
    const int tid = threadIdx.x;
    const int lane = tid & 63;
    const int wave = tid >> 6;
    const int bm = blockIdx.y * 128, bn = blockIdx.x * 128;
    const int wm = (wave >> 1) * 64, wn = (wave & 1) * 64;
    const int ln = lane & 15, quad = lane >> 4;

    f32x4 acc[4][4] = {};

    const int srow = tid >> 2;
    const int scol = (tid & 3) * 8;
    const u16* gA = A + (size_t)(bm + srow) * K + scol;
    const u16* gB = B + (size_t)(bn + srow) * K + scol;
    u16* lA = &As[wave * 512];
    u16* lB = &Bs[wave * 512];

    for (int k0 = 0; k0 < K; k0 += 32) {
        glds16(gA + k0, lA);
        glds16(gA + (size_t)64 * K + k0, lA + 2048);
        glds16(gB + k0, lB);
        glds16(gB + (size_t)64 * K + k0, lB + 2048);
        __builtin_amdgcn_s_waitcnt(0);
        __syncthreads();

        bf16x8 af[4], bfr[4];
#pragma unroll
        for (int i = 0; i < 4; ++i)
            af[i] = *(const bf16x8*)&As[(wm + i * 16 + ln) * 32 + quad * 8];
#pragma unroll
        for (int j = 0; j < 4; ++j)
            bfr[j] = *(const bf16x8*)&Bs[(wn + j * 16 + ln) * 32 + quad * 8];
#pragma unroll
        for (int i = 0; i < 4; ++i)
#pragma unroll
            for (int j = 0; j < 4; ++j)
                acc[i][j] = __builtin_amdgcn_mfma_f32_16x16x32_bf16(af[i], bfr[j], acc[i][j], 0, 0, 0);
        __syncthreads();
    }

#pragma unroll
    for (int i = 0; i < 4; ++i) {
#pragma unroll
        for (int r = 0; r < 4; ++r) {
            int gm = bm + wm + i * 16 + quad * 4 + r;
            float* Crow = C + (size_t)gm * N + bn + wn + ln;
#pragma unroll
            for (int j = 0; j < 4; ++j)
                Crow[j * 16] = acc[i][j][r];
        }
    }
}

// ---------------- fused RMSNorm + RoPE for q,k only ----------------
// q out: (B,H,T,64) linear.  k out: (B,H,T,64) with 16B-chunk XOR swizzle by (t&7).
__global__ void normrope_kernel(
    const float* __restrict__ qkv, const float* __restrict__ fcos,
    const float* __restrict__ fsin, const float* __restrict__ qw,
    const float* __restrict__ kw,
    u16* __restrict__ q, u16* __restrict__ k)
{
    int gw = blockIdx.x * 4 + (threadIdx.x >> 6);   // (b,t,which01,h)
    int lane = threadIdx.x & 63;
    int h = gw & 15;
    int rest = gw >> 4;
    int which = rest & 1;
    int bt = rest >> 1;          // b*2048 + t
    int t = bt & 2047;
    int b = bt >> 11;

    float xv = qkv[((size_t)(bt * 3 + which) * 16 + h) * 64 + lane];
    float ss = xv * xv;
#pragma unroll
    for (int m = 32; m; m >>= 1) ss += __shfl_xor(ss, m);
    float xn = xv * rsqrtf(ss * (1.0f / 64.0f) + 1e-6f) * ((which == 0) ? qw[lane] : kw[lane]);
    float other = __shfl_xor(xn, 1);
    float c = fcos[t * 32 + (lane >> 1)];
    float s = fsin[t * 32 + (lane >> 1)];
    float res = (lane & 1) ? fmaf(other, s, xn * c) : fmaf(xn, c, -(other * s));

    size_t rowbase = ((size_t)((b * 16 + h) * 2048 + t)) * 64;
    if (which == 0) {
        q[rowbase + lane] = f2bf(res);
    } else {
        int dsw = ((((lane >> 3) ^ (t & 7)) << 3)) | (lane & 7);
        k[rowbase + dsw] = f2bf(res);
    }
}

// ---------------- V transpose: qkv fp32 v-slice -> vt (B,H,64,2048) bf16, swizzled ----------------
__global__ __launch_bounds__(256) void vtrans_kernel(const float* __restrict__ qkv,
                                                     u16* __restrict__ vt)
{
    __shared__ float Ls[64 * 72];
    const int tid = threadIdx.x;
    const int tt = blockIdx.x;     // t tile 0..31
    const int bh = blockIdx.y;     // 0..31
    const int t0 = tt * 64;
    const int b = bh >> 4, h = bh & 15;

    // read 64 t-rows x 64 f32 (each thread: one row-quarter = 16 floats)
    int row = tid >> 2, cq = tid & 3;
    size_t off = ((size_t)((b * 2048 + t0 + row) * 3 + 2) * 16 + h) * 64 + cq * 16;
#pragma unroll
    for (int i = 0; i < 4; ++i)
        *(float4*)&Ls[row * 72 + cq * 16 + i * 4] = *(const float4*)&qkv[off + i * 4];
    __syncthreads();

    // write: thread d = tid>>2, chunks ct = (tid&3)*2 + i; 8 t per chunk
    int d = tid >> 2;
#pragma unroll
    for (int i = 0; i < 2; ++i) {
        int ct = (tid & 3) * 2 + i;
        u32 w[4];
#pragma unroll
        for (int p = 0; p < 4; ++p) {
            u16 lo = f2bf(Ls[(ct * 8 + 2 * p) * 72 + d]);
            u16 hi = f2bf(Ls[(ct * 8 + 2 * p + 1) * 72 + d]);
            w[p] = (u32)lo | ((u32)hi << 16);
        }
        size_t dst = ((size_t)(bh * 64 + d)) * 2048 + t0 + ((ct ^ (d & 7)) << 3);
        uint4 pk; pk.x = w[0]; pk.y = w[1]; pk.z = w[2]; pk.w = w[3];
        *(uint4*)&vt[dst] = pk;
    }
}

// ---------------- flash attention (causal), S^T formulation ----------------
// Q: (B*H,2048,64) linear. K: (B*H,2048,64) chunk-swizzled. VT: (B*H,64,2048) chunk-swizzled.
// Y: (B,2048,1024) bf16.
__global__ __launch_bounds__(256) void attn_kernel(
    const u16* __restrict__ Q, const u16* __restrict__ K,
    const u16* __restrict__ VT, u16* __restrict__ Y)
{
    __shared__ alignas(16) u16 Ks[2][64 * 64];
    __shared__ alignas(16) u16 Vs[2][64 * 64];
    __shared__ alignas(16) u16 Ps[4][16 * 80];   // per-wave P, [q=16][kv stride 80]

    const int tid = threadIdx.x;
    const int lane = tid & 63;
    const int wave = tid >> 6;
    const int ln = lane & 15, quad = lane >> 4;
    const int qt = 31 - blockIdx.x;          // heavy blocks dispatch first
    const int bh = blockIdx.y;
    const int qb = qt * 64;
    const size_t base = (size_t)bh * 2048 * 64;
    const u16* Kg = K + base;
    const u16* Vg = VT + base;               // same total offset: bh*64*2048

    // Q B-operand fragments (q row = ln)
    const int qrow = qb + wave * 16 + ln;
    bf16x8 qf0 = *(const bf16x8*)&Q[base + (size_t)qrow * 64 + quad * 8];
    bf16x8 qf1 = *(const bf16x8*)&Q[base + (size_t)qrow * 64 + 32 + quad * 8];

    f32x4 o[4] = {};
    float m = -1e30f, l = 0.0f;
    const int ntiles = qb / 64 + 1;
    const int sw = ln & 7;
    const float SC = 0.18033688011112042f;   // 0.125 * log2(e)

    const int srow = wave * 16 + (lane >> 3);
    const int scol = (lane & 7) * 8;

    // prologue: stage tile 0 into buf 0
    glds16(&Kg[(size_t)(0 + srow) * 64 + scol],       &Ks[0][wave * 1024]);
    glds16(&Kg[(size_t)(0 + srow + 8) * 64 + scol],   &Ks[0][wave * 1024 + 512]);
    glds16(&Vg[(size_t)srow * 2048 + 0 + scol],       &Vs[0][wave * 1024]);
    glds16(&Vg[(size_t)(srow + 8) * 2048 + 0 + scol], &Vs[0][wave * 1024 + 512]);

    for (int jt = 0; jt < ntiles; ++jt) {
        const int jb = jt * 64;
        const int jbn = (jt + 1 < ntiles) ? (jt + 1) * 64 : 0;
        const int nb = (jt + 1) & 1;
        // prefetch next tile (dummy tile 0 on last iter; other buffer, harmless)
        glds16(&Kg[(size_t)(jbn + srow) * 64 + scol],       &Ks[nb][wave * 1024]);
        glds16(&Kg[(size_t)(jbn + srow + 8) * 64 + scol],   &Ks[nb][wave * 1024 + 512]);
        glds16(&Vg[(size_t)srow * 2048 + jbn + scol],       &Vs[nb][wave * 1024]);
        glds16(&Vg[(size_t)(srow + 8) * 2048 + jbn + scol], &Vs[nb][wave * 1024 + 512]);

        // wait for CURRENT tile only (4 newest still outstanding), then barrier
        asm volatile("s_waitcnt vmcnt(4)\n\ts_barrier" ::: "memory");

        const u16* ksb = &Ks[jt & 1][0];
        const u16* vsb = &Vs[jt & 1][0];

        // S^T = K * Q^T : rows kv, cols q
        f32x4 st[4];
#pragma unroll
        for (int ct = 0; ct < 4; ++ct) {
            bf16x8 kf0 = *(const bf16x8*)&ksb[(ct * 16 + ln) * 64 + ((0 + quad) ^ sw) * 8];
            bf16x8 kf1 = *(const bf16x8*)&ksb[(ct * 16 + ln) * 64 + ((4 + quad) ^ sw) * 8];
            f32x4 z = {};
            z = __builtin_amdgcn_mfma_f32_16x16x32_bf16(kf0, qf0, z, 0, 0, 0);
            st[ct] = __builtin_amdgcn_mfma_f32_16x16x32_bf16(kf1, qf1, z, 0, 0, 0);
        }

        // scale + causal mask (only last tile needs masking)
        if (jt == ntiles - 1) {
            const int qg = qb + wave * 16 + ln;
#pragma unroll
            for (int ct = 0; ct < 4; ++ct)
#pragma unroll
                for (int r = 0; r < 4; ++r) {
                    int kvg = jb + ct * 16 + quad * 4 + r;
                    st[ct][r] = (kvg > qg) ? -1e30f : st[ct][r] * SC;
                }
        } else {
#pragma unroll
            for (int ct = 0; ct < 4; ++ct)
#pragma unroll
                for (int r = 0; r < 4; ++r) st[ct][r] *= SC;
        }

        // per-lane max over 16 values, then cross-quad (q = ln)
        float tmax = st[0][0];
#pragma unroll
        for (int ct = 0; ct < 4; ++ct)
#pragma unroll
            for (int r = 0; r < 4; ++r) tmax = fmaxf(tmax, st[ct][r]);
        tmax = fmaxf(tmax, __shfl_xor(tmax, 16));
        tmax = fmaxf(tmax, __shfl_xor(tmax, 32));

        float mnew = fmaxf(m, tmax);
        float alpha = exp2f(m - mnew);
        m = mnew;

        float sum = 0.0f;
#pragma unroll
        for (int ct = 0; ct < 4; ++ct) {
            float e0 = exp2f(st[ct][0] - mnew);
            float e1 = exp2f(st[ct][1] - mnew);
            float e2 = exp2f(st[ct][2] - mnew);
            float e3 = exp2f(st[ct][3] - mnew);
            sum += (e0 + e1) + (e2 + e3);
            ushort4 pk;
            pk.x = f2bf(e0); pk.y = f2bf(e1); pk.z = f2bf(e2); pk.w = f2bf(e3);
            *(ushort4*)&Ps[wave][ln * 80 + ct * 16 + quad * 4] = pk;
        }
        sum += __shfl_xor(sum, 16);
        sum += __shfl_xor(sum, 32);
        l = l * alpha + sum;

        // fetch alpha for the q-rows this lane's O accumulator holds (q = quad*4+r)
        float ar[4];
#pragma unroll
        for (int r = 0; r < 4; ++r)
            ar[r] = __shfl(alpha, (lane & 48) + quad * 4 + r);
#pragma unroll
        for (int dt = 0; dt < 4; ++dt)
#pragma unroll
            for (int r = 0; r < 4; ++r) o[dt][r] *= ar[r];

        // P (A-operand) from Ps; wait for our own LDS writes
        __builtin_amdgcn_s_waitcnt(0xC07F);  // lgkmcnt(0)
        bf16x8 pf0 = *(const bf16x8*)&Ps[wave][ln * 80 + quad * 8];
        bf16x8 pf1 = *(const bf16x8*)&Ps[wave][ln * 80 + 32 + quad * 8];

#pragma unroll
        for (int dt = 0; dt < 4; ++dt) {
            bf16x8 vf0 = *(const bf16x8*)&vsb[(dt * 16 + ln) * 64 + ((0 + quad) ^ sw) * 8];
            bf16x8 vf1 = *(const bf16x8*)&vsb[(dt * 16 + ln) * 64 + ((4 + quad) ^ sw) * 8];
            o[dt] = __builtin_amdgcn_mfma_f32_16x16x32_bf16(pf0, vf0, o[dt], 0, 0, 0);
            o[dt] = __builtin_amdgcn_mfma_f32_16x16x32_bf16(pf1, vf1, o[dt], 0, 0, 0);
        }

        // all waves done reading this buffer before anyone's next prefetch lands
        asm volatile("s_waitcnt lgkmcnt(0)\n\ts_barrier" ::: "memory");
    }

    // epilogue: O rows q=quad*4+r, cols d=dt*16+ln ; l lives at lane with ln=q
    const int b = bh >> 4, h = bh & 15;
#pragma unroll
    for (int r = 0; r < 4; ++r) {
        float lr = __shfl(l, (lane & 48) + quad * 4 + r);
        float inv = 1.0f / lr;
        int gq = qb + wave * 16 + quad * 4 + r;
        size_t ybase = ((size_t)(b * 2048 + gq)) * 1024 + h * 64 + ln;
#pragma unroll
        for (int dt = 0; dt < 4; ++dt)
            Y[ybase + dt * 16] = f2bf(o[dt][r] * inv);
    }
}

extern "C" void kernel_launch(void* const* d_in, const int* in_sizes, int n_in,
                              void* d_out, int out_size, void* d_ws, size_t ws_size,
                              hipStream_t stream) {
    const float* x      = (const float*)d_in[0];
    const float* fcos   = (const float*)d_in[1];
    const float* fsin   = (const float*)d_in[2];
    const float* w_attn = (const float*)d_in[3];
    const float* w_proj = (const float*)d_in[4];
    const float* qw     = (const float*)d_in[5];
    const float* kw     = (const float*)d_in[6];
    float* out = (float*)d_out;

    char* ws = (char*)d_ws;
    u16*   xb  = (u16*)(ws + 0);            //  8 MB  x bf16
    u16*   wab = (u16*)(ws + 8388608);      //  6 MB  w_attn bf16
    u16*   wpb = (u16*)(ws + 14680064);     //  2 MB  w_proj bf16
    float* qkv = (float*)(ws + 16777216);   // 48 MB  qkv fp32
    u16*   yb  = (u16*)(ws + 16777216);     //  aliases qkv (dead after vtrans): y bf16
    u16*   qb  = (u16*)(ws + 67108864);     //  8 MB  q bf16 (B,H,T,64)
    u16*   kb  = (u16*)(ws + 75497472);     //  8 MB  k bf16 (B,H,T,64) swizzled
    u16*   vtb = (u16*)(ws + 83886080);     //  8 MB  v^T bf16 (B,H,64,T) swizzled

    castbf<<<4096, 256, 0, stream>>>(x, xb, 1048576);
    castbf<<<3072, 256, 0, stream>>>(w_attn, wab, 786432);
    castbf<<<1024, 256, 0, stream>>>(w_proj, wpb, 262144);

    gemm128<<<dim3(24, 32), 256, 0, stream>>>(xb, wab, qkv, 4096, 3072, 1024);

    normrope_kernel<<<32768, 256, 0, stream>>>(qkv, fcos, fsin, qw, kw, qb, kb);
    vtrans_kernel<<<dim3(32, 32), 256, 0, stream>>>(qkv, vtb);

    attn_kernel<<<dim3(32, 32), 256, 0, stream>>>(qb, kb, vtb, yb);

    gemm128<<<dim3(8, 32), 256, 0, stream>>>(yb, wpb, out, 4096, 1024, 1024);
}

// Round 3
// 243.074 us; speedup vs baseline: 1.6558x; 1.1721x over previous
//
#include <hip/hip_runtime.h>

typedef unsigned short u16;
typedef unsigned int u32;
typedef __bf16 bf16x8 __attribute__((ext_vector_type(8)));
typedef float f32x4 __attribute__((ext_vector_type(4)));

__device__ __forceinline__ u16 f2bf(float f) {
    union { float f; u32 u; } v;
    v.f = f;
    u32 r = v.u + 0x7fffu + ((v.u >> 16) & 1u);
    return (u16)(r >> 16);
}

__device__ __forceinline__ void glds16(const void* g, void* l) {
    __builtin_amdgcn_global_load_lds(
        (__attribute__((address_space(1))) unsigned int*)(g),
        (__attribute__((address_space(3))) unsigned int*)(l), 16, 0, 0);
}

// ---------------- fused cast fp32 -> bf16 for x, w_attn, w_proj ----------------
__global__ void castbf3(const float* __restrict__ a, u16* __restrict__ oa,
                        const float* __restrict__ b, u16* __restrict__ ob,
                        const float* __restrict__ c, u16* __restrict__ oc) {
    int blk = blockIdx.x;
    const float* in; u16* out; int i;
    if (blk < 4096)      { in = a; out = oa; i = blk * 256 + threadIdx.x; }
    else if (blk < 7168) { in = b; out = ob; i = (blk - 4096) * 256 + threadIdx.x; }
    else                 { in = c; out = oc; i = (blk - 7168) * 256 + threadIdx.x; }
    float4 v = ((const float4*)in)[i];
    ushort4 o;
    o.x = f2bf(v.x); o.y = f2bf(v.y); o.z = f2bf(v.z); o.w = f2bf(v.w);
    ((ushort4*)out)[i] = o;
}

// ---------------- 128x128 bf16 GEMM, C = A * B^T, fp32 out ----------------
__global__ __launch_bounds__(256) void gemm128(
    const u16* __restrict__ A, const u16* __restrict__ B,
    float* __restrict__ C, int M, int N, int K)
{
    __shared__ alignas(16) u16 As[128 * 32];
    __shared__ alignas(16) u16 Bs[128 * 32];
    const int tid = threadIdx.x;
    const int lane = tid & 63;
    const int wave = tid >> 6;
    const int bm = blockIdx.y * 128, bn = blockIdx.x * 128;
    const int wm = (wave >> 1) * 64, wn = (wave & 1) * 64;
    const int ln = lane & 15, quad = lane >> 4;

    f32x4 acc[4][4] = {};

    const int srow = tid >> 2;
    const int scol = (tid & 3) * 8;
    const u16* gA = A + (size_t)(bm + srow) * K + scol;
    const u16* gB = B + (size_t)(bn + srow) * K + scol;
    u16* lA = &As[wave * 512];
    u16* lB = &Bs[wave * 512];

    for (int k0 = 0; k0 < K; k0 += 32) {
        glds16(gA + k0, lA);
        glds16(gA + (size_t)64 * K + k0, lA + 2048);
        glds16(gB + k0, lB);
        glds16(gB + (size_t)64 * K + k0, lB + 2048);
        __builtin_amdgcn_s_waitcnt(0);
        __syncthreads();

        bf16x8 af[4], bfr[4];
#pragma unroll
        for (int i = 0; i < 4; ++i)
            af[i] = *(const bf16x8*)&As[(wm + i * 16 + ln) * 32 + quad * 8];
#pragma unroll
        for (int j = 0; j < 4; ++j)
            bfr[j] = *(const bf16x8*)&Bs[(wn + j * 16 + ln) * 32 + quad * 8];
#pragma unroll
        for (int i = 0; i < 4; ++i)
#pragma unroll
            for (int j = 0; j < 4; ++j)
                acc[i][j] = __builtin_amdgcn_mfma_f32_16x16x32_bf16(af[i], bfr[j], acc[i][j], 0, 0, 0);
        __syncthreads();
    }

#pragma unroll
    for (int i = 0; i < 4; ++i) {
#pragma unroll
        for (int r = 0; r < 4; ++r) {
            int gm = bm + wm + i * 16 + quad * 4 + r;
            float* Crow = C + (size_t)gm * N + bn + wn + ln;
#pragma unroll
            for (int j = 0; j < 4; ++j)
                Crow[j * 16] = acc[i][j][r];
        }
    }
}

// ---------------- fused RMSNorm + RoPE for q,k only ----------------
__global__ void normrope_kernel(
    const float* __restrict__ qkv, const float* __restrict__ fcos,
    const float* __restrict__ fsin, const float* __restrict__ qw,
    const float* __restrict__ kw,
    u16* __restrict__ q, u16* __restrict__ k)
{
    int gw = blockIdx.x * 4 + (threadIdx.x >> 6);   // (b,t,which01,h)
    int lane = threadIdx.x & 63;
    int h = gw & 15;
    int rest = gw >> 4;
    int which = rest & 1;
    int bt = rest >> 1;          // b*2048 + t
    int t = bt & 2047;
    int b = bt >> 11;

    float xv = qkv[((size_t)(bt * 3 + which) * 16 + h) * 64 + lane];
    float ss = xv * xv;
#pragma unroll
    for (int m = 32; m; m >>= 1) ss += __shfl_xor(ss, m);
    float xn = xv * rsqrtf(ss * (1.0f / 64.0f) + 1e-6f) * ((which == 0) ? qw[lane] : kw[lane]);
    float other = __shfl_xor(xn, 1);
    float c = fcos[t * 32 + (lane >> 1)];
    float s = fsin[t * 32 + (lane >> 1)];
    float res = (lane & 1) ? fmaf(other, s, xn * c) : fmaf(xn, c, -(other * s));

    size_t rowbase = ((size_t)((b * 16 + h) * 2048 + t)) * 64;
    if (which == 0) {
        q[rowbase + lane] = f2bf(res);
    } else {
        int dsw = ((((lane >> 3) ^ (t & 7)) << 3)) | (lane & 7);
        k[rowbase + dsw] = f2bf(res);
    }
}

// ---------------- V transpose: qkv fp32 v-slice -> vt (B,H,64,2048) bf16, swizzled ----------------
__global__ __launch_bounds__(256) void vtrans_kernel(const float* __restrict__ qkv,
                                                     u16* __restrict__ vt)
{
    __shared__ float Ls[64 * 72];
    const int tid = threadIdx.x;
    const int tt = blockIdx.x;     // t tile 0..31
    const int bh = blockIdx.y;     // 0..31
    const int t0 = tt * 64;
    const int b = bh >> 4, h = bh & 15;

    int row = tid >> 2, cq = tid & 3;
    size_t off = ((size_t)((b * 2048 + t0 + row) * 3 + 2) * 16 + h) * 64 + cq * 16;
#pragma unroll
    for (int i = 0; i < 4; ++i)
        *(float4*)&Ls[row * 72 + cq * 16 + i * 4] = *(const float4*)&qkv[off + i * 4];
    __syncthreads();

    int d = tid >> 2;
#pragma unroll
    for (int i = 0; i < 2; ++i) {
        int ct = (tid & 3) * 2 + i;
        u32 w[4];
#pragma unroll
        for (int p = 0; p < 4; ++p) {
            u16 lo = f2bf(Ls[(ct * 8 + 2 * p) * 72 + d]);
            u16 hi = f2bf(Ls[(ct * 8 + 2 * p + 1) * 72 + d]);
            w[p] = (u32)lo | ((u32)hi << 16);
        }
        size_t dst = ((size_t)(bh * 64 + d)) * 2048 + t0 + ((ct ^ (d & 7)) << 3);
        uint4 pk; pk.x = w[0]; pk.y = w[1]; pk.z = w[2]; pk.w = w[3];
        *(uint4*)&vt[dst] = pk;
    }
}

// ---------------- flash attention (causal), S^T formulation, paired q-tiles ----------------
// Block pi handles q-tiles A=pi and B=31-pi; B processes every kv stage, A joins for jt<=pi.
// Every block does exactly 33 tile-iterations of work -> perfect balance.
__global__ __launch_bounds__(256) void attn_kernel(
    const u16* __restrict__ Q, const u16* __restrict__ K,
    const u16* __restrict__ VT, u16* __restrict__ Y)
{
    __shared__ alignas(16) u16 Ks[2][64 * 64];
    __shared__ alignas(16) u16 Vs[2][64 * 64];
    __shared__ alignas(16) u16 Ps[4][16 * 80];

    const int tid = threadIdx.x;
    const int lane = tid & 63;
    const int wave = tid >> 6;
    const int ln = lane & 15, quad = lane >> 4;
    const int pi = blockIdx.x;           // 0..15
    const int bh = blockIdx.y;
    const int qaIdx = pi, qbIdx = 31 - pi;
    const int qA = qaIdx * 64, qB = qbIdx * 64;
    const size_t base = (size_t)bh * 2048 * 64;
    const u16* Kg = K + base;
    const u16* Vg = VT + base;

    const int qrowA = qA + wave * 16 + ln;
    bf16x8 qfA0 = *(const bf16x8*)&Q[base + (size_t)qrowA * 64 + quad * 8];
    bf16x8 qfA1 = *(const bf16x8*)&Q[base + (size_t)qrowA * 64 + 32 + quad * 8];
    const int qrowB = qB + wave * 16 + ln;
    bf16x8 qfB0 = *(const bf16x8*)&Q[base + (size_t)qrowB * 64 + quad * 8];
    bf16x8 qfB1 = *(const bf16x8*)&Q[base + (size_t)qrowB * 64 + 32 + quad * 8];

    f32x4 oA[4] = {}, oB[4] = {};
    float mA = -1e30f, lA = 0.0f, mB = -1e30f, lB = 0.0f;
    const int nstages = qbIdx + 1;
    const int sw = ln & 7;
    const float SC = 0.18033688011112042f;   // 0.125 * log2(e)

    const int srow = wave * 16 + (lane >> 3);
    const int scol = (lane & 7) * 8;

    // one q-tile's full update against the staged 64-kv tile
    auto process = [&](const bf16x8& qf0, const bf16x8& qf1, float& m, float& l,
                       f32x4* o, const u16* ksb, const u16* vsb, bool domask,
                       int jb, int qb0) {
        f32x4 st[4];
#pragma unroll
        for (int ct = 0; ct < 4; ++ct) {
            bf16x8 kf0 = *(const bf16x8*)&ksb[(ct * 16 + ln) * 64 + ((0 + quad) ^ sw) * 8];
            bf16x8 kf1 = *(const bf16x8*)&ksb[(ct * 16 + ln) * 64 + ((4 + quad) ^ sw) * 8];
            f32x4 z = {};
            z = __builtin_amdgcn_mfma_f32_16x16x32_bf16(kf0, qf0, z, 0, 0, 0);
            st[ct] = __builtin_amdgcn_mfma_f32_16x16x32_bf16(kf1, qf1, st[ct] = z, 0, 0, 0);
        }
        if (domask) {
            const int qg = qb0 + wave * 16 + ln;
#pragma unroll
            for (int ct = 0; ct < 4; ++ct)
#pragma unroll
                for (int r = 0; r < 4; ++r) {
                    int kvg = jb + ct * 16 + quad * 4 + r;
                    st[ct][r] = (kvg > qg) ? -1e30f : st[ct][r] * SC;
                }
        } else {
#pragma unroll
            for (int ct = 0; ct < 4; ++ct)
#pragma unroll
                for (int r = 0; r < 4; ++r) st[ct][r] *= SC;
        }

        float tmax = st[0][0];
#pragma unroll
        for (int ct = 0; ct < 4; ++ct)
#pragma unroll
            for (int r = 0; r < 4; ++r) tmax = fmaxf(tmax, st[ct][r]);
        tmax = fmaxf(tmax, __shfl_xor(tmax, 16));
        tmax = fmaxf(tmax, __shfl_xor(tmax, 32));

        float mnew = fmaxf(m, tmax);
        float alpha = exp2f(m - mnew);
        m = mnew;

        float sum = 0.0f;
#pragma unroll
        for (int ct = 0; ct < 4; ++ct) {
            float e0 = exp2f(st[ct][0] - mnew);
            float e1 = exp2f(st[ct][1] - mnew);
            float e2 = exp2f(st[ct][2] - mnew);
            float e3 = exp2f(st[ct][3] - mnew);
            sum += (e0 + e1) + (e2 + e3);
            ushort4 pk;
            pk.x = f2bf(e0); pk.y = f2bf(e1); pk.z = f2bf(e2); pk.w = f2bf(e3);
            *(ushort4*)&Ps[wave][ln * 80 + ct * 16 + quad * 4] = pk;
        }
        sum += __shfl_xor(sum, 16);
        sum += __shfl_xor(sum, 32);
        l = l * alpha + sum;

        float ar[4];
#pragma unroll
        for (int r = 0; r < 4; ++r)
            ar[r] = __shfl(alpha, (lane & 48) + quad * 4 + r);
#pragma unroll
        for (int dt = 0; dt < 4; ++dt)
#pragma unroll
            for (int r = 0; r < 4; ++r) o[dt][r] *= ar[r];

        __builtin_amdgcn_s_waitcnt(0xC07F);  // lgkmcnt(0): Ps visible
        bf16x8 pf0 = *(const bf16x8*)&Ps[wave][ln * 80 + quad * 8];
        bf16x8 pf1 = *(const bf16x8*)&Ps[wave][ln * 80 + 32 + quad * 8];

#pragma unroll
        for (int dt = 0; dt < 4; ++dt) {
            bf16x8 vf0 = *(const bf16x8*)&vsb[(dt * 16 + ln) * 64 + ((0 + quad) ^ sw) * 8];
            bf16x8 vf1 = *(const bf16x8*)&vsb[(dt * 16 + ln) * 64 + ((4 + quad) ^ sw) * 8];
            o[dt] = __builtin_amdgcn_mfma_f32_16x16x32_bf16(pf0, vf0, o[dt], 0, 0, 0);
            o[dt] = __builtin_amdgcn_mfma_f32_16x16x32_bf16(pf1, vf1, o[dt], 0, 0, 0);
        }
    };

    // prologue: stage tile 0 into buf 0
    glds16(&Kg[(size_t)(0 + srow) * 64 + scol],       &Ks[0][wave * 1024]);
    glds16(&Kg[(size_t)(0 + srow + 8) * 64 + scol],   &Ks[0][wave * 1024 + 512]);
    glds16(&Vg[(size_t)srow * 2048 + 0 + scol],       &Vs[0][wave * 1024]);
    glds16(&Vg[(size_t)(srow + 8) * 2048 + 0 + scol], &Vs[0][wave * 1024 + 512]);

    for (int jt = 0; jt < nstages; ++jt) {
        const int jb = jt * 64;
        const int jbn = (jt + 1 < nstages) ? (jt + 1) * 64 : 0;
        const int nb = (jt + 1) & 1;
        glds16(&Kg[(size_t)(jbn + srow) * 64 + scol],       &Ks[nb][wave * 1024]);
        glds16(&Kg[(size_t)(jbn + srow + 8) * 64 + scol],   &Ks[nb][wave * 1024 + 512]);
        glds16(&Vg[(size_t)srow * 2048 + jbn + scol],       &Vs[nb][wave * 1024]);
        glds16(&Vg[(size_t)(srow + 8) * 2048 + jbn + scol], &Vs[nb][wave * 1024 + 512]);

        asm volatile("s_waitcnt vmcnt(4)\n\ts_barrier" ::: "memory");

        const u16* ksb = &Ks[jt & 1][0];
        const u16* vsb = &Vs[jt & 1][0];

        if (jt <= qaIdx)
            process(qfA0, qfA1, mA, lA, oA, ksb, vsb, jt == qaIdx, jb, qA);
        process(qfB0, qfB1, mB, lB, oB, ksb, vsb, jt == qbIdx, jb, qB);

        asm volatile("s_waitcnt lgkmcnt(0)\n\ts_barrier" ::: "memory");
    }

    // epilogue
    const int b = bh >> 4, h = bh & 15;
#pragma unroll
    for (int r = 0; r < 4; ++r) {
        float lra = __shfl(lA, (lane & 48) + quad * 4 + r);
        float invA = 1.0f / lra;
        int gqA = qA + wave * 16 + quad * 4 + r;
        size_t ybA = ((size_t)(b * 2048 + gqA)) * 1024 + h * 64 + ln;
        float lrb = __shfl(lB, (lane & 48) + quad * 4 + r);
        float invB = 1.0f / lrb;
        int gqB = qB + wave * 16 + quad * 4 + r;
        size_t ybB = ((size_t)(b * 2048 + gqB)) * 1024 + h * 64 + ln;
#pragma unroll
        for (int dt = 0; dt < 4; ++dt) {
            Y[ybA + dt * 16] = f2bf(oA[dt][r] * invA);
            Y[ybB + dt * 16] = f2bf(oB[dt][r] * invB);
        }
    }
}

extern "C" void kernel_launch(void* const* d_in, const int* in_sizes, int n_in,
                              void* d_out, int out_size, void* d_ws, size_t ws_size,
                              hipStream_t stream) {
    const float* x      = (const float*)d_in[0];
    const float* fcos   = (const float*)d_in[1];
    const float* fsin   = (const float*)d_in[2];
    const float* w_attn = (const float*)d_in[3];
    const float* w_proj = (const float*)d_in[4];
    const float* qw     = (const float*)d_in[5];
    const float* kw     = (const float*)d_in[6];
    float* out = (float*)d_out;

    char* ws = (char*)d_ws;
    u16*   xb  = (u16*)(ws + 0);            //  8 MB  x bf16
    u16*   wab = (u16*)(ws + 8388608);      //  6 MB  w_attn bf16
    u16*   wpb = (u16*)(ws + 14680064);     //  2 MB  w_proj bf16
    float* qkv = (float*)(ws + 16777216);   // 48 MB  qkv fp32
    u16*   yb  = (u16*)(ws + 16777216);     //  aliases qkv (dead after vtrans): y bf16
    u16*   qb  = (u16*)(ws + 67108864);     //  8 MB  q bf16 (B,H,T,64)
    u16*   kb  = (u16*)(ws + 75497472);     //  8 MB  k bf16 swizzled
    u16*   vtb = (u16*)(ws + 83886080);     //  8 MB  v^T bf16 swizzled

    castbf3<<<8192, 256, 0, stream>>>(x, xb, w_attn, wab, w_proj, wpb);

    gemm128<<<dim3(24, 32), 256, 0, stream>>>(xb, wab, qkv, 4096, 3072, 1024);

    normrope_kernel<<<32768, 256, 0, stream>>>(qkv, fcos, fsin, qw, kw, qb, kb);
    vtrans_kernel<<<dim3(32, 32), 256, 0, stream>>>(qkv, vtb);

    attn_kernel<<<dim3(16, 32), 256, 0, stream>>>(qb, kb, vtb, yb);

    gemm128<<<dim3(8, 32), 256, 0, stream>>>(yb, wpb, out, 4096, 1024, 1024);
}

// Round 4
// 227.415 us; speedup vs baseline: 1.7698x; 1.0689x over previous
//
#include <hip/hip_runtime.h>

typedef unsigned short u16;
typedef unsigned int u32;
typedef __bf16 bf16x8 __attribute__((ext_vector_type(8)));
typedef float f32x4 __attribute__((ext_vector_type(4)));

__device__ __forceinline__ u16 f2bf(float f) {
    union { float f; u32 u; } v;
    v.f = f;
    u32 r = v.u + 0x7fffu + ((v.u >> 16) & 1u);
    return (u16)(r >> 16);
}

__device__ __forceinline__ u32 fbits(float f) {
    union { float f; u32 u; } v; v.f = f; return v.u;
}

__device__ __forceinline__ void glds16(const void* g, void* l) {
    __builtin_amdgcn_global_load_lds(
        (__attribute__((address_space(1))) unsigned int*)(g),
        (__attribute__((address_space(3))) unsigned int*)(l), 16, 0, 0);
}

// ---------------- fused cast fp32 -> bf16 for x, w_attn, w_proj ----------------
__global__ void castbf3(const float* __restrict__ a, u16* __restrict__ oa,
                        const float* __restrict__ b, u16* __restrict__ ob,
                        const float* __restrict__ c, u16* __restrict__ oc) {
    int blk = blockIdx.x;
    const float* in; u16* out; int i;
    if (blk < 4096)      { in = a; out = oa; i = blk * 256 + threadIdx.x; }
    else if (blk < 7168) { in = b; out = ob; i = (blk - 4096) * 256 + threadIdx.x; }
    else                 { in = c; out = oc; i = (blk - 7168) * 256 + threadIdx.x; }
    float4 v = ((const float4*)in)[i];
    ushort4 o;
    o.x = f2bf(v.x); o.y = f2bf(v.y); o.z = f2bf(v.z); o.w = f2bf(v.w);
    ((ushort4*)out)[i] = o;
}

// ---------------- 128x128 bf16 GEMM, C = A * B^T, fp32 out ----------------
__global__ __launch_bounds__(256) void gemm128(
    const u16* __restrict__ A, const u16* __restrict__ B,
    float* __restrict__ C, int M, int N, int K)
{
    __shared__ alignas(16) u16 As[128 * 32];
    __shared__ alignas(16) u16 Bs[128 * 32];
    const int tid = threadIdx.x;
    const int lane = tid & 63;
    const int wave = tid >> 6;
    const int bm = blockIdx.y * 128, bn = blockIdx.x * 128;
    const int wm = (wave >> 1) * 64, wn = (wave & 1) * 64;
    const int ln = lane & 15, quad = lane >> 4;

    f32x4 acc[4][4] = {};

    const int srow = tid >> 2;
    const int scol = (tid & 3) * 8;
    const u16* gA = A + (size_t)(bm + srow) * K + scol;
    const u16* gB = B + (size_t)(bn + srow) * K + scol;
    u16* lA = &As[wave * 512];
    u16* lB = &Bs[wave * 512];

    for (int k0 = 0; k0 < K; k0 += 32) {
        glds16(gA + k0, lA);
        glds16(gA + (size_t)64 * K + k0, lA + 2048);
        glds16(gB + k0, lB);
        glds16(gB + (size_t)64 * K + k0, lB + 2048);
        __builtin_amdgcn_s_waitcnt(0);
        __syncthreads();

        bf16x8 af[4], bfr[4];
#pragma unroll
        for (int i = 0; i < 4; ++i)
            af[i] = *(const bf16x8*)&As[(wm + i * 16 + ln) * 32 + quad * 8];
#pragma unroll
        for (int j = 0; j < 4; ++j)
            bfr[j] = *(const bf16x8*)&Bs[(wn + j * 16 + ln) * 32 + quad * 8];
#pragma unroll
        for (int i = 0; i < 4; ++i)
#pragma unroll
            for (int j = 0; j < 4; ++j)
                acc[i][j] = __builtin_amdgcn_mfma_f32_16x16x32_bf16(af[i], bfr[j], acc[i][j], 0, 0, 0);
        __syncthreads();
    }

#pragma unroll
    for (int i = 0; i < 4; ++i) {
#pragma unroll
        for (int r = 0; r < 4; ++r) {
            int gm = bm + wm + i * 16 + quad * 4 + r;
            float* Crow = C + (size_t)gm * N + bn + wn + ln;
#pragma unroll
            for (int j = 0; j < 4; ++j)
                Crow[j * 16] = acc[i][j][r];
        }
    }
}

// ---------------- fused RMSNorm+RoPE (q,k) + V transpose, one launch ----------------
// blocks [0, 32768): normrope rows.  blocks [32768, 33792): vtrans tiles.
// q out pre-scaled by 0.125*log2(e) so attention scores are in log2 units.
__global__ __launch_bounds__(256) void normvt_kernel(
    const float* __restrict__ qkv, const float* __restrict__ fcos,
    const float* __restrict__ fsin, const float* __restrict__ qw,
    const float* __restrict__ kw,
    u16* __restrict__ q, u16* __restrict__ k, u16* __restrict__ vt)
{
    __shared__ float Ls[64 * 72];
    const int tid = threadIdx.x;

    if (blockIdx.x < 32768) {
        int gw = blockIdx.x * 4 + (tid >> 6);   // (b,t,which01,h)
        int lane = tid & 63;
        int h = gw & 15;
        int rest = gw >> 4;
        int which = rest & 1;
        int bt = rest >> 1;          // b*2048 + t
        int t = bt & 2047;
        int b = bt >> 11;

        float xv = qkv[((size_t)(bt * 3 + which) * 16 + h) * 64 + lane];
        float ss = xv * xv;
#pragma unroll
        for (int m = 32; m; m >>= 1) ss += __shfl_xor(ss, m);
        float xn = xv * rsqrtf(ss * (1.0f / 64.0f) + 1e-6f) * ((which == 0) ? qw[lane] : kw[lane]);
        float other = __shfl_xor(xn, 1);
        float c = fcos[t * 32 + (lane >> 1)];
        float s = fsin[t * 32 + (lane >> 1)];
        float res = (lane & 1) ? fmaf(other, s, xn * c) : fmaf(xn, c, -(other * s));

        size_t rowbase = ((size_t)((b * 16 + h) * 2048 + t)) * 64;
        if (which == 0) {
            q[rowbase + lane] = f2bf(res * 0.18033688011112042f);  // 0.125*log2(e)
        } else {
            int dsw = ((((lane >> 3) ^ (t & 7)) << 3)) | (lane & 7);
            k[rowbase + dsw] = f2bf(res);
        }
        return;
    }

    // ---- vtrans part ----
    const int idx = blockIdx.x - 32768;
    const int tt = idx & 31;       // t tile
    const int bh = idx >> 5;       // 0..31
    const int t0 = tt * 64;
    const int b = bh >> 4, h = bh & 15;

    int row = tid >> 2, cq = tid & 3;
    size_t off = ((size_t)((b * 2048 + t0 + row) * 3 + 2) * 16 + h) * 64 + cq * 16;
#pragma unroll
    for (int i = 0; i < 4; ++i)
        *(float4*)&Ls[row * 72 + cq * 16 + i * 4] = *(const float4*)&qkv[off + i * 4];
    __syncthreads();

    int d = tid >> 2;
#pragma unroll
    for (int i = 0; i < 2; ++i) {
        int ct = (tid & 3) * 2 + i;
        u32 w[4];
#pragma unroll
        for (int p = 0; p < 4; ++p) {
            u16 lo = f2bf(Ls[(ct * 8 + 2 * p) * 72 + d]);
            u16 hi = f2bf(Ls[(ct * 8 + 2 * p + 1) * 72 + d]);
            w[p] = (u32)lo | ((u32)hi << 16);
        }
        size_t dst = ((size_t)(bh * 64 + d)) * 2048 + t0 + ((ct ^ (d & 7)) << 3);
        uint4 pk; pk.x = w[0]; pk.y = w[1]; pk.z = w[2]; pk.w = w[3];
        *(uint4*)&vt[dst] = pk;
    }
}

// ---------------- flash attention (causal), S^T form, paired q-tiles, NO online max ----------------
// Valid because q,k are RMS-normalized (|row|=8) and RoPE is a rotation:
// |score*scale| <= 8  ->  st (log2 units) <= 11.55, exp2(st) <= 2981, fp32 sums safe.
__global__ __launch_bounds__(256) void attn_kernel(
    const u16* __restrict__ Q, const u16* __restrict__ K,
    const u16* __restrict__ VT, u16* __restrict__ Y)
{
    __shared__ alignas(16) u16 Ks[2][64 * 64];
    __shared__ alignas(16) u16 Vs[2][64 * 64];
    __shared__ alignas(16) u16 Ps[4][16 * 80];

    const int tid = threadIdx.x;
    const int lane = tid & 63;
    const int wave = tid >> 6;
    const int ln = lane & 15, quad = lane >> 4;
    const int pi = blockIdx.x;           // 0..15
    const int bh = blockIdx.y;
    const int qaIdx = pi, qbIdx = 31 - pi;
    const int qA = qaIdx * 64, qB = qbIdx * 64;
    const size_t base = (size_t)bh * 2048 * 64;
    const u16* Kg = K + base;
    const u16* Vg = VT + base;

    const int qrowA = qA + wave * 16 + ln;
    bf16x8 qfA0 = *(const bf16x8*)&Q[base + (size_t)qrowA * 64 + quad * 8];
    bf16x8 qfA1 = *(const bf16x8*)&Q[base + (size_t)qrowA * 64 + 32 + quad * 8];
    const int qrowB = qB + wave * 16 + ln;
    bf16x8 qfB0 = *(const bf16x8*)&Q[base + (size_t)qrowB * 64 + quad * 8];
    bf16x8 qfB1 = *(const bf16x8*)&Q[base + (size_t)qrowB * 64 + 32 + quad * 8];

    f32x4 oA[4] = {}, oB[4] = {};
    float lA = 0.0f, lB = 0.0f;
    const int nstages = qbIdx + 1;
    const int sw = ln & 7;

    const int srow = wave * 16 + (lane >> 3);
    const int scol = (lane & 7) * 8;

    auto process = [&](const bf16x8& qf0, const bf16x8& qf1, float& l,
                       f32x4* o, const u16* ksb, const u16* vsb, bool domask,
                       int jb, int qb0) {
        f32x4 st[4];
#pragma unroll
        for (int ct = 0; ct < 4; ++ct) {
            bf16x8 kf0 = *(const bf16x8*)&ksb[(ct * 16 + ln) * 64 + ((0 + quad) ^ sw) * 8];
            bf16x8 kf1 = *(const bf16x8*)&ksb[(ct * 16 + ln) * 64 + ((4 + quad) ^ sw) * 8];
            f32x4 z = {};
            z = __builtin_amdgcn_mfma_f32_16x16x32_bf16(kf0, qf0, z, 0, 0, 0);
            st[ct] = __builtin_amdgcn_mfma_f32_16x16x32_bf16(kf1, qf1, z, 0, 0, 0);
        }
        if (domask) {
            const int qg = qb0 + wave * 16 + ln;
#pragma unroll
            for (int ct = 0; ct < 4; ++ct)
#pragma unroll
                for (int r = 0; r < 4; ++r) {
                    int kvg = jb + ct * 16 + quad * 4 + r;
                    if (kvg > qg) st[ct][r] = -1e30f;
                }
        }

        float sum = 0.0f;
#pragma unroll
        for (int ct = 0; ct < 4; ++ct) {
            float e0 = exp2f(st[ct][0]);
            float e1 = exp2f(st[ct][1]);
            float e2 = exp2f(st[ct][2]);
            float e3 = exp2f(st[ct][3]);
            sum += (e0 + e1) + (e2 + e3);
            // truncate-pack two f32 -> bf16x2 with one v_perm each
            uint2 pk;
            pk.x = __builtin_amdgcn_perm(fbits(e1), fbits(e0), 0x07060302u);
            pk.y = __builtin_amdgcn_perm(fbits(e3), fbits(e2), 0x07060302u);
            *(uint2*)&Ps[wave][ln * 80 + ct * 16 + quad * 4] = pk;
        }
        sum += __shfl_xor(sum, 16);
        sum += __shfl_xor(sum, 32);
        l += sum;

        __builtin_amdgcn_s_waitcnt(0xC07F);  // lgkmcnt(0): Ps visible
        bf16x8 pf0 = *(const bf16x8*)&Ps[wave][ln * 80 + quad * 8];
        bf16x8 pf1 = *(const bf16x8*)&Ps[wave][ln * 80 + 32 + quad * 8];

#pragma unroll
        for (int dt = 0; dt < 4; ++dt) {
            bf16x8 vf0 = *(const bf16x8*)&vsb[(dt * 16 + ln) * 64 + ((0 + quad) ^ sw) * 8];
            bf16x8 vf1 = *(const bf16x8*)&vsb[(dt * 16 + ln) * 64 + ((4 + quad) ^ sw) * 8];
            o[dt] = __builtin_amdgcn_mfma_f32_16x16x32_bf16(pf0, vf0, o[dt], 0, 0, 0);
            o[dt] = __builtin_amdgcn_mfma_f32_16x16x32_bf16(pf1, vf1, o[dt], 0, 0, 0);
        }
    };

    // prologue: stage tile 0 into buf 0
    glds16(&Kg[(size_t)(0 + srow) * 64 + scol],       &Ks[0][wave * 1024]);
    glds16(&Kg[(size_t)(0 + srow + 8) * 64 + scol],   &Ks[0][wave * 1024 + 512]);
    glds16(&Vg[(size_t)srow * 2048 + 0 + scol],       &Vs[0][wave * 1024]);
    glds16(&Vg[(size_t)(srow + 8) * 2048 + 0 + scol], &Vs[0][wave * 1024 + 512]);

    for (int jt = 0; jt < nstages; ++jt) {
        const int jb = jt * 64;
        const int jbn = (jt + 1 < nstages) ? (jt + 1) * 64 : 0;
        const int nb = (jt + 1) & 1;
        glds16(&Kg[(size_t)(jbn + srow) * 64 + scol],       &Ks[nb][wave * 1024]);
        glds16(&Kg[(size_t)(jbn + srow + 8) * 64 + scol],   &Ks[nb][wave * 1024 + 512]);
        glds16(&Vg[(size_t)srow * 2048 + jbn + scol],       &Vs[nb][wave * 1024]);
        glds16(&Vg[(size_t)(srow + 8) * 2048 + jbn + scol], &Vs[nb][wave * 1024 + 512]);

        asm volatile("s_waitcnt vmcnt(4)\n\ts_barrier" ::: "memory");

        const u16* ksb = &Ks[jt & 1][0];
        const u16* vsb = &Vs[jt & 1][0];

        if (jt <= qaIdx)
            process(qfA0, qfA1, lA, oA, ksb, vsb, jt == qaIdx, jb, qA);
        process(qfB0, qfB1, lB, oB, ksb, vsb, jt == qbIdx, jb, qB);

        asm volatile("s_waitcnt lgkmcnt(0)\n\ts_barrier" ::: "memory");
    }

    // epilogue
    const int b = bh >> 4, h = bh & 15;
#pragma unroll
    for (int r = 0; r < 4; ++r) {
        float lra = __shfl(lA, (lane & 48) + quad * 4 + r);
        float invA = 1.0f / lra;
        int gqA = qA + wave * 16 + quad * 4 + r;
        size_t ybA = ((size_t)(b * 2048 + gqA)) * 1024 + h * 64 + ln;
        float lrb = __shfl(lB, (lane & 48) + quad * 4 + r);
        float invB = 1.0f / lrb;
        int gqB = qB + wave * 16 + quad * 4 + r;
        size_t ybB = ((size_t)(b * 2048 + gqB)) * 1024 + h * 64 + ln;
#pragma unroll
        for (int dt = 0; dt < 4; ++dt) {
            Y[ybA + dt * 16] = f2bf(oA[dt][r] * invA);
            Y[ybB + dt * 16] = f2bf(oB[dt][r] * invB);
        }
    }
}

extern "C" void kernel_launch(void* const* d_in, const int* in_sizes, int n_in,
                              void* d_out, int out_size, void* d_ws, size_t ws_size,
                              hipStream_t stream) {
    const float* x      = (const float*)d_in[0];
    const float* fcos   = (const float*)d_in[1];
    const float* fsin   = (const float*)d_in[2];
    const float* w_attn = (const float*)d_in[3];
    const float* w_proj = (const float*)d_in[4];
    const float* qw     = (const float*)d_in[5];
    const float* kw     = (const float*)d_in[6];
    float* out = (float*)d_out;

    char* ws = (char*)d_ws;
    u16*   xb  = (u16*)(ws + 0);            //  8 MB  x bf16
    u16*   wab = (u16*)(ws + 8388608);      //  6 MB  w_attn bf16
    u16*   wpb = (u16*)(ws + 14680064);     //  2 MB  w_proj bf16
    float* qkv = (float*)(ws + 16777216);   // 48 MB  qkv fp32
    u16*   yb  = (u16*)(ws + 16777216);     //  aliases qkv (dead after normvt): y bf16
    u16*   qb  = (u16*)(ws + 67108864);     //  8 MB  q bf16 (B,H,T,64), pre-scaled
    u16*   kb  = (u16*)(ws + 75497472);     //  8 MB  k bf16 swizzled
    u16*   vtb = (u16*)(ws + 83886080);     //  8 MB  v^T bf16 swizzled

    castbf3<<<8192, 256, 0, stream>>>(x, xb, w_attn, wab, w_proj, wpb);

    gemm128<<<dim3(24, 32), 256, 0, stream>>>(xb, wab, qkv, 4096, 3072, 1024);

    normvt_kernel<<<33792, 256, 0, stream>>>(qkv, fcos, fsin, qw, kw, qb, kb, vtb);

    attn_kernel<<<dim3(16, 32), 256, 0, stream>>>(qb, kb, vtb, yb);

    gemm128<<<dim3(8, 32), 256, 0, stream>>>(yb, wpb, out, 4096, 1024, 1024);
}

// Round 5
// 215.195 us; speedup vs baseline: 1.8703x; 1.0568x over previous
//
#include <hip/hip_runtime.h>

typedef unsigned short u16;
typedef unsigned int u32;
typedef __bf16 bf16x8 __attribute__((ext_vector_type(8)));
typedef float f32x4 __attribute__((ext_vector_type(4)));

__device__ __forceinline__ u16 f2bf(float f) {
    union { float f; u32 u; } v;
    v.f = f;
    u32 r = v.u + 0x7fffu + ((v.u >> 16) & 1u);
    return (u16)(r >> 16);
}

__device__ __forceinline__ u32 fbits(float f) {
    union { float f; u32 u; } v; v.f = f; return v.u;
}

__device__ __forceinline__ void glds16(const void* g, void* l) {
    __builtin_amdgcn_global_load_lds(
        (__attribute__((address_space(1))) unsigned int*)(g),
        (__attribute__((address_space(3))) unsigned int*)(l), 16, 0, 0);
}

// ---------------- fused cast fp32 -> bf16 for x, w_attn (q/k rows permuted), w_proj ----
// w_attn q/k rows are permuted within each head: original dim d -> nd = (d>>1) + (d&1)*32,
// i.e. head layout becomes [evens | odds]. RoPE partner then sits 32 dims away (same lane
// in the GEMM fragment), and q.k dot products are invariant to the shared permutation.
__global__ void castbf3(const float* __restrict__ a, u16* __restrict__ oa,
                        const float* __restrict__ b, u16* __restrict__ ob,
                        const float* __restrict__ c, u16* __restrict__ oc) {
    int blk = blockIdx.x;
    if (blk < 4096) {
        int i = blk * 256 + threadIdx.x;
        float4 v = ((const float4*)a)[i];
        ushort4 o;
        o.x = f2bf(v.x); o.y = f2bf(v.y); o.z = f2bf(v.z); o.w = f2bf(v.w);
        ((ushort4*)oa)[i] = o;
    } else if (blk < 7168) {
        int i = (blk - 4096) * 256 + threadIdx.x;   // float4 index over (3072,1024)
        int n = i >> 8, c4 = i & 255;
        int np;
        if (n < 2048) {
            int part = n >> 10, rem = n & 1023;
            int h = rem >> 6, d = rem & 63;
            int nd = (d >> 1) + ((d & 1) << 5);
            np = part * 1024 + h * 64 + nd;
        } else np = n;
        float4 v = ((const float4*)b)[i];
        ushort4 o;
        o.x = f2bf(v.x); o.y = f2bf(v.y); o.z = f2bf(v.z); o.w = f2bf(v.w);
        ((ushort4*)ob)[np * 256 + c4] = o;
    } else {
        int i = (blk - 7168) * 256 + threadIdx.x;
        float4 v = ((const float4*)c)[i];
        ushort4 o;
        o.x = f2bf(v.x); o.y = f2bf(v.y); o.z = f2bf(v.z); o.w = f2bf(v.w);
        ((ushort4*)oc)[i] = o;
    }
}

// ---------------- QKV GEMM (128x128) with fused RMSNorm+RoPE+transpose epilogue -------
// A: xb (4096x1024), B: wab (3072x1024, q/k rows permuted). Outputs:
//   q (B,H,T,64) bf16, pre-scaled by 0.125*log2(e), permuted-d layout
//   k (B,H,T,64) bf16, chunk-swizzled by t&7, permuted-d layout
//   vt (B,H,64,T) bf16, chunk-swizzled by d&7
__global__ __launch_bounds__(256) void gemm_qkv(
    const u16* __restrict__ A, const u16* __restrict__ B,
    const float* __restrict__ fcos, const float* __restrict__ fsin,
    const float* __restrict__ qw, const float* __restrict__ kw,
    u16* __restrict__ q, u16* __restrict__ k, u16* __restrict__ vt)
{
    __shared__ alignas(16) u16 As[128 * 32];
    __shared__ alignas(16) u16 Bs[128 * 32];
    const int tid = threadIdx.x;
    const int lane = tid & 63;
    const int wave = tid >> 6;
    const int bm = blockIdx.y * 128, bn = blockIdx.x * 128;
    const int wm = (wave >> 1) * 64, wn = (wave & 1) * 64;
    const int ln = lane & 15, quad = lane >> 4;
    const int K = 1024;

    f32x4 acc[4][4] = {};

    const int srow = tid >> 2;
    const int scol = (tid & 3) * 8;
    const u16* gA = A + (size_t)(bm + srow) * K + scol;
    const u16* gB = B + (size_t)(bn + srow) * K + scol;
    u16* lA = &As[wave * 512];
    u16* lB = &Bs[wave * 512];

    for (int k0 = 0; k0 < K; k0 += 32) {
        glds16(gA + k0, lA);
        glds16(gA + (size_t)64 * K + k0, lA + 2048);
        glds16(gB + k0, lB);
        glds16(gB + (size_t)64 * K + k0, lB + 2048);
        __builtin_amdgcn_s_waitcnt(0);
        __syncthreads();

        bf16x8 af[4], bfr[4];
#pragma unroll
        for (int i = 0; i < 4; ++i)
            af[i] = *(const bf16x8*)&As[(wm + i * 16 + ln) * 32 + quad * 8];
#pragma unroll
        for (int j = 0; j < 4; ++j)
            bfr[j] = *(const bf16x8*)&Bs[(wn + j * 16 + ln) * 32 + quad * 8];
#pragma unroll
        for (int i = 0; i < 4; ++i)
#pragma unroll
            for (int j = 0; j < 4; ++j)
                acc[i][j] = __builtin_amdgcn_mfma_f32_16x16x32_bf16(af[i], bfr[j], acc[i][j], 0, 0, 0);
        __syncthreads();
    }

    // ---- epilogue ----
    const int part = bn >> 10;                       // 0=q 1=k 2=v
    const int h = ((bn & 1023) + wn) >> 6;           // head for this wave
    const float SC = 0.18033688011112042f;           // 0.125 * log2(e)

    if (part == 2) {
        // V: write transposed (B,H,64,T), chunk-swizzled along t by d&7 (= ln&7)
#pragma unroll
        for (int i = 0; i < 4; ++i) {
#pragma unroll
            for (int r = 0; r < 4; ++r) {
                int gm = bm + wm + i * 16 + quad * 4 + r;
                int b = gm >> 11, t = gm & 2047;
                int tsw = (t & ~63) + ((((t >> 3) & 7) ^ (ln & 7)) << 3) + (t & 7);
                size_t rb = ((size_t)((b * 16 + h) * 64)) * 2048 + tsw;
#pragma unroll
                for (int j = 0; j < 4; ++j)
                    vt[rb + (size_t)(j * 16 + ln) * 2048] = f2bf(acc[i][j][r]);
            }
        }
        return;
    }

    // Q/K: RMSNorm + RoPE (in-lane, thanks to the [evens|odds] permutation)
    const float* nw = (part == 0) ? qw : kw;
    float wv[4];
#pragma unroll
    for (int j = 0; j < 4; ++j) {
        int nd = j * 16 + ln;
        int od = ((nd & 31) << 1) | (nd >> 5);       // original dim
        wv[j] = nw[od];
    }
    const int swd = ((ln >> 3) << 3) | (ln & 7);     // j-invariant part of k swizzle

#pragma unroll
    for (int i = 0; i < 4; ++i) {
#pragma unroll
        for (int r = 0; r < 4; ++r) {
            int gm = bm + wm + i * 16 + quad * 4 + r;
            int b = gm >> 11, t = gm & 2047;

            float v0 = acc[i][0][r], v1 = acc[i][1][r];
            float v2 = acc[i][2][r], v3 = acc[i][3][r];
            float ss = v0 * v0 + v1 * v1 + v2 * v2 + v3 * v3;
            ss += __shfl_xor(ss, 1);
            ss += __shfl_xor(ss, 2);
            ss += __shfl_xor(ss, 4);
            ss += __shfl_xor(ss, 8);
            float g = rsqrtf(ss * (1.0f / 64.0f) + 1e-6f);

            float x0a = v0 * g * wv[0], x0b = v1 * g * wv[1];
            float x1a = v2 * g * wv[2], x1b = v3 * g * wv[3];
            float c0 = fcos[t * 32 + ln],      s0 = fsin[t * 32 + ln];
            float c1 = fcos[t * 32 + 16 + ln], s1 = fsin[t * 32 + 16 + ln];
            float o0 = x0a * c0 - x1a * s0;
            float o2 = x0a * s0 + x1a * c0;
            float o1 = x0b * c1 - x1b * s1;
            float o3 = x0b * s1 + x1b * c1;

            size_t rb = ((size_t)((b * 16 + h) * 2048 + t)) * 64;
            if (part == 0) {
                q[rb + 0  + ln] = f2bf(o0 * SC);
                q[rb + 16 + ln] = f2bf(o1 * SC);
                q[rb + 32 + ln] = f2bf(o2 * SC);
                q[rb + 48 + ln] = f2bf(o3 * SC);
            } else {
                int x8 = (t & 7) << 3;
#pragma unroll
                for (int j = 0; j < 4; ++j) {
                    float oj = (j == 0) ? o0 : (j == 1) ? o1 : (j == 2) ? o2 : o3;
                    int nd = j * 16 + ln;
                    k[rb + ((((nd >> 3) << 3) ^ x8) | (ln & 7))] = f2bf(oj);
                }
            }
        }
    }
}

// ---------------- 64x128 bf16 GEMM (projection), C = A * B^T, fp32 out ----------------
__global__ __launch_bounds__(256) void gemm64(
    const u16* __restrict__ A, const u16* __restrict__ B,
    float* __restrict__ C, int M, int N, int K)
{
    __shared__ alignas(16) u16 As[64 * 32];
    __shared__ alignas(16) u16 Bs[128 * 32];
    const int tid = threadIdx.x;
    const int lane = tid & 63;
    const int wave = tid >> 6;
    const int bm = blockIdx.y * 64, bn = blockIdx.x * 128;
    const int wm = (wave >> 1) * 32, wn = (wave & 1) * 64;
    const int ln = lane & 15, quad = lane >> 4;

    f32x4 acc[2][4] = {};

    const int srow = tid >> 2;
    const int scol = (tid & 3) * 8;
    const u16* gA = A + (size_t)(bm + (srow & 63)) * K + scol;
    const u16* gB = B + (size_t)(bn + srow) * K + scol;
    u16* lA = &As[wave * 512];
    u16* lB = &Bs[wave * 512];

    for (int k0 = 0; k0 < K; k0 += 32) {
        glds16(gA + k0, lA);
        glds16(gB + k0, lB);
        glds16(gB + (size_t)64 * K + k0, lB + 2048);
        __builtin_amdgcn_s_waitcnt(0);
        __syncthreads();

        bf16x8 af[2], bfr[4];
#pragma unroll
        for (int i = 0; i < 2; ++i)
            af[i] = *(const bf16x8*)&As[(wm + i * 16 + ln) * 32 + quad * 8];
#pragma unroll
        for (int j = 0; j < 4; ++j)
            bfr[j] = *(const bf16x8*)&Bs[(wn + j * 16 + ln) * 32 + quad * 8];
#pragma unroll
        for (int i = 0; i < 2; ++i)
#pragma unroll
            for (int j = 0; j < 4; ++j)
                acc[i][j] = __builtin_amdgcn_mfma_f32_16x16x32_bf16(af[i], bfr[j], acc[i][j], 0, 0, 0);
        __syncthreads();
    }

#pragma unroll
    for (int i = 0; i < 2; ++i) {
#pragma unroll
        for (int r = 0; r < 4; ++r) {
            int gm = bm + wm + i * 16 + quad * 4 + r;
            float* Crow = C + (size_t)gm * N + bn + wn + ln;
#pragma unroll
            for (int j = 0; j < 4; ++j)
                Crow[j * 16] = acc[i][j][r];
        }
    }
}

// ---------------- flash attention (causal), S^T form, paired q-tiles, no online max ----
__global__ __launch_bounds__(256) void attn_kernel(
    const u16* __restrict__ Q, const u16* __restrict__ K,
    const u16* __restrict__ VT, u16* __restrict__ Y)
{
    __shared__ alignas(16) u16 Ks[2][64 * 64];
    __shared__ alignas(16) u16 Vs[2][64 * 64];
    __shared__ alignas(16) u16 Ps[4][16 * 80];

    const int tid = threadIdx.x;
    const int lane = tid & 63;
    const int wave = tid >> 6;
    const int ln = lane & 15, quad = lane >> 4;
    const int pi = blockIdx.x;           // 0..15
    const int bh = blockIdx.y;
    const int qaIdx = pi, qbIdx = 31 - pi;
    const int qA = qaIdx * 64, qB = qbIdx * 64;
    const size_t base = (size_t)bh * 2048 * 64;
    const u16* Kg = K + base;
    const u16* Vg = VT + base;

    const int qrowA = qA + wave * 16 + ln;
    bf16x8 qfA0 = *(const bf16x8*)&Q[base + (size_t)qrowA * 64 + quad * 8];
    bf16x8 qfA1 = *(const bf16x8*)&Q[base + (size_t)qrowA * 64 + 32 + quad * 8];
    const int qrowB = qB + wave * 16 + ln;
    bf16x8 qfB0 = *(const bf16x8*)&Q[base + (size_t)qrowB * 64 + quad * 8];
    bf16x8 qfB1 = *(const bf16x8*)&Q[base + (size_t)qrowB * 64 + 32 + quad * 8];

    f32x4 oA[4] = {}, oB[4] = {};
    float lA = 0.0f, lB = 0.0f;
    const int nstages = qbIdx + 1;
    const int sw = ln & 7;

    const int srow = wave * 16 + (lane >> 3);
    const int scol = (lane & 7) * 8;

    auto process = [&](const bf16x8& qf0, const bf16x8& qf1, float& l,
                       f32x4* o, const u16* ksb, const u16* vsb, bool domask,
                       int jb, int qb0) {
        f32x4 st[4];
#pragma unroll
        for (int ct = 0; ct < 4; ++ct) {
            bf16x8 kf0 = *(const bf16x8*)&ksb[(ct * 16 + ln) * 64 + ((0 + quad) ^ sw) * 8];
            bf16x8 kf1 = *(const bf16x8*)&ksb[(ct * 16 + ln) * 64 + ((4 + quad) ^ sw) * 8];
            f32x4 z = {};
            z = __builtin_amdgcn_mfma_f32_16x16x32_bf16(kf0, qf0, z, 0, 0, 0);
            st[ct] = __builtin_amdgcn_mfma_f32_16x16x32_bf16(kf1, qf1, z, 0, 0, 0);
        }
        if (domask) {
            const int qg = qb0 + wave * 16 + ln;
#pragma unroll
            for (int ct = 0; ct < 4; ++ct)
#pragma unroll
                for (int r = 0; r < 4; ++r) {
                    int kvg = jb + ct * 16 + quad * 4 + r;
                    if (kvg > qg) st[ct][r] = -1e30f;
                }
        }

        float sum = 0.0f;
#pragma unroll
        for (int ct = 0; ct < 4; ++ct) {
            float e0 = exp2f(st[ct][0]);
            float e1 = exp2f(st[ct][1]);
            float e2 = exp2f(st[ct][2]);
            float e3 = exp2f(st[ct][3]);
            sum += (e0 + e1) + (e2 + e3);
            uint2 pk;
            pk.x = __builtin_amdgcn_perm(fbits(e1), fbits(e0), 0x07060302u);
            pk.y = __builtin_amdgcn_perm(fbits(e3), fbits(e2), 0x07060302u);
            *(uint2*)&Ps[wave][ln * 80 + ct * 16 + quad * 4] = pk;
        }
        sum += __shfl_xor(sum, 16);
        sum += __shfl_xor(sum, 32);
        l += sum;

        __builtin_amdgcn_s_waitcnt(0xC07F);  // lgkmcnt(0): Ps visible
        bf16x8 pf0 = *(const bf16x8*)&Ps[wave][ln * 80 + quad * 8];
        bf16x8 pf1 = *(const bf16x8*)&Ps[wave][ln * 80 + 32 + quad * 8];

#pragma unroll
        for (int dt = 0; dt < 4; ++dt) {
            bf16x8 vf0 = *(const bf16x8*)&vsb[(dt * 16 + ln) * 64 + ((0 + quad) ^ sw) * 8];
            bf16x8 vf1 = *(const bf16x8*)&vsb[(dt * 16 + ln) * 64 + ((4 + quad) ^ sw) * 8];
            o[dt] = __builtin_amdgcn_mfma_f32_16x16x32_bf16(pf0, vf0, o[dt], 0, 0, 0);
            o[dt] = __builtin_amdgcn_mfma_f32_16x16x32_bf16(pf1, vf1, o[dt], 0, 0, 0);
        }
    };

    glds16(&Kg[(size_t)(0 + srow) * 64 + scol],       &Ks[0][wave * 1024]);
    glds16(&Kg[(size_t)(0 + srow + 8) * 64 + scol],   &Ks[0][wave * 1024 + 512]);
    glds16(&Vg[(size_t)srow * 2048 + 0 + scol],       &Vs[0][wave * 1024]);
    glds16(&Vg[(size_t)(srow + 8) * 2048 + 0 + scol], &Vs[0][wave * 1024 + 512]);

    for (int jt = 0; jt < nstages; ++jt) {
        const int jb = jt * 64;
        const int jbn = (jt + 1 < nstages) ? (jt + 1) * 64 : 0;
        const int nb = (jt + 1) & 1;
        glds16(&Kg[(size_t)(jbn + srow) * 64 + scol],       &Ks[nb][wave * 1024]);
        glds16(&Kg[(size_t)(jbn + srow + 8) * 64 + scol],   &Ks[nb][wave * 1024 + 512]);
        glds16(&Vg[(size_t)srow * 2048 + jbn + scol],       &Vs[nb][wave * 1024]);
        glds16(&Vg[(size_t)(srow + 8) * 2048 + jbn + scol], &Vs[nb][wave * 1024 + 512]);

        asm volatile("s_waitcnt vmcnt(4)\n\ts_barrier" ::: "memory");

        const u16* ksb = &Ks[jt & 1][0];
        const u16* vsb = &Vs[jt & 1][0];

        if (jt <= qaIdx)
            process(qfA0, qfA1, lA, oA, ksb, vsb, jt == qaIdx, jb, qA);
        process(qfB0, qfB1, lB, oB, ksb, vsb, jt == qbIdx, jb, qB);

        asm volatile("s_waitcnt lgkmcnt(0)\n\ts_barrier" ::: "memory");
    }

    const int b = bh >> 4, h = bh & 15;
#pragma unroll
    for (int r = 0; r < 4; ++r) {
        float lra = __shfl(lA, (lane & 48) + quad * 4 + r);
        float invA = 1.0f / lra;
        int gqA = qA + wave * 16 + quad * 4 + r;
        size_t ybA = ((size_t)(b * 2048 + gqA)) * 1024 + h * 64 + ln;
        float lrb = __shfl(lB, (lane & 48) + quad * 4 + r);
        float invB = 1.0f / lrb;
        int gqB = qB + wave * 16 + quad * 4 + r;
        size_t ybB = ((size_t)(b * 2048 + gqB)) * 1024 + h * 64 + ln;
#pragma unroll
        for (int dt = 0; dt < 4; ++dt) {
            Y[ybA + dt * 16] = f2bf(oA[dt][r] * invA);
            Y[ybB + dt * 16] = f2bf(oB[dt][r] * invB);
        }
    }
}

extern "C" void kernel_launch(void* const* d_in, const int* in_sizes, int n_in,
                              void* d_out, int out_size, void* d_ws, size_t ws_size,
                              hipStream_t stream) {
    const float* x      = (const float*)d_in[0];
    const float* fcos   = (const float*)d_in[1];
    const float* fsin   = (const float*)d_in[2];
    const float* w_attn = (const float*)d_in[3];
    const float* w_proj = (const float*)d_in[4];
    const float* qw     = (const float*)d_in[5];
    const float* kw     = (const float*)d_in[6];
    float* out = (float*)d_out;

    char* ws = (char*)d_ws;
    u16* xb  = (u16*)(ws + 0);          //  8 MB  x bf16
    u16* wab = (u16*)(ws + 8388608);    //  6 MB  w_attn bf16 (q/k rows permuted)
    u16* wpb = (u16*)(ws + 14680064);   //  2 MB  w_proj bf16
    u16* yb  = (u16*)(ws + 16777216);   //  8 MB  y bf16 (B,T,C)
    u16* qb  = (u16*)(ws + 25165824);   //  8 MB  q bf16 (B,H,T,64), pre-scaled, perm-d
    u16* kb  = (u16*)(ws + 33554432);   //  8 MB  k bf16 swizzled, perm-d
    u16* vtb = (u16*)(ws + 41943040);   //  8 MB  v^T bf16 swizzled

    castbf3<<<8192, 256, 0, stream>>>(x, xb, w_attn, wab, w_proj, wpb);

    gemm_qkv<<<dim3(24, 32), 256, 0, stream>>>(xb, wab, fcos, fsin, qw, kw, qb, kb, vtb);

    attn_kernel<<<dim3(16, 32), 256, 0, stream>>>(qb, kb, vtb, yb);

    gemm64<<<dim3(8, 64), 256, 0, stream>>>(yb, wpb, out, 4096, 1024, 1024);
}

// Round 6
// 212.239 us; speedup vs baseline: 1.8963x; 1.0139x over previous
//
#include <hip/hip_runtime.h>

typedef unsigned short u16;
typedef unsigned int u32;
typedef __bf16 bf16x8 __attribute__((ext_vector_type(8)));
typedef float f32x4 __attribute__((ext_vector_type(4)));

__device__ __forceinline__ u16 f2bf(float f) {
    union { float f; u32 u; } v;
    v.f = f;
    u32 r = v.u + 0x7fffu + ((v.u >> 16) & 1u);
    return (u16)(r >> 16);
}

__device__ __forceinline__ u32 fbits(float f) {
    union { float f; u32 u; } v; v.f = f; return v.u;
}

__device__ __forceinline__ void glds16(const void* g, void* l) {
    __builtin_amdgcn_global_load_lds(
        (__attribute__((address_space(1))) unsigned int*)(g),
        (__attribute__((address_space(3))) unsigned int*)(l), 16, 0, 0);
}

// ---------------- fused cast fp32 -> bf16 for x, w_attn (q/k rows permuted), w_proj ----
__global__ void castbf3(const float* __restrict__ a, u16* __restrict__ oa,
                        const float* __restrict__ b, u16* __restrict__ ob,
                        const float* __restrict__ c, u16* __restrict__ oc) {
    int blk = blockIdx.x;
    if (blk < 4096) {
        int i = blk * 256 + threadIdx.x;
        float4 v = ((const float4*)a)[i];
        ushort4 o;
        o.x = f2bf(v.x); o.y = f2bf(v.y); o.z = f2bf(v.z); o.w = f2bf(v.w);
        ((ushort4*)oa)[i] = o;
    } else if (blk < 7168) {
        int i = (blk - 4096) * 256 + threadIdx.x;   // float4 index over (3072,1024)
        int n = i >> 8, c4 = i & 255;
        int np;
        if (n < 2048) {
            int part = n >> 10, rem = n & 1023;
            int h = rem >> 6, d = rem & 63;
            int nd = (d >> 1) + ((d & 1) << 5);
            np = part * 1024 + h * 64 + nd;
        } else np = n;
        float4 v = ((const float4*)b)[i];
        ushort4 o;
        o.x = f2bf(v.x); o.y = f2bf(v.y); o.z = f2bf(v.z); o.w = f2bf(v.w);
        ((ushort4*)ob)[np * 256 + c4] = o;
    } else {
        int i = (blk - 7168) * 256 + threadIdx.x;
        float4 v = ((const float4*)c)[i];
        ushort4 o;
        o.x = f2bf(v.x); o.y = f2bf(v.y); o.z = f2bf(v.z); o.w = f2bf(v.w);
        ((ushort4*)oc)[i] = o;
    }
}

// ---------------- QKV GEMM (128x128) with fused RMSNorm+RoPE+transpose epilogue -------
// Epilogues stage through a 32KB LDS tile and emit 16B coalesced stores.
__global__ __launch_bounds__(256) void gemm_qkv(
    const u16* __restrict__ A, const u16* __restrict__ B,
    const float* __restrict__ fcos, const float* __restrict__ fsin,
    const float* __restrict__ qw, const float* __restrict__ kw,
    u16* __restrict__ q, u16* __restrict__ k, u16* __restrict__ vt)
{
    __shared__ alignas(16) u16 As[128 * 32];
    __shared__ alignas(16) u16 Bs[128 * 32];
    __shared__ alignas(16) u16 Es[2 * 128 * 64];   // 32 KB epilogue tile
    const int tid = threadIdx.x;
    const int lane = tid & 63;
    const int wave = tid >> 6;
    const int bm = blockIdx.y * 128, bn = blockIdx.x * 128;
    const int wm = (wave >> 1) * 64, wn = (wave & 1) * 64;
    const int ln = lane & 15, quad = lane >> 4;
    const int K = 1024;

    f32x4 acc[4][4] = {};

    const int srow = tid >> 2;
    const int scol = (tid & 3) * 8;
    const u16* gA = A + (size_t)(bm + srow) * K + scol;
    const u16* gB = B + (size_t)(bn + srow) * K + scol;
    u16* lA = &As[wave * 512];
    u16* lB = &Bs[wave * 512];

    for (int k0 = 0; k0 < K; k0 += 32) {
        glds16(gA + k0, lA);
        glds16(gA + (size_t)64 * K + k0, lA + 2048);
        glds16(gB + k0, lB);
        glds16(gB + (size_t)64 * K + k0, lB + 2048);
        __builtin_amdgcn_s_waitcnt(0);
        __syncthreads();

        bf16x8 af[4], bfr[4];
#pragma unroll
        for (int i = 0; i < 4; ++i)
            af[i] = *(const bf16x8*)&As[(wm + i * 16 + ln) * 32 + quad * 8];
#pragma unroll
        for (int j = 0; j < 4; ++j)
            bfr[j] = *(const bf16x8*)&Bs[(wn + j * 16 + ln) * 32 + quad * 8];
#pragma unroll
        for (int i = 0; i < 4; ++i)
#pragma unroll
            for (int j = 0; j < 4; ++j)
                acc[i][j] = __builtin_amdgcn_mfma_f32_16x16x32_bf16(af[i], bfr[j], acc[i][j], 0, 0, 0);
        __syncthreads();
    }

    // ---- epilogue ----
    const int part = bn >> 10;                       // 0=q 1=k 2=v
    const int headw = wave & 1;                      // local head (= wn>>6)
    const int h0 = (bn & 1023) >> 6;                 // first head of this block
    const float SC = 0.18033688011112042f;           // 0.125 * log2(e)

    if (part == 2) {
        // V: stage [head][d 64][t 128] with t XOR-swizzled by d&15
#pragma unroll
        for (int i = 0; i < 4; ++i)
#pragma unroll
            for (int r = 0; r < 4; ++r) {
                int tloc = wm + i * 16 + quad * 4 + r;
#pragma unroll
                for (int j = 0; j < 4; ++j) {
                    int d = j * 16 + ln;
                    Es[headw * 8192 + d * 128 + (tloc ^ (ln << 3))] = f2bf(acc[i][j][r]);
                }
            }
        __syncthreads();
        const int b = bm >> 11, tbase = bm & 2047;
#pragma unroll
        for (int c = 0; c < 8; ++c) {
            int cid = c * 256 + tid;
            int tc = cid & 15, d = (cid >> 4) & 63, hd = cid >> 10;
            uint4 v = *(const uint4*)&Es[hd * 8192 + d * 128 + ((tc ^ (d & 15)) << 3)];
            size_t dst = ((size_t)((b * 16 + h0 + hd) * 64 + d)) * 2048
                       + tbase + ((tc >> 3) << 6) + (((tc & 7) ^ (d & 7)) << 3);
            *(uint4*)&vt[dst] = v;
        }
        return;
    }

    // Q/K: RMSNorm + RoPE (in-lane via [evens|odds] permutation), stage [head][t 128][d 64]
    // with d-quarter XOR-swizzled by quad -> conflict-free writes.
    const float* nw = (part == 0) ? qw : kw;
    float wv[4];
#pragma unroll
    for (int j = 0; j < 4; ++j) {
        int nd = j * 16 + ln;
        int od = ((nd & 31) << 1) | (nd >> 5);       // original dim
        wv[j] = nw[od];
    }

#pragma unroll
    for (int i = 0; i < 4; ++i) {
#pragma unroll
        for (int r = 0; r < 4; ++r) {
            int tloc = wm + i * 16 + quad * 4 + r;
            int t = (bm + tloc) & 2047;

            float v0 = acc[i][0][r], v1 = acc[i][1][r];
            float v2 = acc[i][2][r], v3 = acc[i][3][r];
            float ss = v0 * v0 + v1 * v1 + v2 * v2 + v3 * v3;
            ss += __shfl_xor(ss, 1);
            ss += __shfl_xor(ss, 2);
            ss += __shfl_xor(ss, 4);
            ss += __shfl_xor(ss, 8);
            float g = rsqrtf(ss * (1.0f / 64.0f) + 1e-6f);
            if (part == 0) g *= SC;

            float x0a = v0 * g * wv[0], x0b = v1 * g * wv[1];
            float x1a = v2 * g * wv[2], x1b = v3 * g * wv[3];
            float c0 = fcos[t * 32 + ln],      s0 = fsin[t * 32 + ln];
            float c1 = fcos[t * 32 + 16 + ln], s1 = fsin[t * 32 + 16 + ln];
            float o0 = x0a * c0 - x1a * s0;
            float o2 = x0a * s0 + x1a * c0;
            float o1 = x0b * c1 - x1b * s1;
            float o3 = x0b * s1 + x1b * c1;

            u16* e = &Es[headw * 8192 + tloc * 64 + ln];
            e[((0 ^ quad) << 4)] = f2bf(o0);
            e[((1 ^ quad) << 4)] = f2bf(o1);
            e[((2 ^ quad) << 4)] = f2bf(o2);
            e[((3 ^ quad) << 4)] = f2bf(o3);
        }
    }
    __syncthreads();
#pragma unroll
    for (int c = 0; c < 8; ++c) {
        int cid = c * 256 + tid;
        int dc = cid & 7, tloc = (cid >> 3) & 127, hd = cid >> 10;
        int q2 = (tloc >> 2) & 3;
        int sq = (dc >> 1) ^ q2;
        uint4 v = *(const uint4*)&Es[hd * 8192 + tloc * 64 + sq * 16 + (dc & 1) * 8];
        int gm = bm + tloc;
        int b = gm >> 11, t = gm & 2047;
        size_t rb = ((size_t)((b * 16 + h0 + hd) * 2048 + t)) * 64;
        if (part == 0) *(uint4*)&q[rb + dc * 8] = v;
        else           *(uint4*)&k[rb + ((dc ^ (t & 7)) << 3)] = v;
    }
}

// ---------------- 64x128 bf16 GEMM (projection), C = A * B^T, fp32 out ----------------
__global__ __launch_bounds__(256) void gemm64(
    const u16* __restrict__ A, const u16* __restrict__ B,
    float* __restrict__ C, int M, int N, int K)
{
    __shared__ alignas(16) u16 As[64 * 32];
    __shared__ alignas(16) u16 Bs[128 * 32];
    const int tid = threadIdx.x;
    const int lane = tid & 63;
    const int wave = tid >> 6;
    const int bm = blockIdx.y * 64, bn = blockIdx.x * 128;
    const int wm = (wave >> 1) * 32, wn = (wave & 1) * 64;
    const int ln = lane & 15, quad = lane >> 4;

    f32x4 acc[2][4] = {};

    const int srow = tid >> 2;
    const int scol = (tid & 3) * 8;
    const u16* gA = A + (size_t)(bm + (srow & 63)) * K + scol;
    const u16* gB = B + (size_t)(bn + srow) * K + scol;
    u16* lA = &As[wave * 512];
    u16* lB = &Bs[wave * 512];

    for (int k0 = 0; k0 < K; k0 += 32) {
        glds16(gA + k0, lA);
        glds16(gB + k0, lB);
        glds16(gB + (size_t)64 * K + k0, lB + 2048);
        __builtin_amdgcn_s_waitcnt(0);
        __syncthreads();

        bf16x8 af[2], bfr[4];
#pragma unroll
        for (int i = 0; i < 2; ++i)
            af[i] = *(const bf16x8*)&As[(wm + i * 16 + ln) * 32 + quad * 8];
#pragma unroll
        for (int j = 0; j < 4; ++j)
            bfr[j] = *(const bf16x8*)&Bs[(wn + j * 16 + ln) * 32 + quad * 8];
#pragma unroll
        for (int i = 0; i < 2; ++i)
#pragma unroll
            for (int j = 0; j < 4; ++j)
                acc[i][j] = __builtin_amdgcn_mfma_f32_16x16x32_bf16(af[i], bfr[j], acc[i][j], 0, 0, 0);
        __syncthreads();
    }

#pragma unroll
    for (int i = 0; i < 2; ++i) {
#pragma unroll
        for (int r = 0; r < 4; ++r) {
            int gm = bm + wm + i * 16 + quad * 4 + r;
            float* Crow = C + (size_t)gm * N + bn + wn + ln;
#pragma unroll
            for (int j = 0; j < 4; ++j)
                Crow[j * 16] = acc[i][j][r];
        }
    }
}

// ---------------- flash attention (causal), S^T form, paired q-tiles, no online max ----
__global__ __launch_bounds__(256) void attn_kernel(
    const u16* __restrict__ Q, const u16* __restrict__ K,
    const u16* __restrict__ VT, u16* __restrict__ Y)
{
    __shared__ alignas(16) u16 Ks[2][64 * 64];
    __shared__ alignas(16) u16 Vs[2][64 * 64];
    __shared__ alignas(16) u16 Ps[4][16 * 80];

    const int tid = threadIdx.x;
    const int lane = tid & 63;
    const int wave = tid >> 6;
    const int ln = lane & 15, quad = lane >> 4;
    const int pi = blockIdx.x;           // 0..15
    const int bh = blockIdx.y;
    const int qaIdx = pi, qbIdx = 31 - pi;
    const int qA = qaIdx * 64, qB = qbIdx * 64;
    const size_t base = (size_t)bh * 2048 * 64;
    const u16* Kg = K + base;
    const u16* Vg = VT + base;

    const int qrowA = qA + wave * 16 + ln;
    bf16x8 qfA0 = *(const bf16x8*)&Q[base + (size_t)qrowA * 64 + quad * 8];
    bf16x8 qfA1 = *(const bf16x8*)&Q[base + (size_t)qrowA * 64 + 32 + quad * 8];
    const int qrowB = qB + wave * 16 + ln;
    bf16x8 qfB0 = *(const bf16x8*)&Q[base + (size_t)qrowB * 64 + quad * 8];
    bf16x8 qfB1 = *(const bf16x8*)&Q[base + (size_t)qrowB * 64 + 32 + quad * 8];

    f32x4 oA[4] = {}, oB[4] = {};
    float lA = 0.0f, lB = 0.0f;
    const int nstages = qbIdx + 1;
    const int sw = ln & 7;

    const int srow = wave * 16 + (lane >> 3);
    const int scol = (lane & 7) * 8;

    auto process = [&](const bf16x8& qf0, const bf16x8& qf1, float& l,
                       f32x4* o, const u16* ksb, const u16* vsb, bool domask,
                       int jb, int qb0) {
        f32x4 st[4];
#pragma unroll
        for (int ct = 0; ct < 4; ++ct) {
            bf16x8 kf0 = *(const bf16x8*)&ksb[(ct * 16 + ln) * 64 + ((0 + quad) ^ sw) * 8];
            bf16x8 kf1 = *(const bf16x8*)&ksb[(ct * 16 + ln) * 64 + ((4 + quad) ^ sw) * 8];
            f32x4 z = {};
            z = __builtin_amdgcn_mfma_f32_16x16x32_bf16(kf0, qf0, z, 0, 0, 0);
            st[ct] = __builtin_amdgcn_mfma_f32_16x16x32_bf16(kf1, qf1, z, 0, 0, 0);
        }
        if (domask) {
            const int qg = qb0 + wave * 16 + ln;
#pragma unroll
            for (int ct = 0; ct < 4; ++ct)
#pragma unroll
                for (int r = 0; r < 4; ++r) {
                    int kvg = jb + ct * 16 + quad * 4 + r;
                    if (kvg > qg) st[ct][r] = -1e30f;
                }
        }

        float sum = 0.0f;
#pragma unroll
        for (int ct = 0; ct < 4; ++ct) {
            float e0 = exp2f(st[ct][0]);
            float e1 = exp2f(st[ct][1]);
            float e2 = exp2f(st[ct][2]);
            float e3 = exp2f(st[ct][3]);
            sum += (e0 + e1) + (e2 + e3);
            uint2 pk;
            pk.x = __builtin_amdgcn_perm(fbits(e1), fbits(e0), 0x07060302u);
            pk.y = __builtin_amdgcn_perm(fbits(e3), fbits(e2), 0x07060302u);
            *(uint2*)&Ps[wave][ln * 80 + ct * 16 + quad * 4] = pk;
        }
        sum += __shfl_xor(sum, 16);
        sum += __shfl_xor(sum, 32);
        l += sum;

        __builtin_amdgcn_s_waitcnt(0xC07F);  // lgkmcnt(0): Ps visible
        bf16x8 pf0 = *(const bf16x8*)&Ps[wave][ln * 80 + quad * 8];
        bf16x8 pf1 = *(const bf16x8*)&Ps[wave][ln * 80 + 32 + quad * 8];

#pragma unroll
        for (int dt = 0; dt < 4; ++dt) {
            bf16x8 vf0 = *(const bf16x8*)&vsb[(dt * 16 + ln) * 64 + ((0 + quad) ^ sw) * 8];
            bf16x8 vf1 = *(const bf16x8*)&vsb[(dt * 16 + ln) * 64 + ((4 + quad) ^ sw) * 8];
            o[dt] = __builtin_amdgcn_mfma_f32_16x16x32_bf16(pf0, vf0, o[dt], 0, 0, 0);
            o[dt] = __builtin_amdgcn_mfma_f32_16x16x32_bf16(pf1, vf1, o[dt], 0, 0, 0);
        }
    };

    glds16(&Kg[(size_t)(0 + srow) * 64 + scol],       &Ks[0][wave * 1024]);
    glds16(&Kg[(size_t)(0 + srow + 8) * 64 + scol],   &Ks[0][wave * 1024 + 512]);
    glds16(&Vg[(size_t)srow * 2048 + 0 + scol],       &Vs[0][wave * 1024]);
    glds16(&Vg[(size_t)(srow + 8) * 2048 + 0 + scol], &Vs[0][wave * 1024 + 512]);

    for (int jt = 0; jt < nstages; ++jt) {
        const int jb = jt * 64;
        const int jbn = (jt + 1 < nstages) ? (jt + 1) * 64 : 0;
        const int nb = (jt + 1) & 1;
        glds16(&Kg[(size_t)(jbn + srow) * 64 + scol],       &Ks[nb][wave * 1024]);
        glds16(&Kg[(size_t)(jbn + srow + 8) * 64 + scol],   &Ks[nb][wave * 1024 + 512]);
        glds16(&Vg[(size_t)srow * 2048 + jbn + scol],       &Vs[nb][wave * 1024]);
        glds16(&Vg[(size_t)(srow + 8) * 2048 + jbn + scol], &Vs[nb][wave * 1024 + 512]);

        asm volatile("s_waitcnt vmcnt(4)\n\ts_barrier" ::: "memory");

        const u16* ksb = &Ks[jt & 1][0];
        const u16* vsb = &Vs[jt & 1][0];

        if (jt <= qaIdx)
            process(qfA0, qfA1, lA, oA, ksb, vsb, jt == qaIdx, jb, qA);
        process(qfB0, qfB1, lB, oB, ksb, vsb, jt == qbIdx, jb, qB);

        asm volatile("s_waitcnt lgkmcnt(0)\n\ts_barrier" ::: "memory");
    }

    const int b = bh >> 4, h = bh & 15;
#pragma unroll
    for (int r = 0; r < 4; ++r) {
        float lra = __shfl(lA, (lane & 48) + quad * 4 + r);
        float invA = 1.0f / lra;
        int gqA = qA + wave * 16 + quad * 4 + r;
        size_t ybA = ((size_t)(b * 2048 + gqA)) * 1024 + h * 64 + ln;
        float lrb = __shfl(lB, (lane & 48) + quad * 4 + r);
        float invB = 1.0f / lrb;
        int gqB = qB + wave * 16 + quad * 4 + r;
        size_t ybB = ((size_t)(b * 2048 + gqB)) * 1024 + h * 64 + ln;
#pragma unroll
        for (int dt = 0; dt < 4; ++dt) {
            Y[ybA + dt * 16] = f2bf(oA[dt][r] * invA);
            Y[ybB + dt * 16] = f2bf(oB[dt][r] * invB);
        }
    }
}

extern "C" void kernel_launch(void* const* d_in, const int* in_sizes, int n_in,
                              void* d_out, int out_size, void* d_ws, size_t ws_size,
                              hipStream_t stream) {
    const float* x      = (const float*)d_in[0];
    const float* fcos   = (const float*)d_in[1];
    const float* fsin   = (const float*)d_in[2];
    const float* w_attn = (const float*)d_in[3];
    const float* w_proj = (const float*)d_in[4];
    const float* qw     = (const float*)d_in[5];
    const float* kw     = (const float*)d_in[6];
    float* out = (float*)d_out;

    char* ws = (char*)d_ws;
    u16* xb  = (u16*)(ws + 0);          //  8 MB  x bf16
    u16* wab = (u16*)(ws + 8388608);    //  6 MB  w_attn bf16 (q/k rows permuted)
    u16* wpb = (u16*)(ws + 14680064);   //  2 MB  w_proj bf16
    u16* yb  = (u16*)(ws + 16777216);   //  8 MB  y bf16 (B,T,C)
    u16* qb  = (u16*)(ws + 25165824);   //  8 MB  q bf16 (B,H,T,64), pre-scaled, perm-d
    u16* kb  = (u16*)(ws + 33554432);   //  8 MB  k bf16 swizzled, perm-d
    u16* vtb = (u16*)(ws + 41943040);   //  8 MB  v^T bf16 swizzled

    castbf3<<<8192, 256, 0, stream>>>(x, xb, w_attn, wab, w_proj, wpb);

    gemm_qkv<<<dim3(24, 32), 256, 0, stream>>>(xb, wab, fcos, fsin, qw, kw, qb, kb, vtb);

    attn_kernel<<<dim3(16, 32), 256, 0, stream>>>(qb, kb, vtb, yb);

    gemm64<<<dim3(8, 64), 256, 0, stream>>>(yb, wpb, out, 4096, 1024, 1024);
}

// Round 7
// 209.024 us; speedup vs baseline: 1.9255x; 1.0154x over previous
//
#include <hip/hip_runtime.h>

typedef unsigned short u16;
typedef unsigned int u32;
typedef __bf16 bf16x8 __attribute__((ext_vector_type(8)));
typedef float f32x4 __attribute__((ext_vector_type(4)));

__device__ __forceinline__ u16 f2bf(float f) {
    union { float f; u32 u; } v;
    v.f = f;
    u32 r = v.u + 0x7fffu + ((v.u >> 16) & 1u);
    return (u16)(r >> 16);
}

__device__ __forceinline__ u32 fbits(float f) {
    union { float f; u32 u; } v; v.f = f; return v.u;
}

__device__ __forceinline__ void glds16(const void* g, void* l) {
    __builtin_amdgcn_global_load_lds(
        (__attribute__((address_space(1))) unsigned int*)(g),
        (__attribute__((address_space(3))) unsigned int*)(l), 16, 0, 0);
}

#define MFMA __builtin_amdgcn_mfma_f32_16x16x32_bf16

// ---------------- fused cast fp32 -> bf16 + cos/sin float2 table ----------------
__global__ void castbf3(const float* __restrict__ a, u16* __restrict__ oa,
                        const float* __restrict__ b, u16* __restrict__ ob,
                        const float* __restrict__ c, u16* __restrict__ oc,
                        const float* __restrict__ fcos, const float* __restrict__ fsin,
                        float2* __restrict__ csb) {
    int blk = blockIdx.x;
    if (blk < 4096) {
        int i = blk * 256 + threadIdx.x;
        float4 v = ((const float4*)a)[i];
        ushort4 o;
        o.x = f2bf(v.x); o.y = f2bf(v.y); o.z = f2bf(v.z); o.w = f2bf(v.w);
        ((ushort4*)oa)[i] = o;
    } else if (blk < 7168) {
        int i = (blk - 4096) * 256 + threadIdx.x;   // float4 index over (3072,1024)
        int n = i >> 8, c4 = i & 255;
        int np;
        if (n < 2048) {
            int part = n >> 10, rem = n & 1023;
            int h = rem >> 6, d = rem & 63;
            int nd = (d >> 1) + ((d & 1) << 5);
            np = part * 1024 + h * 64 + nd;
        } else np = n;
        float4 v = ((const float4*)b)[i];
        ushort4 o;
        o.x = f2bf(v.x); o.y = f2bf(v.y); o.z = f2bf(v.z); o.w = f2bf(v.w);
        ((ushort4*)ob)[np * 256 + c4] = o;
    } else if (blk < 8192) {
        int i = (blk - 7168) * 256 + threadIdx.x;
        float4 v = ((const float4*)c)[i];
        ushort4 o;
        o.x = f2bf(v.x); o.y = f2bf(v.y); o.z = f2bf(v.z); o.w = f2bf(v.w);
        ((ushort4*)oc)[i] = o;
    } else {
        int i = (blk - 8192) * 256 + threadIdx.x;   // 0..65535 over (2048 t, 32 freq)
        csb[i] = make_float2(fcos[i], fsin[i]);
    }
}

// ---------------- QKV GEMM (128x128) with fused RMSNorm+RoPE+transpose epilogue -------
__global__ __launch_bounds__(256) void gemm_qkv(
    const u16* __restrict__ A, const u16* __restrict__ B,
    const float2* __restrict__ csb,
    const float* __restrict__ qw, const float* __restrict__ kw,
    u16* __restrict__ q, u16* __restrict__ k, u16* __restrict__ vt)
{
    __shared__ alignas(16) u16 As[128 * 32];
    __shared__ alignas(16) u16 Bs[128 * 32];
    __shared__ alignas(16) u16 Es[2 * 128 * 64];   // 32 KB epilogue tile
    const int tid = threadIdx.x;
    const int lane = tid & 63;
    const int wave = tid >> 6;
    const int bm = blockIdx.y * 128, bn = blockIdx.x * 128;
    const int wm = (wave >> 1) * 64, wn = (wave & 1) * 64;
    const int ln = lane & 15, quad = lane >> 4;
    const int K = 1024;

    f32x4 acc[4][4] = {};

    const int srow = tid >> 2;
    const int scol = (tid & 3) * 8;
    const u16* gA = A + (size_t)(bm + srow) * K + scol;
    const u16* gB = B + (size_t)(bn + srow) * K + scol;
    u16* lA = &As[wave * 512];
    u16* lB = &Bs[wave * 512];

    for (int k0 = 0; k0 < K; k0 += 32) {
        glds16(gA + k0, lA);
        glds16(gA + (size_t)64 * K + k0, lA + 2048);
        glds16(gB + k0, lB);
        glds16(gB + (size_t)64 * K + k0, lB + 2048);
        __builtin_amdgcn_s_waitcnt(0);
        __syncthreads();

        bf16x8 af[4], bfr[4];
#pragma unroll
        for (int i = 0; i < 4; ++i)
            af[i] = *(const bf16x8*)&As[(wm + i * 16 + ln) * 32 + quad * 8];
#pragma unroll
        for (int j = 0; j < 4; ++j)
            bfr[j] = *(const bf16x8*)&Bs[(wn + j * 16 + ln) * 32 + quad * 8];
#pragma unroll
        for (int i = 0; i < 4; ++i)
#pragma unroll
            for (int j = 0; j < 4; ++j)
                acc[i][j] = MFMA(af[i], bfr[j], acc[i][j], 0, 0, 0);
        __syncthreads();
    }

    // ---- epilogue ----
    const int part = bn >> 10;                       // 0=q 1=k 2=v
    const int headw = wave & 1;
    const int h0 = (bn & 1023) >> 6;
    const float SC = 0.18033688011112042f;           // 0.125 * log2(e)

    if (part == 2) {
        // V: stage [head][d 64][t 128], t XOR-swizzled by d&15; pack 4 t-vals -> b64
#pragma unroll
        for (int i = 0; i < 4; ++i) {
            int tlb = wm + i * 16 + quad * 4;
#pragma unroll
            for (int j = 0; j < 4; ++j) {
                int d = j * 16 + ln;
                uint2 pk;
                pk.x = __builtin_amdgcn_perm(fbits(acc[i][j][1]), fbits(acc[i][j][0]), 0x07060302u);
                pk.y = __builtin_amdgcn_perm(fbits(acc[i][j][3]), fbits(acc[i][j][2]), 0x07060302u);
                *(uint2*)&Es[headw * 8192 + d * 128 + (tlb ^ (ln << 3))] = pk;
            }
        }
        __syncthreads();
        const int b = bm >> 11, tbase = bm & 2047;
#pragma unroll
        for (int c = 0; c < 8; ++c) {
            int cid = c * 256 + tid;
            int tc = cid & 15, d = (cid >> 4) & 63, hd = cid >> 10;
            uint4 v = *(const uint4*)&Es[hd * 8192 + d * 128 + ((tc ^ (d & 15)) << 3)];
            size_t dst = ((size_t)((b * 16 + h0 + hd) * 64 + d)) * 2048
                       + tbase + ((tc >> 3) << 6) + (((tc & 7) ^ (d & 7)) << 3);
            *(uint4*)&vt[dst] = v;
        }
        return;
    }

    // Q/K: RMSNorm + RoPE (in-lane via [evens|odds] permutation)
    const float* nw = (part == 0) ? qw : kw;
    float wv[4];
#pragma unroll
    for (int j = 0; j < 4; ++j) {
        int nd = j * 16 + ln;
        int od = ((nd & 31) << 1) | (nd >> 5);
        wv[j] = nw[od];
    }

#pragma unroll
    for (int i = 0; i < 4; ++i) {
#pragma unroll
        for (int r = 0; r < 4; ++r) {
            int tloc = wm + i * 16 + quad * 4 + r;
            int t = (bm + tloc) & 2047;

            float v0 = acc[i][0][r], v1 = acc[i][1][r];
            float v2 = acc[i][2][r], v3 = acc[i][3][r];
            float ss = v0 * v0 + v1 * v1 + v2 * v2 + v3 * v3;
            ss += __shfl_xor(ss, 1);
            ss += __shfl_xor(ss, 2);
            ss += __shfl_xor(ss, 4);
            ss += __shfl_xor(ss, 8);
            float g = rsqrtf(ss * (1.0f / 64.0f) + 1e-6f);
            if (part == 0) g *= SC;

            float x0a = v0 * g * wv[0], x0b = v1 * g * wv[1];
            float x1a = v2 * g * wv[2], x1b = v3 * g * wv[3];
            float2 cs0 = csb[t * 32 + ln];
            float2 cs1 = csb[t * 32 + 16 + ln];
            float o0 = x0a * cs0.x - x1a * cs0.y;
            float o2 = x0a * cs0.y + x1a * cs0.x;
            float o1 = x0b * cs1.x - x1b * cs1.y;
            float o3 = x0b * cs1.y + x1b * cs1.x;

            u16* e = &Es[headw * 8192 + tloc * 64 + ln];
            e[((0 ^ quad) << 4)] = f2bf(o0);
            e[((1 ^ quad) << 4)] = f2bf(o1);
            e[((2 ^ quad) << 4)] = f2bf(o2);
            e[((3 ^ quad) << 4)] = f2bf(o3);
        }
    }
    __syncthreads();
#pragma unroll
    for (int c = 0; c < 8; ++c) {
        int cid = c * 256 + tid;
        int dc = cid & 7, tloc = (cid >> 3) & 127, hd = cid >> 10;
        int q2 = (tloc >> 2) & 3;
        int sq = (dc >> 1) ^ q2;
        uint4 v = *(const uint4*)&Es[hd * 8192 + tloc * 64 + sq * 16 + (dc & 1) * 8];
        int gm = bm + tloc;
        int b = gm >> 11, t = gm & 2047;
        size_t rb = ((size_t)((b * 16 + h0 + hd) * 2048 + t)) * 64;
        if (part == 0) *(uint4*)&q[rb + dc * 8] = v;
        else           *(uint4*)&k[rb + ((dc ^ (t & 7)) << 3)] = v;
    }
}

// ---------------- 64x128 bf16 GEMM (projection), C = A * B^T, fp32 out ----------------
__global__ __launch_bounds__(256) void gemm64(
    const u16* __restrict__ A, const u16* __restrict__ B,
    float* __restrict__ C, int M, int N, int K)
{
    __shared__ alignas(16) u16 As[64 * 32];
    __shared__ alignas(16) u16 Bs[128 * 32];
    const int tid = threadIdx.x;
    const int lane = tid & 63;
    const int wave = tid >> 6;
    const int bm = blockIdx.y * 64, bn = blockIdx.x * 128;
    const int wm = (wave >> 1) * 32, wn = (wave & 1) * 64;
    const int ln = lane & 15, quad = lane >> 4;

    f32x4 acc[2][4] = {};

    const int srow = tid >> 2;
    const int scol = (tid & 3) * 8;
    const u16* gA = A + (size_t)(bm + (srow & 63)) * K + scol;
    const u16* gB = B + (size_t)(bn + srow) * K + scol;
    u16* lA = &As[wave * 512];
    u16* lB = &Bs[wave * 512];

    for (int k0 = 0; k0 < K; k0 += 32) {
        glds16(gA + k0, lA);
        glds16(gB + k0, lB);
        glds16(gB + (size_t)64 * K + k0, lB + 2048);
        __builtin_amdgcn_s_waitcnt(0);
        __syncthreads();

        bf16x8 af[2], bfr[4];
#pragma unroll
        for (int i = 0; i < 2; ++i)
            af[i] = *(const bf16x8*)&As[(wm + i * 16 + ln) * 32 + quad * 8];
#pragma unroll
        for (int j = 0; j < 4; ++j)
            bfr[j] = *(const bf16x8*)&Bs[(wn + j * 16 + ln) * 32 + quad * 8];
#pragma unroll
        for (int i = 0; i < 2; ++i)
#pragma unroll
            for (int j = 0; j < 4; ++j)
                acc[i][j] = MFMA(af[i], bfr[j], acc[i][j], 0, 0, 0);
        __syncthreads();
    }

#pragma unroll
    for (int i = 0; i < 2; ++i) {
#pragma unroll
        for (int r = 0; r < 4; ++r) {
            int gm = bm + wm + i * 16 + quad * 4 + r;
            float* Crow = C + (size_t)gm * N + bn + wn + ln;
#pragma unroll
            for (int j = 0; j < 4; ++j)
                Crow[j * 16] = acc[i][j][r];
        }
    }
}

// ---------------- attention stage: A (optional) and B batched, separate Ps ----------
template <bool DUAL>
__device__ __forceinline__ void attn_stage(
    int ln, int quad, int sw,
    const u16* __restrict__ ksb, const u16* __restrict__ vsb,
    u16* __restrict__ PsA, u16* __restrict__ PsB,
    const bf16x8& qfA0, const bf16x8& qfA1,
    const bf16x8& qfB0, const bf16x8& qfB1,
    f32x4* oA, f32x4* oB, float& lA, float& lB,
    bool maskA, bool maskB, int jb, int qA, int qB)
{
    f32x4 stA[4], stB[4];
#pragma unroll
    for (int ct = 0; ct < 4; ++ct) {
        bf16x8 kf0 = *(const bf16x8*)&ksb[(ct * 16 + ln) * 64 + ((0 + quad) ^ sw) * 8];
        bf16x8 kf1 = *(const bf16x8*)&ksb[(ct * 16 + ln) * 64 + ((4 + quad) ^ sw) * 8];
        f32x4 z = {};
        z = MFMA(kf0, qfB0, z, 0, 0, 0);
        stB[ct] = MFMA(kf1, qfB1, z, 0, 0, 0);
        if (DUAL) {
            f32x4 za = {};
            za = MFMA(kf0, qfA0, za, 0, 0, 0);
            stA[ct] = MFMA(kf1, qfA1, za, 0, 0, 0);
        }
    }
    if (maskB) {
        const int qg = qB + ln;   // qB already includes wave*16
#pragma unroll
        for (int ct = 0; ct < 4; ++ct)
#pragma unroll
            for (int r = 0; r < 4; ++r)
                if (jb + ct * 16 + quad * 4 + r > qg) stB[ct][r] = -1e30f;
    }
    if (DUAL && maskA) {
        const int qg = qA + ln;
#pragma unroll
        for (int ct = 0; ct < 4; ++ct)
#pragma unroll
            for (int r = 0; r < 4; ++r)
                if (jb + ct * 16 + quad * 4 + r > qg) stA[ct][r] = -1e30f;
    }

    float sumB = 0.0f, sumA = 0.0f;
#pragma unroll
    for (int ct = 0; ct < 4; ++ct) {
        float b0 = exp2f(stB[ct][0]), b1 = exp2f(stB[ct][1]);
        float b2 = exp2f(stB[ct][2]), b3 = exp2f(stB[ct][3]);
        sumB += (b0 + b1) + (b2 + b3);
        uint2 pk;
        pk.x = __builtin_amdgcn_perm(fbits(b1), fbits(b0), 0x07060302u);
        pk.y = __builtin_amdgcn_perm(fbits(b3), fbits(b2), 0x07060302u);
        *(uint2*)&PsB[ln * 80 + ct * 16 + quad * 4] = pk;
        if (DUAL) {
            float a0 = exp2f(stA[ct][0]), a1 = exp2f(stA[ct][1]);
            float a2 = exp2f(stA[ct][2]), a3 = exp2f(stA[ct][3]);
            sumA += (a0 + a1) + (a2 + a3);
            uint2 pa;
            pa.x = __builtin_amdgcn_perm(fbits(a1), fbits(a0), 0x07060302u);
            pa.y = __builtin_amdgcn_perm(fbits(a3), fbits(a2), 0x07060302u);
            *(uint2*)&PsA[ln * 80 + ct * 16 + quad * 4] = pa;
        }
    }
    sumB += __shfl_xor(sumB, 16);
    sumB += __shfl_xor(sumB, 32);
    lB += sumB;
    if (DUAL) {
        sumA += __shfl_xor(sumA, 16);
        sumA += __shfl_xor(sumA, 32);
        lA += sumA;
    }

    __builtin_amdgcn_s_waitcnt(0xC07F);  // lgkmcnt(0): Ps writes visible
    bf16x8 pfB0 = *(const bf16x8*)&PsB[ln * 80 + quad * 8];
    bf16x8 pfB1 = *(const bf16x8*)&PsB[ln * 80 + 32 + quad * 8];
    bf16x8 pfA0, pfA1;
    if (DUAL) {
        pfA0 = *(const bf16x8*)&PsA[ln * 80 + quad * 8];
        pfA1 = *(const bf16x8*)&PsA[ln * 80 + 32 + quad * 8];
    }

#pragma unroll
    for (int dt = 0; dt < 4; ++dt) {
        bf16x8 vf0 = *(const bf16x8*)&vsb[(dt * 16 + ln) * 64 + ((0 + quad) ^ sw) * 8];
        bf16x8 vf1 = *(const bf16x8*)&vsb[(dt * 16 + ln) * 64 + ((4 + quad) ^ sw) * 8];
        oB[dt] = MFMA(pfB0, vf0, oB[dt], 0, 0, 0);
        oB[dt] = MFMA(pfB1, vf1, oB[dt], 0, 0, 0);
        if (DUAL) {
            oA[dt] = MFMA(pfA0, vf0, oA[dt], 0, 0, 0);
            oA[dt] = MFMA(pfA1, vf1, oA[dt], 0, 0, 0);
        }
    }
}

// ---------------- flash attention (causal), S^T form, paired q-tiles, no online max ----
__global__ __launch_bounds__(256) void attn_kernel(
    const u16* __restrict__ Q, const u16* __restrict__ K,
    const u16* __restrict__ VT, u16* __restrict__ Y)
{
    __shared__ alignas(16) u16 Ks[2][64 * 64];
    __shared__ alignas(16) u16 Vs[2][64 * 64];
    __shared__ alignas(16) u16 PsA[4][16 * 80];
    __shared__ alignas(16) u16 PsB[4][16 * 80];

    const int tid = threadIdx.x;
    const int lane = tid & 63;
    const int wave = tid >> 6;
    const int ln = lane & 15, quad = lane >> 4;
    const int pi = blockIdx.x;           // 0..15
    const int bh = blockIdx.y;
    const int qaIdx = pi, qbIdx = 31 - pi;
    const int qA = qaIdx * 64, qB = qbIdx * 64;
    const size_t base = (size_t)bh * 2048 * 64;
    const u16* Kg = K + base;
    const u16* Vg = VT + base;

    const int qrowA = qA + wave * 16 + ln;
    bf16x8 qfA0 = *(const bf16x8*)&Q[base + (size_t)qrowA * 64 + quad * 8];
    bf16x8 qfA1 = *(const bf16x8*)&Q[base + (size_t)qrowA * 64 + 32 + quad * 8];
    const int qrowB = qB + wave * 16 + ln;
    bf16x8 qfB0 = *(const bf16x8*)&Q[base + (size_t)qrowB * 64 + quad * 8];
    bf16x8 qfB1 = *(const bf16x8*)&Q[base + (size_t)qrowB * 64 + 32 + quad * 8];

    f32x4 oA[4] = {}, oB[4] = {};
    float lA = 0.0f, lB = 0.0f;
    const int nstages = qbIdx + 1;
    const int sw = ln & 7;

    const int srow = wave * 16 + (lane >> 3);
    const int scol = (lane & 7) * 8;

    auto prefetch = [&](int jbn, int nb) {
        glds16(&Kg[(size_t)(jbn + srow) * 64 + scol],       &Ks[nb][wave * 1024]);
        glds16(&Kg[(size_t)(jbn + srow + 8) * 64 + scol],   &Ks[nb][wave * 1024 + 512]);
        glds16(&Vg[(size_t)srow * 2048 + jbn + scol],       &Vs[nb][wave * 1024]);
        glds16(&Vg[(size_t)(srow + 8) * 2048 + jbn + scol], &Vs[nb][wave * 1024 + 512]);
    };

    prefetch(0, 0);

    int jt = 0;
    // phase 1: dual (A and B both active), jt in [0, qaIdx]
    for (; jt <= qaIdx; ++jt) {
        const int jbn = (jt + 1 < nstages) ? (jt + 1) * 64 : 0;
        prefetch(jbn, (jt + 1) & 1);
        asm volatile("s_waitcnt vmcnt(4)\n\ts_barrier" ::: "memory");
        attn_stage<true>(ln, quad, sw, &Ks[jt & 1][0], &Vs[jt & 1][0],
                         &PsA[wave][0], &PsB[wave][0],
                         qfA0, qfA1, qfB0, qfB1, oA, oB, lA, lB,
                         jt == qaIdx, false, jt * 64, qA + wave * 16, qB + wave * 16);
        asm volatile("s_waitcnt lgkmcnt(0)\n\ts_barrier" ::: "memory");
    }
    // phase 2: B only, jt in (qaIdx, qbIdx]
    for (; jt < nstages; ++jt) {
        const int jbn = (jt + 1 < nstages) ? (jt + 1) * 64 : 0;
        prefetch(jbn, (jt + 1) & 1);
        asm volatile("s_waitcnt vmcnt(4)\n\ts_barrier" ::: "memory");
        attn_stage<false>(ln, quad, sw, &Ks[jt & 1][0], &Vs[jt & 1][0],
                          &PsA[wave][0], &PsB[wave][0],
                          qfA0, qfA1, qfB0, qfB1, oA, oB, lA, lB,
                          false, jt == qbIdx, jt * 64, qA + wave * 16, qB + wave * 16);
        asm volatile("s_waitcnt lgkmcnt(0)\n\ts_barrier" ::: "memory");
    }

    const int b = bh >> 4, h = bh & 15;
#pragma unroll
    for (int r = 0; r < 4; ++r) {
        float lra = __shfl(lA, (lane & 48) + quad * 4 + r);
        float invA = 1.0f / lra;
        int gqA = qA + wave * 16 + quad * 4 + r;
        size_t ybA = ((size_t)(b * 2048 + gqA)) * 1024 + h * 64 + ln;
        float lrb = __shfl(lB, (lane & 48) + quad * 4 + r);
        float invB = 1.0f / lrb;
        int gqB = qB + wave * 16 + quad * 4 + r;
        size_t ybB = ((size_t)(b * 2048 + gqB)) * 1024 + h * 64 + ln;
#pragma unroll
        for (int dt = 0; dt < 4; ++dt) {
            Y[ybA + dt * 16] = f2bf(oA[dt][r] * invA);
            Y[ybB + dt * 16] = f2bf(oB[dt][r] * invB);
        }
    }
}

extern "C" void kernel_launch(void* const* d_in, const int* in_sizes, int n_in,
                              void* d_out, int out_size, void* d_ws, size_t ws_size,
                              hipStream_t stream) {
    const float* x      = (const float*)d_in[0];
    const float* fcos   = (const float*)d_in[1];
    const float* fsin   = (const float*)d_in[2];
    const float* w_attn = (const float*)d_in[3];
    const float* w_proj = (const float*)d_in[4];
    const float* qw     = (const float*)d_in[5];
    const float* kw     = (const float*)d_in[6];
    float* out = (float*)d_out;

    char* ws = (char*)d_ws;
    u16*    xb  = (u16*)(ws + 0);          //  8 MB  x bf16
    u16*    wab = (u16*)(ws + 8388608);    //  6 MB  w_attn bf16 (q/k rows permuted)
    u16*    wpb = (u16*)(ws + 14680064);   //  2 MB  w_proj bf16
    u16*    yb  = (u16*)(ws + 16777216);   //  8 MB  y bf16 (B,T,C)
    u16*    qb  = (u16*)(ws + 25165824);   //  8 MB  q bf16 (B,H,T,64), pre-scaled, perm-d
    u16*    kb  = (u16*)(ws + 33554432);   //  8 MB  k bf16 swizzled, perm-d
    u16*    vtb = (u16*)(ws + 41943040);   //  8 MB  v^T bf16 swizzled
    float2* csb = (float2*)(ws + 50331648);// 512 KB cos/sin interleaved table

    castbf3<<<8448, 256, 0, stream>>>(x, xb, w_attn, wab, w_proj, wpb, fcos, fsin, csb);

    gemm_qkv<<<dim3(24, 32), 256, 0, stream>>>(xb, wab, csb, qw, kw, qb, kb, vtb);

    attn_kernel<<<dim3(16, 32), 256, 0, stream>>>(qb, kb, vtb, yb);

    gemm64<<<dim3(8, 64), 256, 0, stream>>>(yb, wpb, out, 4096, 1024, 1024);
}

// Round 8
// 206.674 us; speedup vs baseline: 1.9474x; 1.0114x over previous
//
#include <hip/hip_runtime.h>

typedef unsigned short u16;
typedef unsigned int u32;
typedef __bf16 bf16x8 __attribute__((ext_vector_type(8)));
typedef float f32x4 __attribute__((ext_vector_type(4)));

__device__ __forceinline__ u16 f2bf(float f) {
    union { float f; u32 u; } v;
    v.f = f;
    u32 r = v.u + 0x7fffu + ((v.u >> 16) & 1u);
    return (u16)(r >> 16);
}

__device__ __forceinline__ u32 fbits(float f) {
    union { float f; u32 u; } v; v.f = f; return v.u;
}

__device__ __forceinline__ void glds16(const void* g, void* l) {
    __builtin_amdgcn_global_load_lds(
        (__attribute__((address_space(1))) unsigned int*)(g),
        (__attribute__((address_space(3))) unsigned int*)(l), 16, 0, 0);
}

#define MFMA __builtin_amdgcn_mfma_f32_16x16x32_bf16

// ---------------- fused cast fp32 -> bf16 + cos/sin float2 table ----------------
__global__ void castbf3(const float* __restrict__ a, u16* __restrict__ oa,
                        const float* __restrict__ b, u16* __restrict__ ob,
                        const float* __restrict__ c, u16* __restrict__ oc,
                        const float* __restrict__ fcos, const float* __restrict__ fsin,
                        float2* __restrict__ csb) {
    int blk = blockIdx.x;
    if (blk < 4096) {
        int i = blk * 256 + threadIdx.x;
        float4 v = ((const float4*)a)[i];
        ushort4 o;
        o.x = f2bf(v.x); o.y = f2bf(v.y); o.z = f2bf(v.z); o.w = f2bf(v.w);
        ((ushort4*)oa)[i] = o;
    } else if (blk < 7168) {
        int i = (blk - 4096) * 256 + threadIdx.x;   // float4 index over (3072,1024)
        int n = i >> 8, c4 = i & 255;
        int np;
        if (n < 2048) {
            int part = n >> 10, rem = n & 1023;
            int h = rem >> 6, d = rem & 63;
            int nd = (d >> 1) + ((d & 1) << 5);
            np = part * 1024 + h * 64 + nd;
        } else np = n;
        float4 v = ((const float4*)b)[i];
        ushort4 o;
        o.x = f2bf(v.x); o.y = f2bf(v.y); o.z = f2bf(v.z); o.w = f2bf(v.w);
        ((ushort4*)ob)[np * 256 + c4] = o;
    } else if (blk < 8192) {
        int i = (blk - 7168) * 256 + threadIdx.x;
        float4 v = ((const float4*)c)[i];
        ushort4 o;
        o.x = f2bf(v.x); o.y = f2bf(v.y); o.z = f2bf(v.z); o.w = f2bf(v.w);
        ((ushort4*)oc)[i] = o;
    } else {
        int i = (blk - 8192) * 256 + threadIdx.x;   // 0..65535 over (2048 t, 32 freq)
        csb[i] = make_float2(fcos[i], fsin[i]);
    }
}

// ---------------- QKV GEMM (128x128) with fused RMSNorm+RoPE+transpose epilogue -------
// Outputs: q (B,H,64d,2048t) pre-scaled by 0.125*log2(e), perm-d, linear t
//          k (B,H,T,64) chunk-swizzled by t&7, perm-d
//          vt (B,H,64,T) chunk-swizzled by d&7
__global__ __launch_bounds__(256) void gemm_qkv(
    const u16* __restrict__ A, const u16* __restrict__ B,
    const float2* __restrict__ csb,
    const float* __restrict__ qw, const float* __restrict__ kw,
    u16* __restrict__ q, u16* __restrict__ k, u16* __restrict__ vt)
{
    __shared__ alignas(16) u16 As[128 * 32];
    __shared__ alignas(16) u16 Bs[128 * 32];
    __shared__ alignas(16) u16 Es[2 * 128 * 64];   // 32 KB epilogue tile
    const int tid = threadIdx.x;
    const int lane = tid & 63;
    const int wave = tid >> 6;
    const int bm = blockIdx.y * 128, bn = blockIdx.x * 128;
    const int wm = (wave >> 1) * 64, wn = (wave & 1) * 64;
    const int ln = lane & 15, quad = lane >> 4;
    const int K = 1024;

    f32x4 acc[4][4] = {};

    const int srow = tid >> 2;
    const int scol = (tid & 3) * 8;
    const u16* gA = A + (size_t)(bm + srow) * K + scol;
    const u16* gB = B + (size_t)(bn + srow) * K + scol;
    u16* lA = &As[wave * 512];
    u16* lB = &Bs[wave * 512];

    for (int k0 = 0; k0 < K; k0 += 32) {
        glds16(gA + k0, lA);
        glds16(gA + (size_t)64 * K + k0, lA + 2048);
        glds16(gB + k0, lB);
        glds16(gB + (size_t)64 * K + k0, lB + 2048);
        __builtin_amdgcn_s_waitcnt(0);
        __syncthreads();

        bf16x8 af[4], bfr[4];
#pragma unroll
        for (int i = 0; i < 4; ++i)
            af[i] = *(const bf16x8*)&As[(wm + i * 16 + ln) * 32 + quad * 8];
#pragma unroll
        for (int j = 0; j < 4; ++j)
            bfr[j] = *(const bf16x8*)&Bs[(wn + j * 16 + ln) * 32 + quad * 8];
#pragma unroll
        for (int i = 0; i < 4; ++i)
#pragma unroll
            for (int j = 0; j < 4; ++j)
                acc[i][j] = MFMA(af[i], bfr[j], acc[i][j], 0, 0, 0);
        __syncthreads();
    }

    // ---- epilogue ----
    const int part = bn >> 10;                       // 0=q 1=k 2=v
    const int headw = wave & 1;
    const int h0 = (bn & 1023) >> 6;
    const float SC = 0.18033688011112042f;           // 0.125 * log2(e)
    const int b = bm >> 11, tbase = bm & 2047;

    if (part == 2) {
        // V: stage [head][d 64][t 128], t XOR-swizzled by d&15; pack 4 t-vals -> b64
#pragma unroll
        for (int i = 0; i < 4; ++i) {
            int tlb = wm + i * 16 + quad * 4;
#pragma unroll
            for (int j = 0; j < 4; ++j) {
                int d = j * 16 + ln;
                uint2 pk;
                pk.x = __builtin_amdgcn_perm(fbits(acc[i][j][1]), fbits(acc[i][j][0]), 0x07060302u);
                pk.y = __builtin_amdgcn_perm(fbits(acc[i][j][3]), fbits(acc[i][j][2]), 0x07060302u);
                *(uint2*)&Es[headw * 8192 + d * 128 + (tlb ^ (ln << 3))] = pk;
            }
        }
        __syncthreads();
#pragma unroll
        for (int c = 0; c < 8; ++c) {
            int cid = c * 256 + tid;
            int tc = cid & 15, d = (cid >> 4) & 63, hd = cid >> 10;
            uint4 v = *(const uint4*)&Es[hd * 8192 + d * 128 + ((tc ^ (d & 15)) << 3)];
            size_t dst = ((size_t)((b * 16 + h0 + hd) * 64 + d)) * 2048
                       + tbase + ((tc >> 3) << 6) + (((tc & 7) ^ (d & 7)) << 3);
            *(uint4*)&vt[dst] = v;
        }
        return;
    }

    const float* nw = (part == 0) ? qw : kw;
    float wv[4];
#pragma unroll
    for (int j = 0; j < 4; ++j) {
        int nd = j * 16 + ln;
        int od = ((nd & 31) << 1) | (nd >> 5);
        wv[j] = nw[od];
    }

    if (part == 0) {
        // Q: RMSNorm+RoPE, stage V-style [head][d 64][t 128], r-packed b64 writes
#pragma unroll
        for (int i = 0; i < 4; ++i) {
            float oj[4][4];
#pragma unroll
            for (int r = 0; r < 4; ++r) {
                int tloc = wm + i * 16 + quad * 4 + r;
                int t = (bm + tloc) & 2047;
                float v0 = acc[i][0][r], v1 = acc[i][1][r];
                float v2 = acc[i][2][r], v3 = acc[i][3][r];
                float ss = v0 * v0 + v1 * v1 + v2 * v2 + v3 * v3;
                ss += __shfl_xor(ss, 1);
                ss += __shfl_xor(ss, 2);
                ss += __shfl_xor(ss, 4);
                ss += __shfl_xor(ss, 8);
                float g = rsqrtf(ss * (1.0f / 64.0f) + 1e-6f) * SC;
                float x0a = v0 * g * wv[0], x0b = v1 * g * wv[1];
                float x1a = v2 * g * wv[2], x1b = v3 * g * wv[3];
                float2 cs0 = csb[t * 32 + ln];
                float2 cs1 = csb[t * 32 + 16 + ln];
                oj[0][r] = x0a * cs0.x - x1a * cs0.y;
                oj[2][r] = x0a * cs0.y + x1a * cs0.x;
                oj[1][r] = x0b * cs1.x - x1b * cs1.y;
                oj[3][r] = x0b * cs1.y + x1b * cs1.x;
            }
            int tlb = wm + i * 16 + quad * 4;
#pragma unroll
            for (int j = 0; j < 4; ++j) {
                uint2 pk;
                pk.x = __builtin_amdgcn_perm(fbits(oj[j][1]), fbits(oj[j][0]), 0x07060302u);
                pk.y = __builtin_amdgcn_perm(fbits(oj[j][3]), fbits(oj[j][2]), 0x07060302u);
                *(uint2*)&Es[headw * 8192 + (j * 16 + ln) * 128 + (tlb ^ (ln << 3))] = pk;
            }
        }
        __syncthreads();
#pragma unroll
        for (int c = 0; c < 8; ++c) {
            int cid = c * 256 + tid;
            int tc = cid & 15, d = (cid >> 4) & 63, hd = cid >> 10;
            uint4 v = *(const uint4*)&Es[hd * 8192 + d * 128 + ((tc ^ (d & 15)) << 3)];
            size_t dst = ((size_t)((b * 16 + h0 + hd) * 64 + d)) * 2048 + tbase + tc * 8;
            *(uint4*)&q[dst] = v;
        }
        return;
    }

    // K: RMSNorm + RoPE, [t][d] staging with quarter swizzle
#pragma unroll
    for (int i = 0; i < 4; ++i) {
#pragma unroll
        for (int r = 0; r < 4; ++r) {
            int tloc = wm + i * 16 + quad * 4 + r;
            int t = (bm + tloc) & 2047;

            float v0 = acc[i][0][r], v1 = acc[i][1][r];
            float v2 = acc[i][2][r], v3 = acc[i][3][r];
            float ss = v0 * v0 + v1 * v1 + v2 * v2 + v3 * v3;
            ss += __shfl_xor(ss, 1);
            ss += __shfl_xor(ss, 2);
            ss += __shfl_xor(ss, 4);
            ss += __shfl_xor(ss, 8);
            float g = rsqrtf(ss * (1.0f / 64.0f) + 1e-6f);

            float x0a = v0 * g * wv[0], x0b = v1 * g * wv[1];
            float x1a = v2 * g * wv[2], x1b = v3 * g * wv[3];
            float2 cs0 = csb[t * 32 + ln];
            float2 cs1 = csb[t * 32 + 16 + ln];
            float o0 = x0a * cs0.x - x1a * cs0.y;
            float o2 = x0a * cs0.y + x1a * cs0.x;
            float o1 = x0b * cs1.x - x1b * cs1.y;
            float o3 = x0b * cs1.y + x1b * cs1.x;

            u16* e = &Es[headw * 8192 + tloc * 64 + ln];
            e[((0 ^ quad) << 4)] = f2bf(o0);
            e[((1 ^ quad) << 4)] = f2bf(o1);
            e[((2 ^ quad) << 4)] = f2bf(o2);
            e[((3 ^ quad) << 4)] = f2bf(o3);
        }
    }
    __syncthreads();
#pragma unroll
    for (int c = 0; c < 8; ++c) {
        int cid = c * 256 + tid;
        int dc = cid & 7, tloc = (cid >> 3) & 127, hd = cid >> 10;
        int q2 = (tloc >> 2) & 3;
        int sq = (dc >> 1) ^ q2;
        uint4 v = *(const uint4*)&Es[hd * 8192 + tloc * 64 + sq * 16 + (dc & 1) * 8];
        int gm = bm + tloc;
        int bb = gm >> 11, t = gm & 2047;
        size_t rb = ((size_t)((bb * 16 + h0 + hd) * 2048 + t)) * 64;
        *(uint4*)&k[rb + ((dc ^ (t & 7)) << 3)] = v;
    }
}

// ---------------- 64x128 bf16 GEMM (projection), C = A * B^T, fp32 out ----------------
__global__ __launch_bounds__(256) void gemm64(
    const u16* __restrict__ A, const u16* __restrict__ B,
    float* __restrict__ C, int M, int N, int K)
{
    __shared__ alignas(16) u16 As[64 * 32];
    __shared__ alignas(16) u16 Bs[128 * 32];
    const int tid = threadIdx.x;
    const int lane = tid & 63;
    const int wave = tid >> 6;
    const int bm = blockIdx.y * 64, bn = blockIdx.x * 128;
    const int wm = (wave >> 1) * 32, wn = (wave & 1) * 64;
    const int ln = lane & 15, quad = lane >> 4;

    f32x4 acc[2][4] = {};

    const int srow = tid >> 2;
    const int scol = (tid & 3) * 8;
    const u16* gA = A + (size_t)(bm + (srow & 63)) * K + scol;
    const u16* gB = B + (size_t)(bn + srow) * K + scol;
    u16* lA = &As[wave * 512];
    u16* lB = &Bs[wave * 512];

    for (int k0 = 0; k0 < K; k0 += 32) {
        glds16(gA + k0, lA);
        glds16(gB + k0, lB);
        glds16(gB + (size_t)64 * K + k0, lB + 2048);
        __builtin_amdgcn_s_waitcnt(0);
        __syncthreads();

        bf16x8 af[2], bfr[4];
#pragma unroll
        for (int i = 0; i < 2; ++i)
            af[i] = *(const bf16x8*)&As[(wm + i * 16 + ln) * 32 + quad * 8];
#pragma unroll
        for (int j = 0; j < 4; ++j)
            bfr[j] = *(const bf16x8*)&Bs[(wn + j * 16 + ln) * 32 + quad * 8];
#pragma unroll
        for (int i = 0; i < 2; ++i)
#pragma unroll
            for (int j = 0; j < 4; ++j)
                acc[i][j] = MFMA(af[i], bfr[j], acc[i][j], 0, 0, 0);
        __syncthreads();
    }

#pragma unroll
    for (int i = 0; i < 2; ++i) {
#pragma unroll
        for (int r = 0; r < 4; ++r) {
            int gm = bm + wm + i * 16 + quad * 4 + r;
            float* Crow = C + (size_t)gm * N + bn + wn + ln;
#pragma unroll
            for (int j = 0; j < 4; ++j)
                Crow[j * 16] = acc[i][j][r];
        }
    }
}

// ---------------- flash attention: 512-thread blocks, wave-split paired q-tiles -------
// Waves 0-3 own q-tile A=pi (rows (wave&3)*16), waves 4-7 own q-tile B=31-pi.
// All 8 waves cooperate on K/V staging; A-waves idle past their causal limit.
__global__ __launch_bounds__(512) void attn_kernel(
    const u16* __restrict__ Q, const u16* __restrict__ K,
    const u16* __restrict__ VT, u16* __restrict__ Y)
{
    __shared__ alignas(16) u16 Ks[2][64 * 64];
    __shared__ alignas(16) u16 Vs[2][64 * 64];
    __shared__ alignas(16) u16 Ps[8][16 * 80];

    const int tid = threadIdx.x;
    const int lane = tid & 63;
    const int wave = tid >> 6;          // 0..7
    const int ln = lane & 15, quad = lane >> 4;
    const int pi = blockIdx.x;          // 0..15
    const int bh = blockIdx.y;
    const int qaIdx = pi, qbIdx = 31 - pi;
    const bool isB = wave >= 4;
    const int qidx = isB ? qbIdx : qaIdx;
    const int myq = qidx * 64 + (wave & 3) * 16;
    const size_t base = (size_t)bh * 2048 * 64;
    const u16* Kg = K + base;
    const u16* Vg = VT + base;
    const __bf16* Qg = (const __bf16*)(Q + base);   // (64 d, 2048 t) per head

    // Q fragments via scalar gathers (once per block)
    const int qt = myq + ln;
    bf16x8 qf0, qf1;
#pragma unroll
    for (int j = 0; j < 8; ++j) {
        qf0[j] = Qg[(size_t)(quad * 8 + j) * 2048 + qt];
        qf1[j] = Qg[(size_t)(32 + quad * 8 + j) * 2048 + qt];
    }

    f32x4 o[4] = {};
    float l = 0.0f;
    const int nstages = qbIdx + 1;
    const int sw = ln & 7;
    const int srow = wave * 8 + (lane >> 3);
    const int scol = (lane & 7) * 8;
    u16* Psw = &Ps[wave][0];

    auto prefetch = [&](int jb, int nb) {
        glds16(&Kg[(size_t)(jb + srow) * 64 + scol], &Ks[nb][wave * 512]);
        glds16(&Vg[(size_t)srow * 2048 + jb + scol], &Vs[nb][wave * 512]);
    };
    prefetch(0, 0);

    for (int jt = 0; jt < nstages; ++jt) {
        const int jbn = (jt + 1 < nstages) ? (jt + 1) * 64 : 0;
        prefetch(jbn, (jt + 1) & 1);
        asm volatile("s_waitcnt vmcnt(2)\n\ts_barrier" ::: "memory");

        const u16* ksb = &Ks[jt & 1][0];
        const u16* vsb = &Vs[jt & 1][0];

        if (isB || jt <= qaIdx) {
            f32x4 st[4];
#pragma unroll
            for (int ct = 0; ct < 4; ++ct) {
                bf16x8 kf0 = *(const bf16x8*)&ksb[(ct * 16 + ln) * 64 + ((0 + quad) ^ sw) * 8];
                bf16x8 kf1 = *(const bf16x8*)&ksb[(ct * 16 + ln) * 64 + ((4 + quad) ^ sw) * 8];
                f32x4 z = {};
                z = MFMA(kf0, qf0, z, 0, 0, 0);
                st[ct] = MFMA(kf1, qf1, z, 0, 0, 0);
            }
            if (jt == qidx) {
                const int qg = myq + ln;
                const int jb = jt * 64;
#pragma unroll
                for (int ct = 0; ct < 4; ++ct)
#pragma unroll
                    for (int r = 0; r < 4; ++r)
                        if (jb + ct * 16 + quad * 4 + r > qg) st[ct][r] = -1e30f;
            }

            float sum = 0.0f;
#pragma unroll
            for (int ct = 0; ct < 4; ++ct) {
                float e0 = exp2f(st[ct][0]), e1 = exp2f(st[ct][1]);
                float e2 = exp2f(st[ct][2]), e3 = exp2f(st[ct][3]);
                sum += (e0 + e1) + (e2 + e3);
                uint2 pk;
                pk.x = __builtin_amdgcn_perm(fbits(e1), fbits(e0), 0x07060302u);
                pk.y = __builtin_amdgcn_perm(fbits(e3), fbits(e2), 0x07060302u);
                *(uint2*)&Psw[ln * 80 + ct * 16 + quad * 4] = pk;
            }
            sum += __shfl_xor(sum, 16);
            sum += __shfl_xor(sum, 32);
            l += sum;

            __builtin_amdgcn_s_waitcnt(0xC07F);  // lgkmcnt(0): own Ps writes visible
            bf16x8 pf0 = *(const bf16x8*)&Psw[ln * 80 + quad * 8];
            bf16x8 pf1 = *(const bf16x8*)&Psw[ln * 80 + 32 + quad * 8];

#pragma unroll
            for (int dt = 0; dt < 4; ++dt) {
                bf16x8 vf0 = *(const bf16x8*)&vsb[(dt * 16 + ln) * 64 + ((0 + quad) ^ sw) * 8];
                bf16x8 vf1 = *(const bf16x8*)&vsb[(dt * 16 + ln) * 64 + ((4 + quad) ^ sw) * 8];
                o[dt] = MFMA(pf0, vf0, o[dt], 0, 0, 0);
                o[dt] = MFMA(pf1, vf1, o[dt], 0, 0, 0);
            }
        }
        asm volatile("s_waitcnt lgkmcnt(0)\n\ts_barrier" ::: "memory");
    }

    const int b = bh >> 4, h = bh & 15;
#pragma unroll
    for (int r = 0; r < 4; ++r) {
        float lr = __shfl(l, (lane & 48) + quad * 4 + r);
        float inv = 1.0f / lr;
        int gq = myq + quad * 4 + r;
        size_t yb = ((size_t)(b * 2048 + gq)) * 1024 + h * 64 + ln;
#pragma unroll
        for (int dt = 0; dt < 4; ++dt)
            Y[yb + dt * 16] = f2bf(o[dt][r] * inv);
    }
}

extern "C" void kernel_launch(void* const* d_in, const int* in_sizes, int n_in,
                              void* d_out, int out_size, void* d_ws, size_t ws_size,
                              hipStream_t stream) {
    const float* x      = (const float*)d_in[0];
    const float* fcos   = (const float*)d_in[1];
    const float* fsin   = (const float*)d_in[2];
    const float* w_attn = (const float*)d_in[3];
    const float* w_proj = (const float*)d_in[4];
    const float* qw     = (const float*)d_in[5];
    const float* kw     = (const float*)d_in[6];
    float* out = (float*)d_out;

    char* ws = (char*)d_ws;
    u16*    xb  = (u16*)(ws + 0);          //  8 MB  x bf16; aliased as yb after gemm_qkv
    u16*    yb  = (u16*)(ws + 0);
    u16*    wab = (u16*)(ws + 8388608);    //  6 MB  w_attn bf16 (q/k rows permuted)
    u16*    wpb = (u16*)(ws + 14680064);   //  2 MB  w_proj bf16
    u16*    qb  = (u16*)(ws + 16777216);   //  8 MB  q bf16 (B,H,64,2048), pre-scaled, perm-d
    u16*    kb  = (u16*)(ws + 25165824);   //  8 MB  k bf16 swizzled, perm-d
    u16*    vtb = (u16*)(ws + 33554432);   //  8 MB  v^T bf16 swizzled
    float2* csb = (float2*)(ws + 41943040);// 512 KB cos/sin interleaved table

    castbf3<<<8448, 256, 0, stream>>>(x, xb, w_attn, wab, w_proj, wpb, fcos, fsin, csb);

    gemm_qkv<<<dim3(24, 32), 256, 0, stream>>>(xb, wab, csb, qw, kw, qb, kb, vtb);

    attn_kernel<<<dim3(16, 32), 512, 0, stream>>>(qb, kb, vtb, yb);

    gemm64<<<dim3(8, 64), 256, 0, stream>>>(yb, wpb, out, 4096, 1024, 1024);
}

// Round 9
// 193.024 us; speedup vs baseline: 2.0851x; 1.0707x over previous
//
#include <hip/hip_runtime.h>

typedef unsigned short u16;
typedef unsigned int u32;
typedef __bf16 bf16x8 __attribute__((ext_vector_type(8)));
typedef float f32x4 __attribute__((ext_vector_type(4)));

__device__ __forceinline__ u16 f2bf(float f) {
    union { float f; u32 u; } v;
    v.f = f;
    u32 r = v.u + 0x7fffu + ((v.u >> 16) & 1u);
    return (u16)(r >> 16);
}

__device__ __forceinline__ u32 fbits(float f) {
    union { float f; u32 u; } v; v.f = f; return v.u;
}

__device__ __forceinline__ void glds16(const void* g, void* l) {
    __builtin_amdgcn_global_load_lds(
        (__attribute__((address_space(1))) unsigned int*)(g),
        (__attribute__((address_space(3))) unsigned int*)(l), 16, 0, 0);
}

#define MFMA __builtin_amdgcn_mfma_f32_16x16x32_bf16

// ---------------- fused cast fp32 -> bf16 + cos/sin float2 table ----------------
__global__ void castbf3(const float* __restrict__ a, u16* __restrict__ oa,
                        const float* __restrict__ b, u16* __restrict__ ob,
                        const float* __restrict__ c, u16* __restrict__ oc,
                        const float* __restrict__ fcos, const float* __restrict__ fsin,
                        float2* __restrict__ csb) {
    int blk = blockIdx.x;
    if (blk < 4096) {
        int i = blk * 256 + threadIdx.x;
        float4 v = ((const float4*)a)[i];
        ushort4 o;
        o.x = f2bf(v.x); o.y = f2bf(v.y); o.z = f2bf(v.z); o.w = f2bf(v.w);
        ((ushort4*)oa)[i] = o;
    } else if (blk < 7168) {
        int i = (blk - 4096) * 256 + threadIdx.x;   // float4 index over (3072,1024)
        int n = i >> 8, c4 = i & 255;
        int np;
        if (n < 2048) {
            int part = n >> 10, rem = n & 1023;
            int h = rem >> 6, d = rem & 63;
            int nd = (d >> 1) + ((d & 1) << 5);
            np = part * 1024 + h * 64 + nd;
        } else np = n;
        float4 v = ((const float4*)b)[i];
        ushort4 o;
        o.x = f2bf(v.x); o.y = f2bf(v.y); o.z = f2bf(v.z); o.w = f2bf(v.w);
        ((ushort4*)ob)[np * 256 + c4] = o;
    } else if (blk < 8192) {
        int i = (blk - 7168) * 256 + threadIdx.x;
        float4 v = ((const float4*)c)[i];
        ushort4 o;
        o.x = f2bf(v.x); o.y = f2bf(v.y); o.z = f2bf(v.z); o.w = f2bf(v.w);
        ((ushort4*)oc)[i] = o;
    } else {
        int i = (blk - 8192) * 256 + threadIdx.x;   // 0..65535 over (2048 t, 32 freq)
        csb[i] = make_float2(fcos[i], fsin[i]);
    }
}

// ---------------- QKV GEMM (128x128), double-buffered staging + fused epilogue -------
// LDS: 32 KB total — staging dbuf (2 x 16 KB) UNIONed with the 32 KB epilogue tile.
// Outputs: q (B,H,64d,2048t) pre-scaled by 0.125*log2(e), perm-d; k (B,H,T,64) swizzled,
// perm-d; vt (B,H,64,T) swizzled.
__global__ __launch_bounds__(256) void gemm_qkv(
    const u16* __restrict__ A, const u16* __restrict__ B,
    const float2* __restrict__ csb,
    const float* __restrict__ qw, const float* __restrict__ kw,
    u16* __restrict__ q, u16* __restrict__ k, u16* __restrict__ vt)
{
    __shared__ alignas(16) u16 SB[2 * 8192];     // buf b: A at b*8192 (+4096 = B); Es alias
    u16* Es = SB;
    const int tid = threadIdx.x;
    const int lane = tid & 63;
    const int wave = tid >> 6;
    const int bm = blockIdx.y * 128, bn = blockIdx.x * 128;
    const int wm = (wave >> 1) * 64, wn = (wave & 1) * 64;
    const int ln = lane & 15, quad = lane >> 4;
    const int K = 1024;

    f32x4 acc[4][4] = {};

    const int srow = tid >> 2;
    const int scol = (tid & 3) * 8;
    const u16* gA = A + (size_t)(bm + srow) * K + scol;
    const u16* gB = B + (size_t)(bn + srow) * K + scol;

    auto stage = [&](int k0, int bf) {
        u16* lA = &SB[bf * 8192 + wave * 512];
        u16* lB = &SB[bf * 8192 + 4096 + wave * 512];
        glds16(gA + k0, lA);
        glds16(gA + (size_t)64 * K + k0, lA + 2048);
        glds16(gB + k0, lB);
        glds16(gB + (size_t)64 * K + k0, lB + 2048);
    };

    stage(0, 0);
    for (int it = 0; it < 32; ++it) {
        stage((((it + 1) & 31) << 5), (it + 1) & 1);
        // wait only the CURRENT stage's 4 loads; prefetch stays in flight
        asm volatile("s_waitcnt vmcnt(4)\n\ts_barrier" ::: "memory");

        const u16* Asb = &SB[(it & 1) * 8192];
        const u16* Bsb = Asb + 4096;
        bf16x8 af[4], bfr[4];
#pragma unroll
        for (int i = 0; i < 4; ++i)
            af[i] = *(const bf16x8*)&Asb[(wm + i * 16 + ln) * 32 + quad * 8];
#pragma unroll
        for (int j = 0; j < 4; ++j)
            bfr[j] = *(const bf16x8*)&Bsb[(wn + j * 16 + ln) * 32 + quad * 8];
#pragma unroll
        for (int i = 0; i < 4; ++i)
#pragma unroll
            for (int j = 0; j < 4; ++j)
                acc[i][j] = MFMA(af[i], bfr[j], acc[i][j], 0, 0, 0);

        // all waves done reading this buffer before next iter's DMA may land in it
        asm volatile("s_barrier" ::: "memory");
    }
    // drain in-flight redundant prefetch before reusing SB as the epilogue tile
    asm volatile("s_waitcnt vmcnt(0)\n\ts_barrier" ::: "memory");

    // ---- epilogue ----
    const int part = bn >> 10;                       // 0=q 1=k 2=v
    const int headw = wave & 1;
    const int h0 = (bn & 1023) >> 6;
    const float SC = 0.18033688011112042f;           // 0.125 * log2(e)
    const int b = bm >> 11, tbase = bm & 2047;

    if (part == 2) {
        // V: stage [head][d 64][t 128], t XOR-swizzled by d&15; pack 4 t-vals -> b64
#pragma unroll
        for (int i = 0; i < 4; ++i) {
            int tlb = wm + i * 16 + quad * 4;
#pragma unroll
            for (int j = 0; j < 4; ++j) {
                int d = j * 16 + ln;
                uint2 pk;
                pk.x = __builtin_amdgcn_perm(fbits(acc[i][j][1]), fbits(acc[i][j][0]), 0x07060302u);
                pk.y = __builtin_amdgcn_perm(fbits(acc[i][j][3]), fbits(acc[i][j][2]), 0x07060302u);
                *(uint2*)&Es[headw * 8192 + d * 128 + (tlb ^ (ln << 3))] = pk;
            }
        }
        __syncthreads();
#pragma unroll
        for (int c = 0; c < 8; ++c) {
            int cid = c * 256 + tid;
            int tc = cid & 15, d = (cid >> 4) & 63, hd = cid >> 10;
            uint4 v = *(const uint4*)&Es[hd * 8192 + d * 128 + ((tc ^ (d & 15)) << 3)];
            size_t dst = ((size_t)((b * 16 + h0 + hd) * 64 + d)) * 2048
                       + tbase + ((tc >> 3) << 6) + (((tc & 7) ^ (d & 7)) << 3);
            *(uint4*)&vt[dst] = v;
        }
        return;
    }

    const float* nw = (part == 0) ? qw : kw;
    float wv[4];
#pragma unroll
    for (int j = 0; j < 4; ++j) {
        int nd = j * 16 + ln;
        int od = ((nd & 31) << 1) | (nd >> 5);
        wv[j] = nw[od];
    }

    if (part == 0) {
        // Q: RMSNorm+RoPE, stage V-style [head][d 64][t 128], r-packed b64 writes
#pragma unroll
        for (int i = 0; i < 4; ++i) {
            float oj[4][4];
#pragma unroll
            for (int r = 0; r < 4; ++r) {
                int tloc = wm + i * 16 + quad * 4 + r;
                int t = (bm + tloc) & 2047;
                float v0 = acc[i][0][r], v1 = acc[i][1][r];
                float v2 = acc[i][2][r], v3 = acc[i][3][r];
                float ss = v0 * v0 + v1 * v1 + v2 * v2 + v3 * v3;
                ss += __shfl_xor(ss, 1);
                ss += __shfl_xor(ss, 2);
                ss += __shfl_xor(ss, 4);
                ss += __shfl_xor(ss, 8);
                float g = rsqrtf(ss * (1.0f / 64.0f) + 1e-6f) * SC;
                float x0a = v0 * g * wv[0], x0b = v1 * g * wv[1];
                float x1a = v2 * g * wv[2], x1b = v3 * g * wv[3];
                float2 cs0 = csb[t * 32 + ln];
                float2 cs1 = csb[t * 32 + 16 + ln];
                oj[0][r] = x0a * cs0.x - x1a * cs0.y;
                oj[2][r] = x0a * cs0.y + x1a * cs0.x;
                oj[1][r] = x0b * cs1.x - x1b * cs1.y;
                oj[3][r] = x0b * cs1.y + x1b * cs1.x;
            }
            int tlb = wm + i * 16 + quad * 4;
#pragma unroll
            for (int j = 0; j < 4; ++j) {
                uint2 pk;
                pk.x = __builtin_amdgcn_perm(fbits(oj[j][1]), fbits(oj[j][0]), 0x07060302u);
                pk.y = __builtin_amdgcn_perm(fbits(oj[j][3]), fbits(oj[j][2]), 0x07060302u);
                *(uint2*)&Es[headw * 8192 + (j * 16 + ln) * 128 + (tlb ^ (ln << 3))] = pk;
            }
        }
        __syncthreads();
#pragma unroll
        for (int c = 0; c < 8; ++c) {
            int cid = c * 256 + tid;
            int tc = cid & 15, d = (cid >> 4) & 63, hd = cid >> 10;
            uint4 v = *(const uint4*)&Es[hd * 8192 + d * 128 + ((tc ^ (d & 15)) << 3)];
            size_t dst = ((size_t)((b * 16 + h0 + hd) * 64 + d)) * 2048 + tbase + tc * 8;
            *(uint4*)&q[dst] = v;
        }
        return;
    }

    // K: RMSNorm + RoPE, [t][d] staging with quarter swizzle
#pragma unroll
    for (int i = 0; i < 4; ++i) {
#pragma unroll
        for (int r = 0; r < 4; ++r) {
            int tloc = wm + i * 16 + quad * 4 + r;
            int t = (bm + tloc) & 2047;

            float v0 = acc[i][0][r], v1 = acc[i][1][r];
            float v2 = acc[i][2][r], v3 = acc[i][3][r];
            float ss = v0 * v0 + v1 * v1 + v2 * v2 + v3 * v3;
            ss += __shfl_xor(ss, 1);
            ss += __shfl_xor(ss, 2);
            ss += __shfl_xor(ss, 4);
            ss += __shfl_xor(ss, 8);
            float g = rsqrtf(ss * (1.0f / 64.0f) + 1e-6f);

            float x0a = v0 * g * wv[0], x0b = v1 * g * wv[1];
            float x1a = v2 * g * wv[2], x1b = v3 * g * wv[3];
            float2 cs0 = csb[t * 32 + ln];
            float2 cs1 = csb[t * 32 + 16 + ln];
            float o0 = x0a * cs0.x - x1a * cs0.y;
            float o2 = x0a * cs0.y + x1a * cs0.x;
            float o1 = x0b * cs1.x - x1b * cs1.y;
            float o3 = x0b * cs1.y + x1b * cs1.x;

            u16* e = &Es[headw * 8192 + tloc * 64 + ln];
            e[((0 ^ quad) << 4)] = f2bf(o0);
            e[((1 ^ quad) << 4)] = f2bf(o1);
            e[((2 ^ quad) << 4)] = f2bf(o2);
            e[((3 ^ quad) << 4)] = f2bf(o3);
        }
    }
    __syncthreads();
#pragma unroll
    for (int c = 0; c < 8; ++c) {
        int cid = c * 256 + tid;
        int dc = cid & 7, tloc = (cid >> 3) & 127, hd = cid >> 10;
        int q2 = (tloc >> 2) & 3;
        int sq = (dc >> 1) ^ q2;
        uint4 v = *(const uint4*)&Es[hd * 8192 + tloc * 64 + sq * 16 + (dc & 1) * 8];
        int gm = bm + tloc;
        int bb = gm >> 11, t = gm & 2047;
        size_t rb = ((size_t)((bb * 16 + h0 + hd) * 2048 + t)) * 64;
        *(uint4*)&k[rb + ((dc ^ (t & 7)) << 3)] = v;
    }
}

// ---------------- 64x128 bf16 GEMM (projection), dbuf staging, fp32 out ---------------
__global__ __launch_bounds__(256) void gemm64(
    const u16* __restrict__ A, const u16* __restrict__ B,
    float* __restrict__ C, int M, int N, int K)
{
    __shared__ alignas(16) u16 SB[2 * 6144];     // buf: A 64x32 (2048 u16) + B 128x32 (4096)
    const int tid = threadIdx.x;
    const int lane = tid & 63;
    const int wave = tid >> 6;
    const int bm = blockIdx.y * 64, bn = blockIdx.x * 128;
    const int wm = (wave >> 1) * 32, wn = (wave & 1) * 64;
    const int ln = lane & 15, quad = lane >> 4;

    f32x4 acc[2][4] = {};

    const int srow = tid >> 2;
    const int scol = (tid & 3) * 8;
    const u16* gA = A + (size_t)(bm + srow) * K + scol;
    const u16* gB = B + (size_t)(bn + srow) * K + scol;

    auto stage = [&](int k0, int bf) {
        u16* lA = &SB[bf * 6144 + wave * 512];
        u16* lB = &SB[bf * 6144 + 2048 + wave * 512];
        glds16(gA + k0, lA);
        glds16(gB + k0, lB);
        glds16(gB + (size_t)64 * K + k0, lB + 2048);
    };

    stage(0, 0);
    for (int it = 0; it < 32; ++it) {
        stage((((it + 1) & 31) << 5), (it + 1) & 1);
        asm volatile("s_waitcnt vmcnt(3)\n\ts_barrier" ::: "memory");

        const u16* Asb = &SB[(it & 1) * 6144];
        const u16* Bsb = Asb + 2048;
        bf16x8 af[2], bfr[4];
#pragma unroll
        for (int i = 0; i < 2; ++i)
            af[i] = *(const bf16x8*)&Asb[(wm + i * 16 + ln) * 32 + quad * 8];
#pragma unroll
        for (int j = 0; j < 4; ++j)
            bfr[j] = *(const bf16x8*)&Bsb[(wn + j * 16 + ln) * 32 + quad * 8];
#pragma unroll
        for (int i = 0; i < 2; ++i)
#pragma unroll
            for (int j = 0; j < 4; ++j)
                acc[i][j] = MFMA(af[i], bfr[j], acc[i][j], 0, 0, 0);

        asm volatile("s_barrier" ::: "memory");
    }

#pragma unroll
    for (int i = 0; i < 2; ++i) {
#pragma unroll
        for (int r = 0; r < 4; ++r) {
            int gm = bm + wm + i * 16 + quad * 4 + r;
            float* Crow = C + (size_t)gm * N + bn + wn + ln;
#pragma unroll
            for (int j = 0; j < 4; ++j)
                Crow[j * 16] = acc[i][j][r];
        }
    }
}

// ---------------- flash attention: 512-thread blocks, wave-split paired q-tiles -------
__global__ __launch_bounds__(512) void attn_kernel(
    const u16* __restrict__ Q, const u16* __restrict__ K,
    const u16* __restrict__ VT, u16* __restrict__ Y)
{
    __shared__ alignas(16) u16 Ks[2][64 * 64];
    __shared__ alignas(16) u16 Vs[2][64 * 64];
    __shared__ alignas(16) u16 Ps[8][16 * 80];

    const int tid = threadIdx.x;
    const int lane = tid & 63;
    const int wave = tid >> 6;          // 0..7
    const int ln = lane & 15, quad = lane >> 4;
    const int pi = blockIdx.x;          // 0..15
    const int bh = blockIdx.y;
    const int qaIdx = pi, qbIdx = 31 - pi;
    const bool isB = wave >= 4;
    const int qidx = isB ? qbIdx : qaIdx;
    const int myq = qidx * 64 + (wave & 3) * 16;
    const size_t base = (size_t)bh * 2048 * 64;
    const u16* Kg = K + base;
    const u16* Vg = VT + base;
    const __bf16* Qg = (const __bf16*)(Q + base);   // (64 d, 2048 t) per head

    const int qt = myq + ln;
    bf16x8 qf0, qf1;
#pragma unroll
    for (int j = 0; j < 8; ++j) {
        qf0[j] = Qg[(size_t)(quad * 8 + j) * 2048 + qt];
        qf1[j] = Qg[(size_t)(32 + quad * 8 + j) * 2048 + qt];
    }

    f32x4 o[4] = {};
    float l = 0.0f;
    const int nstages = qbIdx + 1;
    const int sw = ln & 7;
    const int srow = wave * 8 + (lane >> 3);
    const int scol = (lane & 7) * 8;
    u16* Psw = &Ps[wave][0];

    auto prefetch = [&](int jb, int nb) {
        glds16(&Kg[(size_t)(jb + srow) * 64 + scol], &Ks[nb][wave * 512]);
        glds16(&Vg[(size_t)srow * 2048 + jb + scol], &Vs[nb][wave * 512]);
    };
    prefetch(0, 0);

    for (int jt = 0; jt < nstages; ++jt) {
        const int jbn = (jt + 1 < nstages) ? (jt + 1) * 64 : 0;
        prefetch(jbn, (jt + 1) & 1);
        asm volatile("s_waitcnt vmcnt(2)\n\ts_barrier" ::: "memory");

        const u16* ksb = &Ks[jt & 1][0];
        const u16* vsb = &Vs[jt & 1][0];

        if (isB || jt <= qaIdx) {
            f32x4 st[4];
#pragma unroll
            for (int ct = 0; ct < 4; ++ct) {
                bf16x8 kf0 = *(const bf16x8*)&ksb[(ct * 16 + ln) * 64 + ((0 + quad) ^ sw) * 8];
                bf16x8 kf1 = *(const bf16x8*)&ksb[(ct * 16 + ln) * 64 + ((4 + quad) ^ sw) * 8];
                f32x4 z = {};
                z = MFMA(kf0, qf0, z, 0, 0, 0);
                st[ct] = MFMA(kf1, qf1, z, 0, 0, 0);
            }
            if (jt == qidx) {
                const int qg = myq + ln;
                const int jb = jt * 64;
#pragma unroll
                for (int ct = 0; ct < 4; ++ct)
#pragma unroll
                    for (int r = 0; r < 4; ++r)
                        if (jb + ct * 16 + quad * 4 + r > qg) st[ct][r] = -1e30f;
            }

            float sum = 0.0f;
#pragma unroll
            for (int ct = 0; ct < 4; ++ct) {
                float e0 = exp2f(st[ct][0]), e1 = exp2f(st[ct][1]);
                float e2 = exp2f(st[ct][2]), e3 = exp2f(st[ct][3]);
                sum += (e0 + e1) + (e2 + e3);
                uint2 pk;
                pk.x = __builtin_amdgcn_perm(fbits(e1), fbits(e0), 0x07060302u);
                pk.y = __builtin_amdgcn_perm(fbits(e3), fbits(e2), 0x07060302u);
                *(uint2*)&Psw[ln * 80 + ct * 16 + quad * 4] = pk;
            }
            sum += __shfl_xor(sum, 16);
            sum += __shfl_xor(sum, 32);
            l += sum;

            __builtin_amdgcn_s_waitcnt(0xC07F);  // lgkmcnt(0): own Ps writes visible
            bf16x8 pf0 = *(const bf16x8*)&Psw[ln * 80 + quad * 8];
            bf16x8 pf1 = *(const bf16x8*)&Psw[ln * 80 + 32 + quad * 8];

#pragma unroll
            for (int dt = 0; dt < 4; ++dt) {
                bf16x8 vf0 = *(const bf16x8*)&vsb[(dt * 16 + ln) * 64 + ((0 + quad) ^ sw) * 8];
                bf16x8 vf1 = *(const bf16x8*)&vsb[(dt * 16 + ln) * 64 + ((4 + quad) ^ sw) * 8];
                o[dt] = MFMA(pf0, vf0, o[dt], 0, 0, 0);
                o[dt] = MFMA(pf1, vf1, o[dt], 0, 0, 0);
            }
        }
        asm volatile("s_waitcnt lgkmcnt(0)\n\ts_barrier" ::: "memory");
    }

    const int b = bh >> 4, h = bh & 15;
#pragma unroll
    for (int r = 0; r < 4; ++r) {
        float lr = __shfl(l, (lane & 48) + quad * 4 + r);
        float inv = 1.0f / lr;
        int gq = myq + quad * 4 + r;
        size_t yb = ((size_t)(b * 2048 + gq)) * 1024 + h * 64 + ln;
#pragma unroll
        for (int dt = 0; dt < 4; ++dt)
            Y[yb + dt * 16] = f2bf(o[dt][r] * inv);
    }
}

extern "C" void kernel_launch(void* const* d_in, const int* in_sizes, int n_in,
                              void* d_out, int out_size, void* d_ws, size_t ws_size,
                              hipStream_t stream) {
    const float* x      = (const float*)d_in[0];
    const float* fcos   = (const float*)d_in[1];
    const float* fsin   = (const float*)d_in[2];
    const float* w_attn = (const float*)d_in[3];
    const float* w_proj = (const float*)d_in[4];
    const float* qw     = (const float*)d_in[5];
    const float* kw     = (const float*)d_in[6];
    float* out = (float*)d_out;

    char* ws = (char*)d_ws;
    u16*    xb  = (u16*)(ws + 0);          //  8 MB  x bf16; aliased as yb after gemm_qkv
    u16*    yb  = (u16*)(ws + 0);
    u16*    wab = (u16*)(ws + 8388608);    //  6 MB  w_attn bf16 (q/k rows permuted)
    u16*    wpb = (u16*)(ws + 14680064);   //  2 MB  w_proj bf16
    u16*    qb  = (u16*)(ws + 16777216);   //  8 MB  q bf16 (B,H,64,2048), pre-scaled, perm-d
    u16*    kb  = (u16*)(ws + 25165824);   //  8 MB  k bf16 swizzled, perm-d
    u16*    vtb = (u16*)(ws + 33554432);   //  8 MB  v^T bf16 swizzled
    float2* csb = (float2*)(ws + 41943040);// 512 KB cos/sin interleaved table

    castbf3<<<8448, 256, 0, stream>>>(x, xb, w_attn, wab, w_proj, wpb, fcos, fsin, csb);

    gemm_qkv<<<dim3(24, 32), 256, 0, stream>>>(xb, wab, csb, qw, kw, qb, kb, vtb);

    attn_kernel<<<dim3(16, 32), 512, 0, stream>>>(qb, kb, vtb, yb);

    gemm64<<<dim3(8, 64), 256, 0, stream>>>(yb, wpb, out, 4096, 1024, 1024);
}

// Round 10
// 187.849 us; speedup vs baseline: 2.1426x; 1.0275x over previous
//
#include <hip/hip_runtime.h>

typedef unsigned short u16;
typedef unsigned int u32;
typedef __bf16 bf16x8 __attribute__((ext_vector_type(8)));
typedef float f32x4 __attribute__((ext_vector_type(4)));

__device__ __forceinline__ u16 f2bf(float f) {
    union { float f; u32 u; } v;
    v.f = f;
    u32 r = v.u + 0x7fffu + ((v.u >> 16) & 1u);
    return (u16)(r >> 16);
}

__device__ __forceinline__ u32 fbits(float f) {
    union { float f; u32 u; } v; v.f = f; return v.u;
}

__device__ __forceinline__ void glds16(const void* g, void* l) {
    __builtin_amdgcn_global_load_lds(
        (__attribute__((address_space(1))) unsigned int*)(g),
        (__attribute__((address_space(3))) unsigned int*)(l), 16, 0, 0);
}

#define MFMA __builtin_amdgcn_mfma_f32_16x16x32_bf16

// ---------------- fused cast fp32 -> bf16 + cos/sin float2 table ----------------
__global__ void castbf3(const float* __restrict__ a, u16* __restrict__ oa,
                        const float* __restrict__ b, u16* __restrict__ ob,
                        const float* __restrict__ c, u16* __restrict__ oc,
                        const float* __restrict__ fcos, const float* __restrict__ fsin,
                        float2* __restrict__ csb) {
    int blk = blockIdx.x;
    if (blk < 4096) {
        int i = blk * 256 + threadIdx.x;
        float4 v = ((const float4*)a)[i];
        ushort4 o;
        o.x = f2bf(v.x); o.y = f2bf(v.y); o.z = f2bf(v.z); o.w = f2bf(v.w);
        ((ushort4*)oa)[i] = o;
    } else if (blk < 7168) {
        int i = (blk - 4096) * 256 + threadIdx.x;   // float4 index over (3072,1024)
        int n = i >> 8, c4 = i & 255;
        int np;
        if (n < 2048) {
            int part = n >> 10, rem = n & 1023;
            int h = rem >> 6, d = rem & 63;
            int nd = (d >> 1) + ((d & 1) << 5);
            np = part * 1024 + h * 64 + nd;
        } else np = n;
        float4 v = ((const float4*)b)[i];
        ushort4 o;
        o.x = f2bf(v.x); o.y = f2bf(v.y); o.z = f2bf(v.z); o.w = f2bf(v.w);
        ((ushort4*)ob)[np * 256 + c4] = o;
    } else if (blk < 8192) {
        int i = (blk - 7168) * 256 + threadIdx.x;
        float4 v = ((const float4*)c)[i];
        ushort4 o;
        o.x = f2bf(v.x); o.y = f2bf(v.y); o.z = f2bf(v.z); o.w = f2bf(v.w);
        ((ushort4*)oc)[i] = o;
    } else {
        int i = (blk - 8192) * 256 + threadIdx.x;   // 0..65535 over (2048 t, 32 freq)
        csb[i] = make_float2(fcos[i], fsin[i]);
    }
}

// ---------------- QKV GEMM (128x128), double-buffered staging + fused epilogue -------
__global__ __launch_bounds__(256) void gemm_qkv(
    const u16* __restrict__ A, const u16* __restrict__ B,
    const float2* __restrict__ csb,
    const float* __restrict__ qw, const float* __restrict__ kw,
    u16* __restrict__ q, u16* __restrict__ k, u16* __restrict__ vt)
{
    __shared__ alignas(16) u16 SB[2 * 8192];     // buf b: A at b*8192 (+4096 = B); Es alias
    u16* Es = SB;
    const int tid = threadIdx.x;
    const int lane = tid & 63;
    const int wave = tid >> 6;
    const int bm = blockIdx.y * 128, bn = blockIdx.x * 128;
    const int wm = (wave >> 1) * 64, wn = (wave & 1) * 64;
    const int ln = lane & 15, quad = lane >> 4;
    const int K = 1024;

    f32x4 acc[4][4] = {};

    const int srow = tid >> 2;
    const int scol = (tid & 3) * 8;
    const u16* gA = A + (size_t)(bm + srow) * K + scol;
    const u16* gB = B + (size_t)(bn + srow) * K + scol;

    auto stage = [&](int k0, int bf) {
        u16* lA = &SB[bf * 8192 + wave * 512];
        u16* lB = &SB[bf * 8192 + 4096 + wave * 512];
        glds16(gA + k0, lA);
        glds16(gA + (size_t)64 * K + k0, lA + 2048);
        glds16(gB + k0, lB);
        glds16(gB + (size_t)64 * K + k0, lB + 2048);
    };

    stage(0, 0);
    for (int it = 0; it < 32; ++it) {
        stage((((it + 1) & 31) << 5), (it + 1) & 1);
        asm volatile("s_waitcnt vmcnt(4)\n\ts_barrier" ::: "memory");

        const u16* Asb = &SB[(it & 1) * 8192];
        const u16* Bsb = Asb + 4096;
        bf16x8 af[4], bfr[4];
#pragma unroll
        for (int i = 0; i < 4; ++i)
            af[i] = *(const bf16x8*)&Asb[(wm + i * 16 + ln) * 32 + quad * 8];
#pragma unroll
        for (int j = 0; j < 4; ++j)
            bfr[j] = *(const bf16x8*)&Bsb[(wn + j * 16 + ln) * 32 + quad * 8];
#pragma unroll
        for (int i = 0; i < 4; ++i)
#pragma unroll
            for (int j = 0; j < 4; ++j)
                acc[i][j] = MFMA(af[i], bfr[j], acc[i][j], 0, 0, 0);

        asm volatile("s_barrier" ::: "memory");
    }
    asm volatile("s_waitcnt vmcnt(0)\n\ts_barrier" ::: "memory");

    // ---- epilogue ----
    const int part = bn >> 10;                       // 0=q 1=k 2=v
    const int headw = wave & 1;
    const int h0 = (bn & 1023) >> 6;
    const float SC = 0.18033688011112042f;           // 0.125 * log2(e)
    const int b = bm >> 11, tbase = bm & 2047;

    if (part == 2) {
#pragma unroll
        for (int i = 0; i < 4; ++i) {
            int tlb = wm + i * 16 + quad * 4;
#pragma unroll
            for (int j = 0; j < 4; ++j) {
                int d = j * 16 + ln;
                uint2 pk;
                pk.x = __builtin_amdgcn_perm(fbits(acc[i][j][1]), fbits(acc[i][j][0]), 0x07060302u);
                pk.y = __builtin_amdgcn_perm(fbits(acc[i][j][3]), fbits(acc[i][j][2]), 0x07060302u);
                *(uint2*)&Es[headw * 8192 + d * 128 + (tlb ^ (ln << 3))] = pk;
            }
        }
        __syncthreads();
#pragma unroll
        for (int c = 0; c < 8; ++c) {
            int cid = c * 256 + tid;
            int tc = cid & 15, d = (cid >> 4) & 63, hd = cid >> 10;
            uint4 v = *(const uint4*)&Es[hd * 8192 + d * 128 + ((tc ^ (d & 15)) << 3)];
            size_t dst = ((size_t)((b * 16 + h0 + hd) * 64 + d)) * 2048
                       + tbase + ((tc >> 3) << 6) + (((tc & 7) ^ (d & 7)) << 3);
            *(uint4*)&vt[dst] = v;
        }
        return;
    }

    const float* nw = (part == 0) ? qw : kw;
    float wv[4];
#pragma unroll
    for (int j = 0; j < 4; ++j) {
        int nd = j * 16 + ln;
        int od = ((nd & 31) << 1) | (nd >> 5);
        wv[j] = nw[od];
    }

    if (part == 0) {
#pragma unroll
        for (int i = 0; i < 4; ++i) {
            float oj[4][4];
#pragma unroll
            for (int r = 0; r < 4; ++r) {
                int tloc = wm + i * 16 + quad * 4 + r;
                int t = (bm + tloc) & 2047;
                float v0 = acc[i][0][r], v1 = acc[i][1][r];
                float v2 = acc[i][2][r], v3 = acc[i][3][r];
                float ss = v0 * v0 + v1 * v1 + v2 * v2 + v3 * v3;
                ss += __shfl_xor(ss, 1);
                ss += __shfl_xor(ss, 2);
                ss += __shfl_xor(ss, 4);
                ss += __shfl_xor(ss, 8);
                float g = rsqrtf(ss * (1.0f / 64.0f) + 1e-6f) * SC;
                float x0a = v0 * g * wv[0], x0b = v1 * g * wv[1];
                float x1a = v2 * g * wv[2], x1b = v3 * g * wv[3];
                float2 cs0 = csb[t * 32 + ln];
                float2 cs1 = csb[t * 32 + 16 + ln];
                oj[0][r] = x0a * cs0.x - x1a * cs0.y;
                oj[2][r] = x0a * cs0.y + x1a * cs0.x;
                oj[1][r] = x0b * cs1.x - x1b * cs1.y;
                oj[3][r] = x0b * cs1.y + x1b * cs1.x;
            }
            int tlb = wm + i * 16 + quad * 4;
#pragma unroll
            for (int j = 0; j < 4; ++j) {
                uint2 pk;
                pk.x = __builtin_amdgcn_perm(fbits(oj[j][1]), fbits(oj[j][0]), 0x07060302u);
                pk.y = __builtin_amdgcn_perm(fbits(oj[j][3]), fbits(oj[j][2]), 0x07060302u);
                *(uint2*)&Es[headw * 8192 + (j * 16 + ln) * 128 + (tlb ^ (ln << 3))] = pk;
            }
        }
        __syncthreads();
#pragma unroll
        for (int c = 0; c < 8; ++c) {
            int cid = c * 256 + tid;
            int tc = cid & 15, d = (cid >> 4) & 63, hd = cid >> 10;
            uint4 v = *(const uint4*)&Es[hd * 8192 + d * 128 + ((tc ^ (d & 15)) << 3)];
            size_t dst = ((size_t)((b * 16 + h0 + hd) * 64 + d)) * 2048 + tbase + tc * 8;
            *(uint4*)&q[dst] = v;
        }
        return;
    }

    // K: RMSNorm + RoPE, [t][d] staging with quarter swizzle
#pragma unroll
    for (int i = 0; i < 4; ++i) {
#pragma unroll
        for (int r = 0; r < 4; ++r) {
            int tloc = wm + i * 16 + quad * 4 + r;
            int t = (bm + tloc) & 2047;

            float v0 = acc[i][0][r], v1 = acc[i][1][r];
            float v2 = acc[i][2][r], v3 = acc[i][3][r];
            float ss = v0 * v0 + v1 * v1 + v2 * v2 + v3 * v3;
            ss += __shfl_xor(ss, 1);
            ss += __shfl_xor(ss, 2);
            ss += __shfl_xor(ss, 4);
            ss += __shfl_xor(ss, 8);
            float g = rsqrtf(ss * (1.0f / 64.0f) + 1e-6f);

            float x0a = v0 * g * wv[0], x0b = v1 * g * wv[1];
            float x1a = v2 * g * wv[2], x1b = v3 * g * wv[3];
            float2 cs0 = csb[t * 32 + ln];
            float2 cs1 = csb[t * 32 + 16 + ln];
            float o0 = x0a * cs0.x - x1a * cs0.y;
            float o2 = x0a * cs0.y + x1a * cs0.x;
            float o1 = x0b * cs1.x - x1b * cs1.y;
            float o3 = x0b * cs1.y + x1b * cs1.x;

            u16* e = &Es[headw * 8192 + tloc * 64 + ln];
            e[((0 ^ quad) << 4)] = f2bf(o0);
            e[((1 ^ quad) << 4)] = f2bf(o1);
            e[((2 ^ quad) << 4)] = f2bf(o2);
            e[((3 ^ quad) << 4)] = f2bf(o3);
        }
    }
    __syncthreads();
#pragma unroll
    for (int c = 0; c < 8; ++c) {
        int cid = c * 256 + tid;
        int dc = cid & 7, tloc = (cid >> 3) & 127, hd = cid >> 10;
        int q2 = (tloc >> 2) & 3;
        int sq = (dc >> 1) ^ q2;
        uint4 v = *(const uint4*)&Es[hd * 8192 + tloc * 64 + sq * 16 + (dc & 1) * 8];
        int gm = bm + tloc;
        int bb = gm >> 11, t = gm & 2047;
        size_t rb = ((size_t)((bb * 16 + h0 + hd) * 2048 + t)) * 64;
        *(uint4*)&k[rb + ((dc ^ (t & 7)) << 3)] = v;
    }
}

// ---------------- 64x128 bf16 GEMM (projection), dbuf staging, fp32 out ---------------
__global__ __launch_bounds__(256) void gemm64(
    const u16* __restrict__ A, const u16* __restrict__ B,
    float* __restrict__ C, int M, int N, int K)
{
    __shared__ alignas(16) u16 SB[2 * 6144];
    const int tid = threadIdx.x;
    const int lane = tid & 63;
    const int wave = tid >> 6;
    const int bm = blockIdx.y * 64, bn = blockIdx.x * 128;
    const int wm = (wave >> 1) * 32, wn = (wave & 1) * 64;
    const int ln = lane & 15, quad = lane >> 4;

    f32x4 acc[2][4] = {};

    const int srow = tid >> 2;
    const int scol = (tid & 3) * 8;
    const u16* gA = A + (size_t)(bm + srow) * K + scol;
    const u16* gB = B + (size_t)(bn + srow) * K + scol;

    auto stage = [&](int k0, int bf) {
        u16* lA = &SB[bf * 6144 + wave * 512];
        u16* lB = &SB[bf * 6144 + 2048 + wave * 512];
        glds16(gA + k0, lA);
        glds16(gB + k0, lB);
        glds16(gB + (size_t)64 * K + k0, lB + 2048);
    };

    stage(0, 0);
    for (int it = 0; it < 32; ++it) {
        stage((((it + 1) & 31) << 5), (it + 1) & 1);
        asm volatile("s_waitcnt vmcnt(3)\n\ts_barrier" ::: "memory");

        const u16* Asb = &SB[(it & 1) * 6144];
        const u16* Bsb = Asb + 2048;
        bf16x8 af[2], bfr[4];
#pragma unroll
        for (int i = 0; i < 2; ++i)
            af[i] = *(const bf16x8*)&Asb[(wm + i * 16 + ln) * 32 + quad * 8];
#pragma unroll
        for (int j = 0; j < 4; ++j)
            bfr[j] = *(const bf16x8*)&Bsb[(wn + j * 16 + ln) * 32 + quad * 8];
#pragma unroll
        for (int i = 0; i < 2; ++i)
#pragma unroll
            for (int j = 0; j < 4; ++j)
                acc[i][j] = MFMA(af[i], bfr[j], acc[i][j], 0, 0, 0);

        asm volatile("s_barrier" ::: "memory");
    }

#pragma unroll
    for (int i = 0; i < 2; ++i) {
#pragma unroll
        for (int r = 0; r < 4; ++r) {
            int gm = bm + wm + i * 16 + quad * 4 + r;
            float* Crow = C + (size_t)gm * N + bn + wn + ln;
#pragma unroll
            for (int j = 0; j < 4; ++j)
                Crow[j * 16] = acc[i][j][r];
        }
    }
}

// ---------------- flash attention: wave-split pairs + S-ahead software pipeline -------
// Waves 0-3 own q-tile A=pi, waves 4-7 own B=31-pi. Per iteration jt:
//   softmax(jt) [VALU, regs] -> vmcnt(0)+barrier (tile jt+1 landed) ->
//   S[jt+1] MFMAs [overlaps softmax in issue stream] -> PV(jt) -> barrier.
__global__ __launch_bounds__(512) void attn_kernel(
    const u16* __restrict__ Q, const u16* __restrict__ K,
    const u16* __restrict__ VT, u16* __restrict__ Y)
{
    __shared__ alignas(16) u16 Ks[2][64 * 64];
    __shared__ alignas(16) u16 Vs[2][64 * 64];
    __shared__ alignas(16) u16 Ps[8][16 * 80];

    const int tid = threadIdx.x;
    const int lane = tid & 63;
    const int wave = tid >> 6;          // 0..7
    const int ln = lane & 15, quad = lane >> 4;
    const int pi = blockIdx.x;          // 0..15
    const int bh = blockIdx.y;
    const int qaIdx = pi, qbIdx = 31 - pi;
    const bool isB = wave >= 4;
    const int qidx = isB ? qbIdx : qaIdx;
    const int myq = qidx * 64 + (wave & 3) * 16;
    const size_t base = (size_t)bh * 2048 * 64;
    const u16* Kg = K + base;
    const u16* Vg = VT + base;
    const __bf16* Qg = (const __bf16*)(Q + base);   // (64 d, 2048 t) per head

    const int qt = myq + ln;
    bf16x8 qf0, qf1;
#pragma unroll
    for (int j = 0; j < 8; ++j) {
        qf0[j] = Qg[(size_t)(quad * 8 + j) * 2048 + qt];
        qf1[j] = Qg[(size_t)(32 + quad * 8 + j) * 2048 + qt];
    }

    f32x4 o[4] = {};
    float l = 0.0f;
    const int nstages = qbIdx + 1;
    const int sw = ln & 7;
    const int srow = wave * 8 + (lane >> 3);
    const int scol = (lane & 7) * 8;
    u16* Psw = &Ps[wave][0];

    auto prefetch = [&](int jb, int nb) {
        glds16(&Kg[(size_t)(jb + srow) * 64 + scol], &Ks[nb][wave * 512]);
        glds16(&Vg[(size_t)srow * 2048 + jb + scol], &Vs[nb][wave * 512]);
    };
    auto computeS = [&](f32x4* st, const u16* ksb) {
#pragma unroll
        for (int ct = 0; ct < 4; ++ct) {
            bf16x8 kf0 = *(const bf16x8*)&ksb[(ct * 16 + ln) * 64 + (quad ^ sw) * 8];
            bf16x8 kf1 = *(const bf16x8*)&ksb[(ct * 16 + ln) * 64 + ((4 + quad) ^ sw) * 8];
            f32x4 z = {};
            z = MFMA(kf0, qf0, z, 0, 0, 0);
            st[ct] = MFMA(kf1, qf1, z, 0, 0, 0);
        }
    };
    auto applyMask = [&](f32x4* st, int jb) {
        const int qg = myq + ln;
#pragma unroll
        for (int ct = 0; ct < 4; ++ct)
#pragma unroll
            for (int r = 0; r < 4; ++r)
                if (jb + ct * 16 + quad * 4 + r > qg) st[ct][r] = -1e30f;
    };

    // prologue: tile 0 resident, S[0] in registers
    prefetch(0, 0);
    asm volatile("s_waitcnt vmcnt(0)\n\ts_barrier" ::: "memory");
    f32x4 st[4];
    computeS(st, &Ks[0][0]);
    if (qidx == 0) applyMask(st, 0);

    for (int jt = 0; jt < nstages; ++jt) {
        const bool haveNext = (jt + 1 < nstages);
        if (haveNext) prefetch((jt + 1) * 64, (jt + 1) & 1);

        const bool curActive = isB || jt <= qaIdx;
        if (curActive) {
            float sum = 0.0f;
#pragma unroll
            for (int ct = 0; ct < 4; ++ct) {
                float e0 = exp2f(st[ct][0]), e1 = exp2f(st[ct][1]);
                float e2 = exp2f(st[ct][2]), e3 = exp2f(st[ct][3]);
                sum += (e0 + e1) + (e2 + e3);
                uint2 pk;
                pk.x = __builtin_amdgcn_perm(fbits(e1), fbits(e0), 0x07060302u);
                pk.y = __builtin_amdgcn_perm(fbits(e3), fbits(e2), 0x07060302u);
                *(uint2*)&Psw[ln * 80 + ct * 16 + quad * 4] = pk;
            }
            l += sum;   // per-lane partial; cross-quad reduce deferred to epilogue
        }

        asm volatile("s_waitcnt vmcnt(0)\n\ts_barrier" ::: "memory");  // tile jt+1 landed

        const bool nextActive = haveNext && (isB || (jt + 1) <= qaIdx);
        if (nextActive) {
            computeS(st, &Ks[(jt + 1) & 1][0]);
            if (jt + 1 == qidx) applyMask(st, (jt + 1) * 64);
        }

        if (curActive) {
            __builtin_amdgcn_s_waitcnt(0xC07F);  // lgkmcnt(0): own Ps writes visible
            bf16x8 pf0 = *(const bf16x8*)&Psw[ln * 80 + quad * 8];
            bf16x8 pf1 = *(const bf16x8*)&Psw[ln * 80 + 32 + quad * 8];
            const u16* vsb = &Vs[jt & 1][0];
#pragma unroll
            for (int dt = 0; dt < 4; ++dt) {
                bf16x8 vf0 = *(const bf16x8*)&vsb[(dt * 16 + ln) * 64 + (quad ^ sw) * 8];
                bf16x8 vf1 = *(const bf16x8*)&vsb[(dt * 16 + ln) * 64 + ((4 + quad) ^ sw) * 8];
                o[dt] = MFMA(pf0, vf0, o[dt], 0, 0, 0);
                o[dt] = MFMA(pf1, vf1, o[dt], 0, 0, 0);
            }
        }
        // all waves done reading buf jt&1 before next iter's DMA may target it
        asm volatile("s_waitcnt lgkmcnt(0)\n\ts_barrier" ::: "memory");
    }

    // deferred l reduction: sum the 4 quad partials per q-column
    l += __shfl_xor(l, 16);
    l += __shfl_xor(l, 32);

    const int b = bh >> 4, h = bh & 15;
#pragma unroll
    for (int r = 0; r < 4; ++r) {
        float lr = __shfl(l, (lane & 48) + quad * 4 + r);
        float inv = 1.0f / lr;
        int gq = myq + quad * 4 + r;
        size_t yb = ((size_t)(b * 2048 + gq)) * 1024 + h * 64 + ln;
#pragma unroll
        for (int dt = 0; dt < 4; ++dt)
            Y[yb + dt * 16] = f2bf(o[dt][r] * inv);
    }
}

extern "C" void kernel_launch(void* const* d_in, const int* in_sizes, int n_in,
                              void* d_out, int out_size, void* d_ws, size_t ws_size,
                              hipStream_t stream) {
    const float* x      = (const float*)d_in[0];
    const float* fcos   = (const float*)d_in[1];
    const float* fsin   = (const float*)d_in[2];
    const float* w_attn = (const float*)d_in[3];
    const float* w_proj = (const float*)d_in[4];
    const float* qw     = (const float*)d_in[5];
    const float* kw     = (const float*)d_in[6];
    float* out = (float*)d_out;

    char* ws = (char*)d_ws;
    u16*    xb  = (u16*)(ws + 0);          //  8 MB  x bf16; aliased as yb after gemm_qkv
    u16*    yb  = (u16*)(ws + 0);
    u16*    wab = (u16*)(ws + 8388608);    //  6 MB  w_attn bf16 (q/k rows permuted)
    u16*    wpb = (u16*)(ws + 14680064);   //  2 MB  w_proj bf16
    u16*    qb  = (u16*)(ws + 16777216);   //  8 MB  q bf16 (B,H,64,2048), pre-scaled, perm-d
    u16*    kb  = (u16*)(ws + 25165824);   //  8 MB  k bf16 swizzled, perm-d
    u16*    vtb = (u16*)(ws + 33554432);   //  8 MB  v^T bf16 swizzled
    float2* csb = (float2*)(ws + 41943040);// 512 KB cos/sin interleaved table

    castbf3<<<8448, 256, 0, stream>>>(x, xb, w_attn, wab, w_proj, wpb, fcos, fsin, csb);

    gemm_qkv<<<dim3(24, 32), 256, 0, stream>>>(xb, wab, csb, qw, kw, qb, kb, vtb);

    attn_kernel<<<dim3(16, 32), 512, 0, stream>>>(qb, kb, vtb, yb);

    gemm64<<<dim3(8, 64), 256, 0, stream>>>(yb, wpb, out, 4096, 1024, 1024);
}